// Round 3
// baseline (1257.815 us; speedup 1.0000x reference)
//
#include <hip/hip_runtime.h>
#include <cstdio>

#define B_   64
#define S_   512
#define D_   512
#define H_   8
#define DK_  64
#define DFF_ 1024
#define L_   2

typedef __attribute__((ext_vector_type(8))) short bf16x8;
typedef __attribute__((ext_vector_type(4))) float f32x4;

__device__ inline short f2bf(float f) {
  unsigned u = __float_as_uint(f);
  u = u + 0x7FFF + ((u >> 16) & 1);
  return (short)(u >> 16);
}
__device__ inline float bf2f(short s) {
  return __uint_as_float(((unsigned)(unsigned short)s) << 16);
}

// async global->LDS, 16B per lane; lds dest = wave-uniform base + lane*16
__device__ inline void gl_lds16(const short* g, void* lds_base) {
  __builtin_amdgcn_global_load_lds(
      (const __attribute__((address_space(1))) void*)g,
      (__attribute__((address_space(3))) void*)lds_base, 16, 0, 0);
}

// ---------------- positional encoding table ----------------
__global__ void pe_kernel(float* __restrict__ pe) {
  int idx = blockIdx.x * 256 + threadIdx.x;      // S_*D_ threads
  int s = idx >> 9, d = idx & 511;
  float dv = __expf((float)(d & ~1) * (-9.210340371976184f / (float)D_));
  float ang = (float)s * dv;
  pe[idx] = (d & 1) ? cosf(ang) : sinf(ang);
}

// x = q + pe (f32 master + bf16 mirror); yb = bf16(qa + pe)
__global__ void prep_kernel(const float* __restrict__ q, const float* __restrict__ qa,
                            const float* __restrict__ pe, float* __restrict__ x,
                            short* __restrict__ xb, short* __restrict__ yb) {
  size_t idx = (size_t)blockIdx.x * 256 + threadIdx.x;
  int sd = (int)(idx & (size_t)(S_ * D_ - 1));
  float p = pe[sd];
  float xv = q[idx] + p;
  x[idx] = xv;
  xb[idx] = f2bf(xv);
  yb[idx] = f2bf(qa[idx] + p);
}

// dst[c][r] = bf16(src[r][c]); src is R x C row-major
__global__ void tr_bf16(const float* __restrict__ src, short* __restrict__ dst, int R, int C) {
  int idx = blockIdx.x * 256 + threadIdx.x;
  if (idx >= R * C) return;
  int r = idx / C, c = idx - r * C;
  dst[(size_t)c * R + r] = f2bf(src[idx]);
}

// ---------------- bf16 MFMA GEMM: C[M,N] = A[M,K] @ BT[N,K]^T + bias ----------------
// 128x128 tile, BK=32, 256 threads (4 waves, 2x2), acc 4x4 16x16 fragments per wave.
// Staging via global_load_lds width=16 (m97 structure, linear LDS).
// vt_mode: write output transposed per (b,head): vT[((b*D)+col)*S + s]
__global__ __launch_bounds__(256) void gemm_bt(
    const short* __restrict__ A, const short* __restrict__ BT,
    const float* __restrict__ bias, short* __restrict__ Cb,
    int M, int N, int K, int relu, int vt_mode)
{
  __shared__ __align__(16) short As[128][32];
  __shared__ __align__(16) short Bs[128][32];
  const int t = threadIdx.x;
  const int bcol = blockIdx.x, brow = blockIdx.y;
  const int w = t >> 6, lane = t & 63, lr = lane & 15, lk = lane >> 4;
  const int wrow = w >> 1, wcol = w & 1;

  const f32x4 vzero = {0.f, 0.f, 0.f, 0.f};
  f32x4 acc[4][4];
#pragma unroll
  for (int m = 0; m < 4; ++m)
#pragma unroll
    for (int n = 0; n < 4; ++n) acc[m][n] = vzero;

  const short* Abase = A + (size_t)brow * 128 * K;
  const short* Bbase = BT + (size_t)bcol * 128 * K;
  char* AsF = (char*)&As[0][0];
  char* BsF = (char*)&Bs[0][0];

  for (int k0 = 0; k0 < K; k0 += 32) {
    __syncthreads();   // protect LDS reuse (compiler drains counts before barrier)
#pragma unroll
    for (int it = 0; it < 2; ++it) {
      int cb = it * 256 + w * 64;          // wave-uniform chunk base (each chunk = 16B)
      int c = cb + lane;                   // this lane's chunk
      int row = c >> 2, seg = c & 3;       // 4 chunks of 16B per 64B row (32 shorts)
      gl_lds16(Abase + (size_t)row * K + k0 + seg * 8, AsF + (size_t)cb * 16);
      gl_lds16(Bbase + (size_t)row * K + k0 + seg * 8, BsF + (size_t)cb * 16);
    }
    __syncthreads();   // vmcnt(0) drain + barrier: tiles ready

    bf16x8 af[4], bf[4];
#pragma unroll
    for (int m = 0; m < 4; ++m) af[m] = *(const bf16x8*)&As[wrow * 64 + m * 16 + lr][lk * 8];
#pragma unroll
    for (int n = 0; n < 4; ++n) bf[n] = *(const bf16x8*)&Bs[wcol * 64 + n * 16 + lr][lk * 8];
#pragma unroll
    for (int m = 0; m < 4; ++m)
#pragma unroll
      for (int n = 0; n < 4; ++n)
        acc[m][n] = __builtin_amdgcn_mfma_f32_16x16x32_bf16(af[m], bf[n], acc[m][n], 0, 0, 0);
  }

#pragma unroll
  for (int m = 0; m < 4; ++m)
#pragma unroll
    for (int n = 0; n < 4; ++n) {
      int col = bcol * 128 + wcol * 64 + n * 16 + lr;
      float bvv = bias ? bias[col] : 0.f;
#pragma unroll
      for (int j = 0; j < 4; ++j) {
        int row = brow * 128 + wrow * 64 + m * 16 + lk * 4 + j;
        float vv = acc[m][n][j] + bvv;
        if (relu) vv = fmaxf(vv, 0.f);
        if (vt_mode) {
          // row = b*512 + s ; transposed per batch: vT[(b*D + col)*S + s]
          Cb[((size_t)(row >> 9) * D_ + col) * S_ + (row & 511)] = f2bf(vv);
        } else {
          Cb[(size_t)row * N + col] = f2bf(vv);
        }
      }
    }
}

// ---------------- fused attention (flash-style, causal tile skipping) ----------------
// grid (S/64, H, B), 256 threads = 4 waves; wave w owns q rows [qb*64+w*16, +16).
// scores = (qk @ qk^T) * scale * fr[q]; strict-lower mask; online softmax; P @ V via vT.
__global__ __launch_bounds__(256) void attn_kernel(
    const short* __restrict__ qk, const short* __restrict__ vT,
    const float* __restrict__ fr, short* __restrict__ out)
{
  const int qb = blockIdx.x, h = blockIdx.y, b = blockIdx.z;
  const int t = threadIdx.x;
  const int w = t >> 6, lane = t & 63, lr = lane & 15, lk = lane >> 4;

  __shared__ __align__(16) short P[4][16][80];   // wave-private P slabs

  const size_t qk_head = (size_t)b * S_ * D_ + (size_t)h * DK_;
  const short* vTh = vT + ((size_t)b * D_ + h * DK_) * S_;
  const int q0 = qb * 64 + w * 16;
  const float NEGBIG = -3.0e38f;
  const float scale = 0.125f;   // 1/sqrt(64)

  // Q fragments: a[j] = Q[q0+lr][ks*32+lk*8+j]
  bf16x8 qf[2];
#pragma unroll
  for (int ks = 0; ks < 2; ++ks)
    qf[ks] = *(const bf16x8*)(qk + qk_head + (size_t)(q0 + lr) * D_ + ks * 32 + lk * 8);

  const f32x4 vzero = {0.f, 0.f, 0.f, 0.f};
  float frv[4], m[4], l[4];
  f32x4 oacc[4];
#pragma unroll
  for (int j = 0; j < 4; ++j) {
    frv[j] = scale * fr[(size_t)b * S_ + q0 + lk * 4 + j];
    m[j] = NEGBIG;
    l[j] = 0.f;
  }
#pragma unroll
  for (int dn = 0; dn < 4; ++dn) oacc[dn] = vzero;

  for (int tkv = 0; tkv <= qb; ++tkv) {
    // ---- QK^T on a 64-key tile: wave computes [16q x 64k]
    f32x4 sacc[4];
#pragma unroll
    for (int n = 0; n < 4; ++n) sacc[n] = vzero;
#pragma unroll
    for (int n = 0; n < 4; ++n) {
      int kvr = tkv * 64 + n * 16 + lr;
#pragma unroll
      for (int ks = 0; ks < 2; ++ks) {
        bf16x8 kf = *(const bf16x8*)(qk + qk_head + (size_t)kvr * D_ + ks * 32 + lk * 8);
        sacc[n] = __builtin_amdgcn_mfma_f32_16x16x32_bf16(qf[ks], kf, sacc[n], 0, 0, 0);
      }
    }

    // ---- scale*fr + mask, tile max
    const int diag = (tkv == qb);
    float sv[4][4], tmax[4];
#pragma unroll
    for (int j = 0; j < 4; ++j) tmax[j] = NEGBIG;
#pragma unroll
    for (int n = 0; n < 4; ++n) {
      int kcol = tkv * 64 + n * 16 + lr;
#pragma unroll
      for (int j = 0; j < 4; ++j) {
        int qrow = q0 + lk * 4 + j;
        bool ok = !diag || (kcol < qrow);
        float s = ok ? sacc[n][j] * frv[j] : NEGBIG;
        sv[n][j] = s;
        tmax[j] = fmaxf(tmax[j], s);
      }
    }
#pragma unroll
    for (int msk = 1; msk < 16; msk <<= 1)
#pragma unroll
      for (int j = 0; j < 4; ++j) tmax[j] = fmaxf(tmax[j], __shfl_xor(tmax[j], msk));

    // ---- online softmax update
    float r[4], tsum[4];
#pragma unroll
    for (int j = 0; j < 4; ++j) {
      float mn = fmaxf(m[j], tmax[j]);
      r[j] = __expf(m[j] - mn);   // NEGBIG-NEGBIG -> exp(0)=1 (l stays 0)
      m[j] = mn;
      tsum[j] = 0.f;
    }
#pragma unroll
    for (int n = 0; n < 4; ++n)
#pragma unroll
      for (int j = 0; j < 4; ++j) {
        float e = (sv[n][j] > -1.0e37f) ? __expf(sv[n][j] - m[j]) : 0.f;
        tsum[j] += e;
        P[w][lk * 4 + j][n * 16 + lr] = f2bf(e);
      }
#pragma unroll
    for (int msk = 1; msk < 16; msk <<= 1)
#pragma unroll
      for (int j = 0; j < 4; ++j) tsum[j] += __shfl_xor(tsum[j], msk);
#pragma unroll
    for (int j = 0; j < 4; ++j) l[j] = l[j] * r[j] + tsum[j];
#pragma unroll
    for (int dn = 0; dn < 4; ++dn)
#pragma unroll
      for (int j = 0; j < 4; ++j) oacc[dn][j] *= r[j];

    // ---- PV: A = P[16q x 64k] (wave-local LDS, DS ops in-order), B = vT vector loads
#pragma unroll
    for (int ks = 0; ks < 2; ++ks) {
      bf16x8 pa = *(const bf16x8*)&P[w][lr][ks * 32 + lk * 8];
#pragma unroll
      for (int dn = 0; dn < 4; ++dn) {
        bf16x8 vf = *(const bf16x8*)(vTh + (size_t)(dn * 16 + lr) * S_ + tkv * 64 + ks * 32 + lk * 8);
        oacc[dn] = __builtin_amdgcn_mfma_f32_16x16x32_bf16(pa, vf, oacc[dn], 0, 0, 0);
      }
    }
  }

  // ---- normalize + write (row with l==0 -> 0, matches zero_pad)
  float invd[4];
#pragma unroll
  for (int j = 0; j < 4; ++j) invd[j] = l[j] > 0.f ? 1.f / l[j] : 0.f;
#pragma unroll
  for (int dn = 0; dn < 4; ++dn)
#pragma unroll
    for (int j = 0; j < 4; ++j)
      out[qk_head + (size_t)(q0 + lk * 4 + j) * D_ + dn * 16 + lr] = f2bf(oacc[dn][j] * invd[j]);
}

// ---------------- fused residual + LayerNorm ----------------
__global__ __launch_bounds__(256) void ln_res(
    const float* __restrict__ xin, const short* __restrict__ add,
    const float* __restrict__ g, const float* __restrict__ bb,
    float* __restrict__ xout, short* __restrict__ xbout)
{
  const int row = blockIdx.x * 4 + (threadIdx.x >> 6);
  const int lane = threadIdx.x & 63;
  const size_t base = (size_t)row * D_ + lane * 8;

  f32x4 a0 = *(const f32x4*)(xin + base);
  f32x4 a1 = *(const f32x4*)(xin + base + 4);
  bf16x8 av = *(const bf16x8*)(add + base);
  float vals[8];
#pragma unroll
  for (int i = 0; i < 4; ++i) vals[i] = a0[i] + bf2f(av[i]);
#pragma unroll
  for (int i = 0; i < 4; ++i) vals[4 + i] = a1[i] + bf2f(av[4 + i]);

  float s = 0.f, sq = 0.f;
#pragma unroll
  for (int i = 0; i < 8; ++i) { s += vals[i]; sq += vals[i] * vals[i]; }
#pragma unroll
  for (int m = 1; m < 64; m <<= 1) { s += __shfl_xor(s, m); sq += __shfl_xor(sq, m); }

  float mean = s * (1.f / D_);
  float var = sq * (1.f / D_) - mean * mean;
  float rstd = rsqrtf(var + 1e-5f);

  int col = lane * 8;
  f32x4 o0, o1; bf16x8 ob;
#pragma unroll
  for (int i = 0; i < 8; ++i) {
    float vv = g[col + i] * (vals[i] - mean) * rstd + bb[col + i];
    if (i < 4) o0[i] = vv; else o1[i - 4] = vv;
    ob[i] = f2bf(vv);
  }
  *(f32x4*)(xout + base) = o0;
  *(f32x4*)(xout + base + 4) = o1;
  *(bf16x8*)(xbout + base) = ob;
}

// ---------------- host ----------------
extern "C" void kernel_launch(void* const* d_in, const int* in_sizes, int n_in,
                              void* d_out, int out_size, void* d_ws, size_t ws_size,
                              hipStream_t stream) {
  const float* q_emb = (const float*)d_in[0];
  const float* qa_emb = (const float*)d_in[1];
  const float* frate = (const float*)d_in[2];
  const float* Wk = (const float*)d_in[3];
  const float* bk = (const float*)d_in[4];
  const float* Wv = (const float*)d_in[5];
  const float* bv = (const float*)d_in[6];
  const float* Wo = (const float*)d_in[7];
  const float* bo = (const float*)d_in[8];
  const float* ln1g = (const float*)d_in[9];
  const float* ln1b = (const float*)d_in[10];
  const float* W1 = (const float*)d_in[11];
  const float* b1 = (const float*)d_in[12];
  const float* W2 = (const float*)d_in[13];
  const float* b2 = (const float*)d_in[14];
  const float* ln2g = (const float*)d_in[15];
  const float* ln2b = (const float*)d_in[16];
  float* x = (float*)d_out;

  char* ws = (char*)d_ws;
  size_t off = 0;
  auto alloc = [&](size_t bytes) -> void* {
    void* p = ws + off;
    off += (bytes + 255) & ~(size_t)255;
    return p;
  };
  const size_t MTOK = (size_t)B_ * S_;   // 32768 rows
  float* pe    = (float*)alloc((size_t)S_ * D_ * 4);
  short* xb    = (short*)alloc(MTOK * D_ * 2);
  short* yb    = (short*)alloc(MTOK * D_ * 2);
  short* qkb   = (short*)alloc(MTOK * D_ * 2);
  short* vTb   = (short*)alloc(MTOK * D_ * 2);   // V transposed per batch: [B][D][S]
  short* ff1b  = (short*)alloc(MTOK * DFF_ * 2);
  // lifetime-based aliases:
  //   attnb (attn->WoGEMM) aliases ff1b (ff1GEMM->ff2GEMM) -- disjoint within a layer
  //   goutb (WoGEMM/ff2GEMM -> ln_res) aliases qkb (dead after attn_kernel)
  short* attnb = ff1b;
  short* goutb = qkb;
  short* wT[L_][5];
  for (int i = 0; i < L_; ++i) {
    wT[i][0] = (short*)alloc((size_t)D_ * D_ * 2);     // WkT [D][D]
    wT[i][1] = (short*)alloc((size_t)D_ * D_ * 2);     // WvT
    wT[i][2] = (short*)alloc((size_t)D_ * D_ * 2);     // WoT
    wT[i][3] = (short*)alloc((size_t)D_ * DFF_ * 2);   // W1T [DFF][D]
    wT[i][4] = (short*)alloc((size_t)DFF_ * D_ * 2);   // W2T [D][DFF]
  }
  if (off > ws_size) {
    fprintf(stderr, "parKT: workspace overflow: need %zu have %zu\n", off, ws_size);
    return;
  }

  pe_kernel<<<(S_ * D_) / 256, 256, 0, stream>>>(pe);
  prep_kernel<<<(int)(MTOK * D_ / 256), 256, 0, stream>>>(q_emb, qa_emb, pe, x, xb, yb);

  for (int i = 0; i < L_; ++i) {
    tr_bf16<<<(D_ * D_ + 255) / 256, 256, 0, stream>>>(Wk + (size_t)i * D_ * D_, wT[i][0], D_, D_);
    tr_bf16<<<(D_ * D_ + 255) / 256, 256, 0, stream>>>(Wv + (size_t)i * D_ * D_, wT[i][1], D_, D_);
    tr_bf16<<<(D_ * D_ + 255) / 256, 256, 0, stream>>>(Wo + (size_t)i * D_ * D_, wT[i][2], D_, D_);
    tr_bf16<<<(D_ * DFF_ + 255) / 256, 256, 0, stream>>>(W1 + (size_t)i * D_ * DFF_, wT[i][3], D_, DFF_);
    tr_bf16<<<(DFF_ * D_ + 255) / 256, 256, 0, stream>>>(W2 + (size_t)i * DFF_ * D_, wT[i][4], DFF_, D_);
  }

  const int M = (int)MTOK;
  for (int i = 0; i < L_; ++i) {
    gemm_bt<<<dim3(D_ / 128, M / 128), 256, 0, stream>>>(xb, wT[i][0], bk + (size_t)i * D_, qkb, M, D_, D_, 0, 0);
    gemm_bt<<<dim3(D_ / 128, M / 128), 256, 0, stream>>>(yb, wT[i][1], bv + (size_t)i * D_, vTb, M, D_, D_, 0, 1);
    attn_kernel<<<dim3(S_ / 64, H_, B_), 256, 0, stream>>>(qkb, vTb, frate, attnb);
    gemm_bt<<<dim3(D_ / 128, M / 128), 256, 0, stream>>>(attnb, wT[i][2], bo + (size_t)i * D_, goutb, M, D_, D_, 0, 0);
    ln_res<<<M / 4, 256, 0, stream>>>(x, goutb, ln1g + (size_t)i * D_, ln1b + (size_t)i * D_, x, xb);
    gemm_bt<<<dim3(DFF_ / 128, M / 128), 256, 0, stream>>>(xb, wT[i][3], b1 + (size_t)i * DFF_, ff1b, M, DFF_, D_, 1, 0);
    gemm_bt<<<dim3(D_ / 128, M / 128), 256, 0, stream>>>(ff1b, wT[i][4], b2 + (size_t)i * D_, goutb, M, D_, DFF_, 0, 0);
    ln_res<<<M / 4, 256, 0, stream>>>(x, goutb, ln2g + (size_t)i * D_, ln2b + (size_t)i * D_, x, xb);
  }
}

// Round 4
// 1222.324 us; speedup vs baseline: 1.0290x; 1.0290x over previous
//
#include <hip/hip_runtime.h>
#include <cstdio>

#define B_   64
#define S_   512
#define D_   512
#define H_   8
#define DK_  64
#define DFF_ 1024
#define L_   2
#define BS_  (B_ * S_)   // 32768

typedef __attribute__((ext_vector_type(8))) short bf16x8;
typedef __attribute__((ext_vector_type(4))) float f32x4;

__device__ inline short f2bf(float f) {
  unsigned u = __float_as_uint(f);
  u = u + 0x7FFF + ((u >> 16) & 1);
  return (short)(u >> 16);
}
__device__ inline float bf2f(short s) {
  return __uint_as_float(((unsigned)(unsigned short)s) << 16);
}

// async global->LDS, 16B per lane; lds dest = wave-uniform base + lane*16
__device__ inline void gl_lds16(const short* g, void* lds_base) {
  __builtin_amdgcn_global_load_lds(
      (const __attribute__((address_space(1))) void*)g,
      (__attribute__((address_space(3))) void*)lds_base, 16, 0, 0);
}

// ---------------- positional encoding table ----------------
__global__ void pe_kernel(float* __restrict__ pe) {
  int idx = blockIdx.x * 256 + threadIdx.x;      // S_*D_ threads
  int s = idx >> 9, d = idx & 511;
  float dv = __expf((float)(d & ~1) * (-9.210340371976184f / (float)D_));
  float ang = (float)s * dv;
  pe[idx] = (d & 1) ? cosf(ang) : sinf(ang);
}

// x = q + pe (f32 master + bf16 mirror); yb = bf16(qa + pe)
__global__ void prep_kernel(const float* __restrict__ q, const float* __restrict__ qa,
                            const float* __restrict__ pe, float* __restrict__ x,
                            short* __restrict__ xb, short* __restrict__ yb) {
  size_t idx = (size_t)blockIdx.x * 256 + threadIdx.x;
  int sd = (int)(idx & (size_t)(S_ * D_ - 1));
  float p = pe[sd];
  float xv = q[idx] + p;
  x[idx] = xv;
  xb[idx] = f2bf(xv);
  yb[idx] = f2bf(qa[idx] + p);
}

// ---------------- tiled weight transpose: dst[c][r] = bf16(src[r][c]) ----------------
// grid (C/64, R/64), 256 threads. Coalesced read + coalesced write via LDS.
__global__ __launch_bounds__(256) void tr_w(const float* __restrict__ src,
                                            short* __restrict__ dst, int R, int C) {
  __shared__ short Ts[64][72];
  const int t = threadIdx.x;
  const int c0 = blockIdx.x * 64, r0 = blockIdx.y * 64;
#pragma unroll
  for (int it = 0; it < 2; ++it) {
    int c2 = it * 256 + t;
    int srow = c2 >> 3, schunk = c2 & 7;         // 8 chunks of 8 floats per 64-float row
    const float* sp = src + (size_t)(r0 + srow) * C + c0 + schunk * 8;
    f32x4 a0 = *(const f32x4*)sp;
    f32x4 a1 = *(const f32x4*)(sp + 4);
#pragma unroll
    for (int k = 0; k < 4; ++k) Ts[srow][schunk * 8 + k] = f2bf(a0[k]);
#pragma unroll
    for (int k = 0; k < 4; ++k) Ts[srow][schunk * 8 + 4 + k] = f2bf(a1[k]);
  }
  __syncthreads();
#pragma unroll
  for (int it = 0; it < 2; ++it) {
    int c2 = it * 256 + t;
    int orow = c2 >> 3, ochunk = c2 & 7;
    bf16x8 vv;
#pragma unroll
    for (int k = 0; k < 8; ++k) vv[k] = Ts[ochunk * 8 + k][orow];
    *(bf16x8*)(dst + (size_t)(c0 + orow) * R + r0 + ochunk * 8) = vv;
  }
}

// ---------------- bf16 MFMA GEMM: C[M,N] = A[M,K] @ BT[N,K]^T + bias ----------------
// 128x128 tile, BK=32, 256 threads (4 waves, 2x2), acc 4x4 16x16 fragments per wave.
// Staging via global_load_lds width=16 (m97 structure, linear LDS).
// bias_row: bias indexed by output row (for the vT = WvT @ y^T GEMM), else by col.
__global__ __launch_bounds__(256) void gemm_bt(
    const short* __restrict__ A, const short* __restrict__ BT,
    const float* __restrict__ bias, short* __restrict__ Cb,
    int M, int N, int K, int relu, int bias_row)
{
  __shared__ __align__(16) short As[128][32];
  __shared__ __align__(16) short Bs[128][32];
  const int t = threadIdx.x;
  const int bcol = blockIdx.x, brow = blockIdx.y;
  const int w = t >> 6, lane = t & 63, lr = lane & 15, lk = lane >> 4;
  const int wrow = w >> 1, wcol = w & 1;

  const f32x4 vzero = {0.f, 0.f, 0.f, 0.f};
  f32x4 acc[4][4];
#pragma unroll
  for (int m = 0; m < 4; ++m)
#pragma unroll
    for (int n = 0; n < 4; ++n) acc[m][n] = vzero;

  const short* Abase = A + (size_t)brow * 128 * K;
  const short* Bbase = BT + (size_t)bcol * 128 * K;
  char* AsF = (char*)&As[0][0];
  char* BsF = (char*)&Bs[0][0];

  for (int k0 = 0; k0 < K; k0 += 32) {
    __syncthreads();
#pragma unroll
    for (int it = 0; it < 2; ++it) {
      int cb = it * 256 + w * 64;          // wave-uniform chunk base (chunk = 16B)
      int c = cb + lane;
      int row = c >> 2, seg = c & 3;       // 4 chunks of 16B per 64B row
      gl_lds16(Abase + (size_t)row * K + k0 + seg * 8, AsF + (size_t)cb * 16);
      gl_lds16(Bbase + (size_t)row * K + k0 + seg * 8, BsF + (size_t)cb * 16);
    }
    __syncthreads();

    bf16x8 af[4], bf[4];
#pragma unroll
    for (int m = 0; m < 4; ++m) af[m] = *(const bf16x8*)&As[wrow * 64 + m * 16 + lr][lk * 8];
#pragma unroll
    for (int n = 0; n < 4; ++n) bf[n] = *(const bf16x8*)&Bs[wcol * 64 + n * 16 + lr][lk * 8];
#pragma unroll
    for (int m = 0; m < 4; ++m)
#pragma unroll
      for (int n = 0; n < 4; ++n)
        acc[m][n] = __builtin_amdgcn_mfma_f32_16x16x32_bf16(af[m], bf[n], acc[m][n], 0, 0, 0);
  }

#pragma unroll
  for (int m = 0; m < 4; ++m)
#pragma unroll
    for (int n = 0; n < 4; ++n) {
      int col = bcol * 128 + wcol * 64 + n * 16 + lr;
      float bcv = (bias && !bias_row) ? bias[col] : 0.f;
#pragma unroll
      for (int j = 0; j < 4; ++j) {
        int row = brow * 128 + wrow * 64 + m * 16 + lk * 4 + j;
        float vv = acc[m][n][j] + ((bias && bias_row) ? bias[row] : bcv);
        if (relu) vv = fmaxf(vv, 0.f);
        Cb[(size_t)row * N + col] = f2bf(vv);
      }
    }
}

// ---------------- fused attention (round-2 structure + causal skip + vector V) ------
// grid (S/32, H, B), 256 threads (4 waves). Block owns 32 q-rows of one head.
// Causal key range [0, q0+32); 16-key fragments distributed round-robin to waves.
// vT layout: [D][B*S] (row d, element b*S+s).
__global__ __launch_bounds__(256) void attn_kernel(
    const short* __restrict__ qk, const short* __restrict__ vT,
    const float* __restrict__ fr, short* __restrict__ out)
{
  const int qb = blockIdx.x, h = blockIdx.y, b = blockIdx.z;
  const int t = threadIdx.x;
  const int w = t >> 6, lane = t & 63, lr = lane & 15, lk = lane >> 4;
  const int q0 = qb * 32;
  const int nkt = (q0 + 32) >> 4;   // # active 16-key fragments (2..32)
  const int nkb = qb + 1;           // # 32-key PV blocks

  __shared__ short P[32][520];
  __shared__ float redmax[32][4];
  __shared__ float redsum[32][4];

  const size_t qk_head = (size_t)b * S_ * D_ + (size_t)h * DK_;
  const float NEGBIG = -3.0e38f;
  const float scale = 0.125f;   // 1/sqrt(64)

  // Q fragments: rows q0 + qt*16 + lr, dk slice ks*32 + lk*8
  bf16x8 qf[2][2];
#pragma unroll
  for (int qt = 0; qt < 2; ++qt)
#pragma unroll
    for (int ks = 0; ks < 2; ++ks)
      qf[qt][ks] = *(const bf16x8*)(qk + qk_head + (size_t)(q0 + qt * 16 + lr) * D_ + ks * 32 + lk * 8);

  const f32x4 vzero = {0.f, 0.f, 0.f, 0.f};
  f32x4 acc[2][8];
#pragma unroll
  for (int qt = 0; qt < 2; ++qt)
#pragma unroll
    for (int i = 0; i < 8; ++i) acc[qt][i] = vzero;

  // QK^T: wave w computes fragments kt = w, w+4, w+8, ...
#pragma unroll
  for (int i = 0; i < 8; ++i) {
    int kt = w + i * 4;
    if (kt < nkt) {
#pragma unroll
      for (int ks = 0; ks < 2; ++ks) {
        bf16x8 kf = *(const bf16x8*)(qk + qk_head + (size_t)(kt * 16 + lr) * D_ + ks * 32 + lk * 8);
        acc[0][i] = __builtin_amdgcn_mfma_f32_16x16x32_bf16(qf[0][ks], kf, acc[0][i], 0, 0, 0);
        acc[1][i] = __builtin_amdgcn_mfma_f32_16x16x32_bf16(qf[1][ks], kf, acc[1][i], 0, 0, 0);
      }
    }
  }

  float frv[2][4], rmax[2][4], rsum[2][4];
#pragma unroll
  for (int qt = 0; qt < 2; ++qt)
#pragma unroll
    for (int j = 0; j < 4; ++j) {
      frv[qt][j] = scale * fr[(size_t)b * S_ + q0 + qt * 16 + lk * 4 + j];
      rmax[qt][j] = NEGBIG;
      rsum[qt][j] = 0.f;
    }

  // pass 1: masked row max over this wave's fragments
#pragma unroll
  for (int i = 0; i < 8; ++i) {
    int kt = w + i * 4;
    if (kt < nkt) {
      int kcol = kt * 16 + lr;
#pragma unroll
      for (int qt = 0; qt < 2; ++qt)
#pragma unroll
        for (int j = 0; j < 4; ++j) {
          int qrow = q0 + qt * 16 + lk * 4 + j;
          if (kcol < qrow) rmax[qt][j] = fmaxf(rmax[qt][j], acc[qt][i][j] * frv[qt][j]);
        }
    }
  }
#pragma unroll
  for (int msk = 1; msk < 16; msk <<= 1)
#pragma unroll
    for (int qt = 0; qt < 2; ++qt)
#pragma unroll
      for (int j = 0; j < 4; ++j)
        rmax[qt][j] = fmaxf(rmax[qt][j], __shfl_xor(rmax[qt][j], msk));
  if (lr == 0) {
#pragma unroll
    for (int qt = 0; qt < 2; ++qt)
#pragma unroll
      for (int j = 0; j < 4; ++j) redmax[qt * 16 + lk * 4 + j][w] = rmax[qt][j];
  }
  __syncthreads();
#pragma unroll
  for (int qt = 0; qt < 2; ++qt)
#pragma unroll
    for (int j = 0; j < 4; ++j) {
      int row = qt * 16 + lk * 4 + j;
      rmax[qt][j] = fmaxf(fmaxf(redmax[row][0], redmax[row][1]),
                          fmaxf(redmax[row][2], redmax[row][3]));
    }

  // pass 2: exp (unnormalized), row sums, write P (bf16) to LDS
#pragma unroll
  for (int i = 0; i < 8; ++i) {
    int kt = w + i * 4;
    if (kt < nkt) {
      int kcol = kt * 16 + lr;
#pragma unroll
      for (int qt = 0; qt < 2; ++qt)
#pragma unroll
        for (int j = 0; j < 4; ++j) {
          int qrow = q0 + qt * 16 + lk * 4 + j;
          float e = 0.f;
          if (kcol < qrow) e = __expf(acc[qt][i][j] * frv[qt][j] - rmax[qt][j]);
          rsum[qt][j] += e;
          P[qt * 16 + lk * 4 + j][kcol] = f2bf(e);
        }
    }
  }
#pragma unroll
  for (int msk = 1; msk < 16; msk <<= 1)
#pragma unroll
    for (int qt = 0; qt < 2; ++qt)
#pragma unroll
      for (int j = 0; j < 4; ++j) rsum[qt][j] += __shfl_xor(rsum[qt][j], msk);
  if (lr == 0) {
#pragma unroll
    for (int qt = 0; qt < 2; ++qt)
#pragma unroll
      for (int j = 0; j < 4; ++j) redsum[qt * 16 + lk * 4 + j][w] = rsum[qt][j];
  }
  __syncthreads();   // P fully written + redsum ready

  // PV: wave w -> q-half (w>>1), dk-half (w&1); output [16 q x 32 dk]
  const int qhalf = w >> 1, dhalf = w & 1;
  float invd[4];
#pragma unroll
  for (int j = 0; j < 4; ++j) {
    int row = qhalf * 16 + lk * 4 + j;
    float dsum = redsum[row][0] + redsum[row][1] + redsum[row][2] + redsum[row][3];
    invd[j] = dsum > 0.f ? 1.f / dsum : 0.f;   // row 0 -> 0 (zero_pad)
  }

  f32x4 oacc[2] = {vzero, vzero};
  for (int kb = 0; kb < nkb; ++kb) {
    bf16x8 pa = *(const bf16x8*)&P[qhalf * 16 + lr][kb * 32 + lk * 8];
#pragma unroll
    for (int n = 0; n < 2; ++n) {
      bf16x8 vf = *(const bf16x8*)(vT + (size_t)(h * DK_ + dhalf * 32 + n * 16 + lr) * BS_
                                      + (size_t)b * S_ + kb * 32 + lk * 8);
      oacc[n] = __builtin_amdgcn_mfma_f32_16x16x32_bf16(pa, vf, oacc[n], 0, 0, 0);
    }
  }

#pragma unroll
  for (int n = 0; n < 2; ++n)
#pragma unroll
    for (int j = 0; j < 4; ++j) {
      int qrow = q0 + qhalf * 16 + lk * 4 + j;
      out[qk_head + (size_t)qrow * D_ + dhalf * 32 + n * 16 + lr] = f2bf(oacc[n][j] * invd[j]);
    }
}

// ---------------- fused residual + LayerNorm ----------------
__global__ __launch_bounds__(256) void ln_res(
    const float* __restrict__ xin, const short* __restrict__ add,
    const float* __restrict__ g, const float* __restrict__ bb,
    float* __restrict__ xout, short* __restrict__ xbout)
{
  const int row = blockIdx.x * 4 + (threadIdx.x >> 6);
  const int lane = threadIdx.x & 63;
  const size_t base = (size_t)row * D_ + lane * 8;

  f32x4 a0 = *(const f32x4*)(xin + base);
  f32x4 a1 = *(const f32x4*)(xin + base + 4);
  bf16x8 av = *(const bf16x8*)(add + base);
  float vals[8];
#pragma unroll
  for (int i = 0; i < 4; ++i) vals[i] = a0[i] + bf2f(av[i]);
#pragma unroll
  for (int i = 0; i < 4; ++i) vals[4 + i] = a1[i] + bf2f(av[4 + i]);

  float s = 0.f, sq = 0.f;
#pragma unroll
  for (int i = 0; i < 8; ++i) { s += vals[i]; sq += vals[i] * vals[i]; }
#pragma unroll
  for (int m = 1; m < 64; m <<= 1) { s += __shfl_xor(s, m); sq += __shfl_xor(sq, m); }

  float mean = s * (1.f / D_);
  float var = sq * (1.f / D_) - mean * mean;
  float rstd = rsqrtf(var + 1e-5f);

  int col = lane * 8;
  f32x4 o0, o1; bf16x8 ob;
#pragma unroll
  for (int i = 0; i < 8; ++i) {
    float vv = g[col + i] * (vals[i] - mean) * rstd + bb[col + i];
    if (i < 4) o0[i] = vv; else o1[i - 4] = vv;
    ob[i] = f2bf(vv);
  }
  *(f32x4*)(xout + base) = o0;
  *(f32x4*)(xout + base + 4) = o1;
  *(bf16x8*)(xbout + base) = ob;
}

// ---------------- host ----------------
extern "C" void kernel_launch(void* const* d_in, const int* in_sizes, int n_in,
                              void* d_out, int out_size, void* d_ws, size_t ws_size,
                              hipStream_t stream) {
  const float* q_emb = (const float*)d_in[0];
  const float* qa_emb = (const float*)d_in[1];
  const float* frate = (const float*)d_in[2];
  const float* Wk = (const float*)d_in[3];
  const float* bk = (const float*)d_in[4];
  const float* Wv = (const float*)d_in[5];
  const float* bv = (const float*)d_in[6];
  const float* Wo = (const float*)d_in[7];
  const float* bo = (const float*)d_in[8];
  const float* ln1g = (const float*)d_in[9];
  const float* ln1b = (const float*)d_in[10];
  const float* W1 = (const float*)d_in[11];
  const float* b1 = (const float*)d_in[12];
  const float* W2 = (const float*)d_in[13];
  const float* b2 = (const float*)d_in[14];
  const float* ln2g = (const float*)d_in[15];
  const float* ln2b = (const float*)d_in[16];
  float* x = (float*)d_out;

  char* ws = (char*)d_ws;
  size_t off = 0;
  auto alloc = [&](size_t bytes) -> void* {
    void* p = ws + off;
    off += (bytes + 255) & ~(size_t)255;
    return p;
  };
  const size_t MTOK = (size_t)BS_;   // 32768 rows
  float* pe    = (float*)alloc((size_t)S_ * D_ * 4);
  short* xb    = (short*)alloc(MTOK * D_ * 2);
  short* yb    = (short*)alloc(MTOK * D_ * 2);
  short* qkb   = (short*)alloc(MTOK * D_ * 2);
  short* vTb   = (short*)alloc(MTOK * D_ * 2);   // V transposed: [D][B*S]
  short* ff1b  = (short*)alloc(MTOK * DFF_ * 2);
  // lifetime-based aliases:
  //   attnb (attn->WoGEMM) aliases ff1b (ff1GEMM->ff2GEMM) -- disjoint within a layer
  //   goutb (WoGEMM/ff2GEMM -> ln_res) aliases qkb (dead after attn_kernel)
  short* attnb = ff1b;
  short* goutb = qkb;
  short* wT[L_][5];
  for (int i = 0; i < L_; ++i) {
    wT[i][0] = (short*)alloc((size_t)D_ * D_ * 2);     // WkT [D][D]
    wT[i][1] = (short*)alloc((size_t)D_ * D_ * 2);     // WvT
    wT[i][2] = (short*)alloc((size_t)D_ * D_ * 2);     // WoT
    wT[i][3] = (short*)alloc((size_t)D_ * DFF_ * 2);   // W1T [DFF][D]
    wT[i][4] = (short*)alloc((size_t)DFF_ * D_ * 2);   // W2T [D][DFF]
  }
  if (off > ws_size) {
    fprintf(stderr, "parKT: workspace overflow: need %zu have %zu\n", off, ws_size);
    return;
  }

  pe_kernel<<<(S_ * D_) / 256, 256, 0, stream>>>(pe);
  prep_kernel<<<(int)(MTOK * D_ / 256), 256, 0, stream>>>(q_emb, qa_emb, pe, x, xb, yb);

  for (int i = 0; i < L_; ++i) {
    tr_w<<<dim3(D_ / 64, D_ / 64), 256, 0, stream>>>(Wk + (size_t)i * D_ * D_, wT[i][0], D_, D_);
    tr_w<<<dim3(D_ / 64, D_ / 64), 256, 0, stream>>>(Wv + (size_t)i * D_ * D_, wT[i][1], D_, D_);
    tr_w<<<dim3(D_ / 64, D_ / 64), 256, 0, stream>>>(Wo + (size_t)i * D_ * D_, wT[i][2], D_, D_);
    tr_w<<<dim3(DFF_ / 64, D_ / 64), 256, 0, stream>>>(W1 + (size_t)i * D_ * DFF_, wT[i][3], D_, DFF_);
    tr_w<<<dim3(D_ / 64, DFF_ / 64), 256, 0, stream>>>(W2 + (size_t)i * DFF_ * D_, wT[i][4], DFF_, D_);
  }

  const int M = (int)MTOK;
  for (int i = 0; i < L_; ++i) {
    // qk = x @ Wk + bk  (M x D)
    gemm_bt<<<dim3(D_ / 128, M / 128), 256, 0, stream>>>(xb, wT[i][0], bk + (size_t)i * D_, qkb, M, D_, D_, 0, 0);
    // vT = WvT @ y^T + bv (bias per row): [D][B*S]
    gemm_bt<<<dim3(M / 128, D_ / 128), 256, 0, stream>>>(wT[i][1], yb, bv + (size_t)i * D_, vTb, D_, M, D_, 0, 1);
    attn_kernel<<<dim3(S_ / 32, H_, B_), 256, 0, stream>>>(qkb, vTb, frate, attnb);
    gemm_bt<<<dim3(D_ / 128, M / 128), 256, 0, stream>>>(attnb, wT[i][2], bo + (size_t)i * D_, goutb, M, D_, D_, 0, 0);
    ln_res<<<M / 4, 256, 0, stream>>>(x, goutb, ln1g + (size_t)i * D_, ln1b + (size_t)i * D_, x, xb);
    gemm_bt<<<dim3(DFF_ / 128, M / 128), 256, 0, stream>>>(xb, wT[i][3], b1 + (size_t)i * DFF_, ff1b, M, DFF_, D_, 1, 0);
    gemm_bt<<<dim3(D_ / 128, M / 128), 256, 0, stream>>>(ff1b, wT[i][4], b2 + (size_t)i * D_, goutb, M, D_, DFF_, 0, 0);
    ln_res<<<M / 4, 256, 0, stream>>>(x, goutb, ln2g + (size_t)i * D_, ln2b + (size_t)i * D_, x, xb);
  }
}

// Round 5
// 1118.498 us; speedup vs baseline: 1.1246x; 1.0928x over previous
//
#include <hip/hip_runtime.h>
#include <cstdio>

#define B_   64
#define S_   512
#define D_   512
#define H_   8
#define DK_  64
#define DFF_ 1024
#define L_   2
#define BS_  (B_ * S_)   // 32768

typedef __attribute__((ext_vector_type(8))) short bf16x8;
typedef __attribute__((ext_vector_type(4))) float f32x4;

__device__ inline short f2bf(float f) {
  unsigned u = __float_as_uint(f);
  u = u + 0x7FFF + ((u >> 16) & 1);
  return (short)(u >> 16);
}
__device__ inline float bf2f(short s) {
  return __uint_as_float(((unsigned)(unsigned short)s) << 16);
}

// async global->LDS, 16B per lane; lds dest = wave-uniform base + lane*16
__device__ inline void gl_lds16(const short* g, void* lds_base) {
  __builtin_amdgcn_global_load_lds(
      (const __attribute__((address_space(1))) void*)g,
      (__attribute__((address_space(3))) void*)lds_base, 16, 0, 0);
}

// ---------------- positional encoding table ----------------
__global__ void pe_kernel(float* __restrict__ pe) {
  int idx = blockIdx.x * 256 + threadIdx.x;      // S_*D_ threads
  int s = idx >> 9, d = idx & 511;
  float dv = __expf((float)(d & ~1) * (-9.210340371976184f / (float)D_));
  float ang = (float)s * dv;
  pe[idx] = (d & 1) ? cosf(ang) : sinf(ang);
}

// x = q + pe (f32 master + bf16 mirror); yb = bf16(qa + pe)
__global__ void prep_kernel(const float* __restrict__ q, const float* __restrict__ qa,
                            const float* __restrict__ pe, float* __restrict__ x,
                            short* __restrict__ xb, short* __restrict__ yb) {
  size_t idx = (size_t)blockIdx.x * 256 + threadIdx.x;
  int sd = (int)(idx & (size_t)(S_ * D_ - 1));
  float p = pe[sd];
  float xv = q[idx] + p;
  x[idx] = xv;
  xb[idx] = f2bf(xv);
  yb[idx] = f2bf(qa[idx] + p);
}

// ---------------- tiled weight transpose: dst[c][r] = bf16(src[r][c]) ----------------
__global__ __launch_bounds__(256) void tr_w(const float* __restrict__ src,
                                            short* __restrict__ dst, int R, int C) {
  __shared__ short Ts[64][72];
  const int t = threadIdx.x;
  const int c0 = blockIdx.x * 64, r0 = blockIdx.y * 64;
#pragma unroll
  for (int it = 0; it < 2; ++it) {
    int c2 = it * 256 + t;
    int srow = c2 >> 3, schunk = c2 & 7;
    const float* sp = src + (size_t)(r0 + srow) * C + c0 + schunk * 8;
    f32x4 a0 = *(const f32x4*)sp;
    f32x4 a1 = *(const f32x4*)(sp + 4);
#pragma unroll
    for (int k = 0; k < 4; ++k) Ts[srow][schunk * 8 + k] = f2bf(a0[k]);
#pragma unroll
    for (int k = 0; k < 4; ++k) Ts[srow][schunk * 8 + 4 + k] = f2bf(a1[k]);
  }
  __syncthreads();
#pragma unroll
  for (int it = 0; it < 2; ++it) {
    int c2 = it * 256 + t;
    int orow = c2 >> 3, ochunk = c2 & 7;
    bf16x8 vv;
#pragma unroll
    for (int k = 0; k < 8; ++k) vv[k] = Ts[ochunk * 8 + k][orow];
    *(bf16x8*)(dst + (size_t)(c0 + orow) * R + r0 + ochunk * 8) = vv;
  }
}

// ---------------- bf16 MFMA GEMM: C[M,N] = A[M,K] @ BT[N,K]^T + bias ----------------
__global__ __launch_bounds__(256) void gemm_bt(
    const short* __restrict__ A, const short* __restrict__ BT,
    const float* __restrict__ bias, short* __restrict__ Cb,
    int M, int N, int K, int relu, int bias_row)
{
  __shared__ __align__(16) short As[128][32];
  __shared__ __align__(16) short Bs[128][32];
  const int t = threadIdx.x;
  const int bcol = blockIdx.x, brow = blockIdx.y;
  const int w = t >> 6, lane = t & 63, lr = lane & 15, lk = lane >> 4;
  const int wrow = w >> 1, wcol = w & 1;

  const f32x4 vzero = {0.f, 0.f, 0.f, 0.f};
  f32x4 acc[4][4];
#pragma unroll
  for (int m = 0; m < 4; ++m)
#pragma unroll
    for (int n = 0; n < 4; ++n) acc[m][n] = vzero;

  const short* Abase = A + (size_t)brow * 128 * K;
  const short* Bbase = BT + (size_t)bcol * 128 * K;
  char* AsF = (char*)&As[0][0];
  char* BsF = (char*)&Bs[0][0];

  for (int k0 = 0; k0 < K; k0 += 32) {
    __syncthreads();
#pragma unroll
    for (int it = 0; it < 2; ++it) {
      int cb = it * 256 + w * 64;          // wave-uniform chunk base (chunk = 16B)
      int c = cb + lane;
      int row = c >> 2, seg = c & 3;
      gl_lds16(Abase + (size_t)row * K + k0 + seg * 8, AsF + (size_t)cb * 16);
      gl_lds16(Bbase + (size_t)row * K + k0 + seg * 8, BsF + (size_t)cb * 16);
    }
    __syncthreads();

    bf16x8 af[4], bf[4];
#pragma unroll
    for (int m = 0; m < 4; ++m) af[m] = *(const bf16x8*)&As[wrow * 64 + m * 16 + lr][lk * 8];
#pragma unroll
    for (int n = 0; n < 4; ++n) bf[n] = *(const bf16x8*)&Bs[wcol * 64 + n * 16 + lr][lk * 8];
#pragma unroll
    for (int m = 0; m < 4; ++m)
#pragma unroll
      for (int n = 0; n < 4; ++n)
        acc[m][n] = __builtin_amdgcn_mfma_f32_16x16x32_bf16(af[m], bf[n], acc[m][n], 0, 0, 0);
  }

#pragma unroll
  for (int m = 0; m < 4; ++m)
#pragma unroll
    for (int n = 0; n < 4; ++n) {
      int col = bcol * 128 + wcol * 64 + n * 16 + lr;
      float bcv = (bias && !bias_row) ? bias[col] : 0.f;
#pragma unroll
      for (int j = 0; j < 4; ++j) {
        int row = brow * 128 + wrow * 64 + m * 16 + lk * 4 + j;
        float vv = acc[m][n][j] + ((bias && bias_row) ? bias[row] : bcv);
        if (relu) vv = fmaxf(vv, 0.f);
        Cb[(size_t)row * N + col] = f2bf(vv);
      }
    }
}

// ---------------- fused attention: balanced-pair causal ----------------
// grid (S/64, H, B): block p handles q-tiles p (rows [32p,32p+32)) and 15-p.
// Combined causal key work = 17 key-blocks of 32 -- constant per block.
// QK^T: 34 16-key fragments round-robined over 4 waves (static 9-iter loop).
// Softmax: phase-split full-row (cross-wave LDS reduce), P in LDS (tiles share
// rows, disjoint column ranges: tile1 cols offset by c0*16).
// PV: each wave = one tile0 unit + one tile1 unit (16 rows x 32 dk) -> 34 MFMA/wave.
__global__ __launch_bounds__(256) void attn_kernel(
    const short* __restrict__ qk, const short* __restrict__ vT,
    const float* __restrict__ fr, short* __restrict__ out)
{
  const int p = blockIdx.x, h = blockIdx.y, b = blockIdx.z;
  const int t = threadIdx.x;
  const int w = t >> 6, lane = t & 63, lr = lane & 15, lk = lane >> 4;

  const int qo[2] = {32 * p, 32 * (15 - p)};
  const int c0 = 2 * p + 2;          // tile0 fragment count
  const int colb1 = c0 * 16;         // tile1 P column offset (= 32p+32)

  __shared__ short P[32][552];
  __shared__ float redmax[2][32][4];
  __shared__ float redsum[2][32][4];

  const size_t qk_head = (size_t)b * S_ * D_ + (size_t)h * DK_;
  const float NEGBIG = -3.0e38f;
  const float scale = 0.125f;   // 1/sqrt(64)

  // Q fragments for both tiles
  bf16x8 qf[2][2][2];   // [tile][qt][ks]
#pragma unroll
  for (int tl = 0; tl < 2; ++tl)
#pragma unroll
    for (int qt = 0; qt < 2; ++qt)
#pragma unroll
      for (int ks = 0; ks < 2; ++ks)
        qf[tl][qt][ks] = *(const bf16x8*)(qk + qk_head +
            (size_t)(qo[tl] + qt * 16 + lr) * D_ + ks * 32 + lk * 8);

  float frv[2][2][4];
#pragma unroll
  for (int tl = 0; tl < 2; ++tl)
#pragma unroll
    for (int qt = 0; qt < 2; ++qt)
#pragma unroll
      for (int j = 0; j < 4; ++j)
        frv[tl][qt][j] = scale * fr[(size_t)b * S_ + qo[tl] + qt * 16 + lk * 4 + j];

  const f32x4 vzero = {0.f, 0.f, 0.f, 0.f};
  f32x4 acc[9][2];
#pragma unroll
  for (int i = 0; i < 9; ++i) { acc[i][0] = vzero; acc[i][1] = vzero; }

  // ---- QK^T: fragment f = w + 4i; f<c0 -> tile0 kt=f, else tile1 kt=f-c0
#pragma unroll
  for (int i = 0; i < 9; ++i) {
    int f = w + 4 * i;
    if (f < 34) {
      int tl = (f < c0) ? 0 : 1;
      int kt = (f < c0) ? f : f - c0;
#pragma unroll
      for (int ks = 0; ks < 2; ++ks) {
        bf16x8 kf = *(const bf16x8*)(qk + qk_head + (size_t)(kt * 16 + lr) * D_ + ks * 32 + lk * 8);
        acc[i][0] = __builtin_amdgcn_mfma_f32_16x16x32_bf16(qf[tl][0][ks], kf, acc[i][0], 0, 0, 0);
        acc[i][1] = __builtin_amdgcn_mfma_f32_16x16x32_bf16(qf[tl][1][ks], kf, acc[i][1], 0, 0, 0);
      }
    }
  }

  // ---- pass 1: scale+mask in place, partial row max
  float rmax[2][2][4], rsum[2][2][4];
#pragma unroll
  for (int tl = 0; tl < 2; ++tl)
#pragma unroll
    for (int qt = 0; qt < 2; ++qt)
#pragma unroll
      for (int j = 0; j < 4; ++j) { rmax[tl][qt][j] = NEGBIG; rsum[tl][qt][j] = 0.f; }

#pragma unroll
  for (int i = 0; i < 9; ++i) {
    int f = w + 4 * i;
    if (f < 34) {
      int tl = (f < c0) ? 0 : 1;
      int kt = (f < c0) ? f : f - c0;
      int kcol = kt * 16 + lr;
#pragma unroll
      for (int qt = 0; qt < 2; ++qt)
#pragma unroll
        for (int j = 0; j < 4; ++j) {
          int qrow = qo[tl] + qt * 16 + lk * 4 + j;
          float sc = (kcol < qrow) ? acc[i][qt][j] * frv[tl][qt][j] : NEGBIG;
          acc[i][qt][j] = sc;
          rmax[tl][qt][j] = fmaxf(rmax[tl][qt][j], sc);
        }
    }
  }
#pragma unroll
  for (int msk = 1; msk < 16; msk <<= 1)
#pragma unroll
    for (int tl = 0; tl < 2; ++tl)
#pragma unroll
      for (int qt = 0; qt < 2; ++qt)
#pragma unroll
        for (int j = 0; j < 4; ++j)
          rmax[tl][qt][j] = fmaxf(rmax[tl][qt][j], __shfl_xor(rmax[tl][qt][j], msk));
  if (lr == 0) {
#pragma unroll
    for (int tl = 0; tl < 2; ++tl)
#pragma unroll
      for (int qt = 0; qt < 2; ++qt)
#pragma unroll
        for (int j = 0; j < 4; ++j) redmax[tl][qt * 16 + lk * 4 + j][w] = rmax[tl][qt][j];
  }
  __syncthreads();
  float rmaxf[2][2][4];
#pragma unroll
  for (int tl = 0; tl < 2; ++tl)
#pragma unroll
    for (int qt = 0; qt < 2; ++qt)
#pragma unroll
      for (int j = 0; j < 4; ++j) {
        int row = qt * 16 + lk * 4 + j;
        rmaxf[tl][qt][j] = fmaxf(fmaxf(redmax[tl][row][0], redmax[tl][row][1]),
                                 fmaxf(redmax[tl][row][2], redmax[tl][row][3]));
      }

  // ---- pass 2: exp, partial sums, write P
#pragma unroll
  for (int i = 0; i < 9; ++i) {
    int f = w + 4 * i;
    if (f < 34) {
      int tl = (f < c0) ? 0 : 1;
      int kt = (f < c0) ? f : f - c0;
      int colbase = (tl ? colb1 : 0) + kt * 16 + lr;
#pragma unroll
      for (int qt = 0; qt < 2; ++qt)
#pragma unroll
        for (int j = 0; j < 4; ++j) {
          float a = acc[i][qt][j];
          float e = (a > -1.0e37f) ? __expf(a - rmaxf[tl][qt][j]) : 0.f;
          rsum[tl][qt][j] += e;
          P[qt * 16 + lk * 4 + j][colbase] = f2bf(e);
        }
    }
  }
#pragma unroll
  for (int msk = 1; msk < 16; msk <<= 1)
#pragma unroll
    for (int tl = 0; tl < 2; ++tl)
#pragma unroll
      for (int qt = 0; qt < 2; ++qt)
#pragma unroll
        for (int j = 0; j < 4; ++j) rsum[tl][qt][j] += __shfl_xor(rsum[tl][qt][j], msk);
  if (lr == 0) {
#pragma unroll
    for (int tl = 0; tl < 2; ++tl)
#pragma unroll
      for (int qt = 0; qt < 2; ++qt)
#pragma unroll
        for (int j = 0; j < 4; ++j) redsum[tl][qt * 16 + lk * 4 + j][w] = rsum[tl][qt][j];
  }
  __syncthreads();   // P + redsum ready

  // ---- PV: wave w -> unit0 (tl=0, qt=w&1, dh=w>>1), unit1 (tl=1, qt=w>>1, dh=w&1)
  const int uqt[2] = {w & 1, w >> 1};
  const int udh[2] = {w >> 1, w & 1};
  const int unkb[2] = {p + 1, 16 - p};
  f32x4 oacc[2][2];
#pragma unroll
  for (int u = 0; u < 2; ++u) { oacc[u][0] = vzero; oacc[u][1] = vzero; }

#pragma unroll
  for (int kb = 0; kb < 16; ++kb) {
#pragma unroll
    for (int u = 0; u < 2; ++u) {
      if (kb < unkb[u]) {
        int qt = uqt[u], dh = udh[u];
        int colbase = (u ? colb1 : 0) + kb * 32 + lk * 8;
        bf16x8 pa = *(const bf16x8*)&P[qt * 16 + lr][colbase];
#pragma unroll
        for (int n = 0; n < 2; ++n) {
          bf16x8 vf = *(const bf16x8*)(vT + (size_t)(h * DK_ + dh * 32 + n * 16 + lr) * BS_
                                          + (size_t)b * S_ + kb * 32 + lk * 8);
          oacc[u][n] = __builtin_amdgcn_mfma_f32_16x16x32_bf16(pa, vf, oacc[u][n], 0, 0, 0);
        }
      }
    }
  }

#pragma unroll
  for (int u = 0; u < 2; ++u) {
    int qt = uqt[u], dh = udh[u];
    float invd[4];
#pragma unroll
    for (int j = 0; j < 4; ++j) {
      int row = qt * 16 + lk * 4 + j;
      float dsum = redsum[u][row][0] + redsum[u][row][1] + redsum[u][row][2] + redsum[u][row][3];
      invd[j] = dsum > 0.f ? 1.f / dsum : 0.f;   // row 0 -> 0 (zero_pad)
    }
#pragma unroll
    for (int n = 0; n < 2; ++n)
#pragma unroll
      for (int j = 0; j < 4; ++j) {
        int qrow = qo[u] + qt * 16 + lk * 4 + j;
        out[qk_head + (size_t)qrow * D_ + dh * 32 + n * 16 + lr] = f2bf(oacc[u][n][j] * invd[j]);
      }
  }
}

// ---------------- fused residual + LayerNorm ----------------
__global__ __launch_bounds__(256) void ln_res(
    const float* __restrict__ xin, const short* __restrict__ add,
    const float* __restrict__ g, const float* __restrict__ bb,
    float* __restrict__ xout, short* __restrict__ xbout)
{
  const int row = blockIdx.x * 4 + (threadIdx.x >> 6);
  const int lane = threadIdx.x & 63;
  const size_t base = (size_t)row * D_ + lane * 8;

  f32x4 a0 = *(const f32x4*)(xin + base);
  f32x4 a1 = *(const f32x4*)(xin + base + 4);
  bf16x8 av = *(const bf16x8*)(add + base);
  float vals[8];
#pragma unroll
  for (int i = 0; i < 4; ++i) vals[i] = a0[i] + bf2f(av[i]);
#pragma unroll
  for (int i = 0; i < 4; ++i) vals[4 + i] = a1[i] + bf2f(av[4 + i]);

  float s = 0.f, sq = 0.f;
#pragma unroll
  for (int i = 0; i < 8; ++i) { s += vals[i]; sq += vals[i] * vals[i]; }
#pragma unroll
  for (int m = 1; m < 64; m <<= 1) { s += __shfl_xor(s, m); sq += __shfl_xor(sq, m); }

  float mean = s * (1.f / D_);
  float var = sq * (1.f / D_) - mean * mean;
  float rstd = rsqrtf(var + 1e-5f);

  int col = lane * 8;
  f32x4 o0, o1; bf16x8 ob;
#pragma unroll
  for (int i = 0; i < 8; ++i) {
    float vv = g[col + i] * (vals[i] - mean) * rstd + bb[col + i];
    if (i < 4) o0[i] = vv; else o1[i - 4] = vv;
    ob[i] = f2bf(vv);
  }
  *(f32x4*)(xout + base) = o0;
  *(f32x4*)(xout + base + 4) = o1;
  *(bf16x8*)(xbout + base) = ob;
}

// ---------------- host ----------------
extern "C" void kernel_launch(void* const* d_in, const int* in_sizes, int n_in,
                              void* d_out, int out_size, void* d_ws, size_t ws_size,
                              hipStream_t stream) {
  const float* q_emb = (const float*)d_in[0];
  const float* qa_emb = (const float*)d_in[1];
  const float* frate = (const float*)d_in[2];
  const float* Wk = (const float*)d_in[3];
  const float* bk = (const float*)d_in[4];
  const float* Wv = (const float*)d_in[5];
  const float* bv = (const float*)d_in[6];
  const float* Wo = (const float*)d_in[7];
  const float* bo = (const float*)d_in[8];
  const float* ln1g = (const float*)d_in[9];
  const float* ln1b = (const float*)d_in[10];
  const float* W1 = (const float*)d_in[11];
  const float* b1 = (const float*)d_in[12];
  const float* W2 = (const float*)d_in[13];
  const float* b2 = (const float*)d_in[14];
  const float* ln2g = (const float*)d_in[15];
  const float* ln2b = (const float*)d_in[16];
  float* x = (float*)d_out;

  char* ws = (char*)d_ws;
  size_t off = 0;
  auto alloc = [&](size_t bytes) -> void* {
    void* p = ws + off;
    off += (bytes + 255) & ~(size_t)255;
    return p;
  };
  const size_t MTOK = (size_t)BS_;   // 32768 rows
  float* pe    = (float*)alloc((size_t)S_ * D_ * 4);
  short* xb    = (short*)alloc(MTOK * D_ * 2);
  short* yb    = (short*)alloc(MTOK * D_ * 2);
  short* qkb   = (short*)alloc(MTOK * D_ * 2);
  short* vTb   = (short*)alloc(MTOK * D_ * 2);   // V transposed: [D][B*S]
  short* ff1b  = (short*)alloc(MTOK * DFF_ * 2);
  // lifetime-based aliases:
  //   attnb (attn->WoGEMM) aliases ff1b (ff1GEMM->ff2GEMM) -- disjoint within a layer
  //   goutb (WoGEMM/ff2GEMM -> ln_res) aliases qkb (dead after attn_kernel)
  short* attnb = ff1b;
  short* goutb = qkb;
  short* wT[L_][5];
  for (int i = 0; i < L_; ++i) {
    wT[i][0] = (short*)alloc((size_t)D_ * D_ * 2);     // WkT [D][D]
    wT[i][1] = (short*)alloc((size_t)D_ * D_ * 2);     // WvT
    wT[i][2] = (short*)alloc((size_t)D_ * D_ * 2);     // WoT
    wT[i][3] = (short*)alloc((size_t)D_ * DFF_ * 2);   // W1T [DFF][D]
    wT[i][4] = (short*)alloc((size_t)DFF_ * D_ * 2);   // W2T [D][DFF]
  }
  if (off > ws_size) {
    fprintf(stderr, "parKT: workspace overflow: need %zu have %zu\n", off, ws_size);
    return;
  }

  pe_kernel<<<(S_ * D_) / 256, 256, 0, stream>>>(pe);
  prep_kernel<<<(int)(MTOK * D_ / 256), 256, 0, stream>>>(q_emb, qa_emb, pe, x, xb, yb);

  for (int i = 0; i < L_; ++i) {
    tr_w<<<dim3(D_ / 64, D_ / 64), 256, 0, stream>>>(Wk + (size_t)i * D_ * D_, wT[i][0], D_, D_);
    tr_w<<<dim3(D_ / 64, D_ / 64), 256, 0, stream>>>(Wv + (size_t)i * D_ * D_, wT[i][1], D_, D_);
    tr_w<<<dim3(D_ / 64, D_ / 64), 256, 0, stream>>>(Wo + (size_t)i * D_ * D_, wT[i][2], D_, D_);
    tr_w<<<dim3(DFF_ / 64, D_ / 64), 256, 0, stream>>>(W1 + (size_t)i * D_ * DFF_, wT[i][3], D_, DFF_);
    tr_w<<<dim3(D_ / 64, DFF_ / 64), 256, 0, stream>>>(W2 + (size_t)i * DFF_ * D_, wT[i][4], DFF_, D_);
  }

  const int M = (int)MTOK;
  for (int i = 0; i < L_; ++i) {
    // qk = x @ Wk + bk  (M x D)
    gemm_bt<<<dim3(D_ / 128, M / 128), 256, 0, stream>>>(xb, wT[i][0], bk + (size_t)i * D_, qkb, M, D_, D_, 0, 0);
    // vT = WvT @ y^T + bv (bias per row): [D][B*S]
    gemm_bt<<<dim3(M / 128, D_ / 128), 256, 0, stream>>>(wT[i][1], yb, bv + (size_t)i * D_, vTb, D_, M, D_, 0, 1);
    attn_kernel<<<dim3(S_ / 64, H_, B_), 256, 0, stream>>>(qkb, vTb, frate, attnb);
    gemm_bt<<<dim3(D_ / 128, M / 128), 256, 0, stream>>>(attnb, wT[i][2], bo + (size_t)i * D_, goutb, M, D_, D_, 0, 0);
    ln_res<<<M / 4, 256, 0, stream>>>(x, goutb, ln1g + (size_t)i * D_, ln1b + (size_t)i * D_, x, xb);
    gemm_bt<<<dim3(DFF_ / 128, M / 128), 256, 0, stream>>>(xb, wT[i][3], b1 + (size_t)i * DFF_, ff1b, M, DFF_, D_, 1, 0);
    gemm_bt<<<dim3(D_ / 128, M / 128), 256, 0, stream>>>(ff1b, wT[i][4], b2 + (size_t)i * D_, goutb, M, D_, DFF_, 0, 0);
    ln_res<<<M / 4, 256, 0, stream>>>(x, goutb, ln2g + (size_t)i * D_, ln2b + (size_t)i * D_, x, xb);
  }
}

// Round 6
// 1034.430 us; speedup vs baseline: 1.2159x; 1.0813x over previous
//
#include <hip/hip_runtime.h>
#include <cstdio>

#define B_   64
#define S_   512
#define D_   512
#define H_   8
#define DK_  64
#define DFF_ 1024
#define L_   2
#define BS_  (B_ * S_)   // 32768

typedef __attribute__((ext_vector_type(8))) short bf16x8;
typedef __attribute__((ext_vector_type(4))) short bf16x4;
typedef __attribute__((ext_vector_type(4))) float f32x4;

__device__ inline short f2bf(float f) {
  unsigned u = __float_as_uint(f);
  u = u + 0x7FFF + ((u >> 16) & 1);
  return (short)(u >> 16);
}
__device__ inline float bf2f(short s) {
  return __uint_as_float(((unsigned)(unsigned short)s) << 16);
}

// async global->LDS, 16B per lane; lds dest = wave-uniform base + lane*16
__device__ inline void gl_lds16(const short* g, void* lds_base) {
  __builtin_amdgcn_global_load_lds(
      (const __attribute__((address_space(1))) void*)g,
      (__attribute__((address_space(3))) void*)lds_base, 16, 0, 0);
}

// ---------------- positional encoding table ----------------
__global__ void pe_kernel(float* __restrict__ pe) {
  int idx = blockIdx.x * 256 + threadIdx.x;      // S_*D_ threads
  int s = idx >> 9, d = idx & 511;
  float dv = __expf((float)(d & ~1) * (-9.210340371976184f / (float)D_));
  float ang = (float)s * dv;
  pe[idx] = (d & 1) ? cosf(ang) : sinf(ang);
}

// x = q + pe (f32 master + bf16 mirror); yb = bf16(qa + pe)
__global__ void prep_kernel(const float* __restrict__ q, const float* __restrict__ qa,
                            const float* __restrict__ pe, float* __restrict__ x,
                            short* __restrict__ xb, short* __restrict__ yb) {
  size_t idx = (size_t)blockIdx.x * 256 + threadIdx.x;
  int sd = (int)(idx & (size_t)(S_ * D_ - 1));
  float p = pe[sd];
  float xv = q[idx] + p;
  x[idx] = xv;
  xb[idx] = f2bf(xv);
  yb[idx] = f2bf(qa[idx] + p);
}

// ---------------- tiled weight transpose: dst[c][r] = bf16(src[r][c]) ----------------
__global__ __launch_bounds__(256) void tr_w(const float* __restrict__ src,
                                            short* __restrict__ dst, int R, int C) {
  __shared__ short Ts[64][72];
  const int t = threadIdx.x;
  const int c0 = blockIdx.x * 64, r0 = blockIdx.y * 64;
#pragma unroll
  for (int it = 0; it < 2; ++it) {
    int c2 = it * 256 + t;
    int srow = c2 >> 3, schunk = c2 & 7;
    const float* sp = src + (size_t)(r0 + srow) * C + c0 + schunk * 8;
    f32x4 a0 = *(const f32x4*)sp;
    f32x4 a1 = *(const f32x4*)(sp + 4);
#pragma unroll
    for (int k = 0; k < 4; ++k) Ts[srow][schunk * 8 + k] = f2bf(a0[k]);
#pragma unroll
    for (int k = 0; k < 4; ++k) Ts[srow][schunk * 8 + 4 + k] = f2bf(a1[k]);
  }
  __syncthreads();
#pragma unroll
  for (int it = 0; it < 2; ++it) {
    int c2 = it * 256 + t;
    int orow = c2 >> 3, ochunk = c2 & 7;
    bf16x8 vv;
#pragma unroll
    for (int k = 0; k < 8; ++k) vv[k] = Ts[ochunk * 8 + k][orow];
    *(bf16x8*)(dst + (size_t)(c0 + orow) * R + r0 + ochunk * 8) = vv;
  }
}

// ---------------- bf16 MFMA GEMM: C[M,N] = A[M,K] @ BT[N,K]^T + bias ----------------
// 128x128 tile, BK=32, double-buffered LDS (2-phase: stage next || compute cur).
__global__ __launch_bounds__(256) void gemm_bt(
    const short* __restrict__ A, const short* __restrict__ BT,
    const float* __restrict__ bias, short* __restrict__ Cb,
    int M, int N, int K, int relu, int bias_row)
{
  __shared__ __align__(16) short As[2][128][32];
  __shared__ __align__(16) short Bs[2][128][32];
  const int t = threadIdx.x;
  const int bcol = blockIdx.x, brow = blockIdx.y;
  const int w = t >> 6, lane = t & 63, lr = lane & 15, lk = lane >> 4;
  const int wrow = w >> 1, wcol = w & 1;

  const f32x4 vzero = {0.f, 0.f, 0.f, 0.f};
  f32x4 acc[4][4];
#pragma unroll
  for (int m = 0; m < 4; ++m)
#pragma unroll
    for (int n = 0; n < 4; ++n) acc[m][n] = vzero;

  const short* Abase = A + (size_t)brow * 128 * K;
  const short* Bbase = BT + (size_t)bcol * 128 * K;

  auto stage = [&](int buf, int k0) {
#pragma unroll
    for (int it = 0; it < 2; ++it) {
      int cb = it * 256 + w * 64;          // wave-uniform chunk base (chunk = 16B)
      int c = cb + lane;
      int row = c >> 2, seg = c & 3;       // 4 chunks of 16B per 64B row
      gl_lds16(Abase + (size_t)row * K + k0 + seg * 8, (char*)&As[buf][0][0] + (size_t)cb * 16);
      gl_lds16(Bbase + (size_t)row * K + k0 + seg * 8, (char*)&Bs[buf][0][0] + (size_t)cb * 16);
    }
  };

  stage(0, 0);
  __syncthreads();          // drain vmcnt + barrier: buf0 ready
  int cur = 0;
  for (int k0 = 0; k0 < K; k0 += 32) {
    if (k0 + 32 < K) stage(cur ^ 1, k0 + 32);   // prefetch next tile (issued before compute)

    bf16x8 af[4], bf[4];
#pragma unroll
    for (int m = 0; m < 4; ++m) af[m] = *(const bf16x8*)&As[cur][wrow * 64 + m * 16 + lr][lk * 8];
#pragma unroll
    for (int n = 0; n < 4; ++n) bf[n] = *(const bf16x8*)&Bs[cur][wcol * 64 + n * 16 + lr][lk * 8];
#pragma unroll
    for (int m = 0; m < 4; ++m)
#pragma unroll
      for (int n = 0; n < 4; ++n)
        acc[m][n] = __builtin_amdgcn_mfma_f32_16x16x32_bf16(af[m], bf[n], acc[m][n], 0, 0, 0);

    __syncthreads();        // full drain: next tile landed + everyone done reading cur
    cur ^= 1;
  }

#pragma unroll
  for (int m = 0; m < 4; ++m)
#pragma unroll
    for (int n = 0; n < 4; ++n) {
      int col = bcol * 128 + wcol * 64 + n * 16 + lr;
      float bcv = (bias && !bias_row) ? bias[col] : 0.f;
#pragma unroll
      for (int j = 0; j < 4; ++j) {
        int row = brow * 128 + wrow * 64 + m * 16 + lk * 4 + j;
        float vv = acc[m][n][j] + ((bias && bias_row) ? bias[row] : bcv);
        if (relu) vv = fmaxf(vv, 0.f);
        Cb[(size_t)row * N + col] = f2bf(vv);
      }
    }
}

// ---------------- fused attention: balanced-pair causal, swapped QK^T ----------------
// grid (S/64, H, B): block p handles q-tiles p (rows [32p,32p+32)) and 15-p.
// QK^T computed as mfma(K, Q) -> C[key][q]: lane holds q = lr (fixed), keys lk*4+j.
// No max-subtract (scores bounded ~<40 << 88 overflow limit, f32 exp safe).
// P[q][key] in LDS via packed ds_write_b64. Single barrier. PV as in round 5.
__global__ __launch_bounds__(256) void attn_kernel(
    const short* __restrict__ qk, const short* __restrict__ vT,
    const float* __restrict__ fr, short* __restrict__ out)
{
  const int p = blockIdx.x, h = blockIdx.y, b = blockIdx.z;
  const int t = threadIdx.x;
  const int w = t >> 6, lane = t & 63, lr = lane & 15, lk = lane >> 4;

  const int qo0 = 32 * p, qo1 = 32 * (15 - p);
  const int c0 = 2 * p + 2;          // tile0 fragment count
  const int colb1 = c0 * 16;         // tile1 P column offset

  __shared__ short P[32][552];       // row stride 1104B (16B-aligned for b128)
  __shared__ float redsum[2][32][4];

  const size_t qk_head = (size_t)b * S_ * D_ + (size_t)h * DK_;
  const float scale = 0.125f;   // 1/sqrt(64)

  // Q fragments (used as B operand; same register layout as A-operand load)
  bf16x8 qf0[2][2], qf1[2][2];   // [qt][ks]
#pragma unroll
  for (int qt = 0; qt < 2; ++qt)
#pragma unroll
    for (int ks = 0; ks < 2; ++ks) {
      qf0[qt][ks] = *(const bf16x8*)(qk + qk_head + (size_t)(qo0 + qt * 16 + lr) * D_ + ks * 32 + lk * 8);
      qf1[qt][ks] = *(const bf16x8*)(qk + qk_head + (size_t)(qo1 + qt * 16 + lr) * D_ + ks * 32 + lk * 8);
    }

  // forget_rate * scale: one scalar per lane per (tile, qt)  (q = qo + qt*16 + lr)
  float frv0[2], frv1[2];
#pragma unroll
  for (int qt = 0; qt < 2; ++qt) {
    frv0[qt] = scale * fr[(size_t)b * S_ + qo0 + qt * 16 + lr];
    frv1[qt] = scale * fr[(size_t)b * S_ + qo1 + qt * 16 + lr];
  }

  const f32x4 vzero = {0.f, 0.f, 0.f, 0.f};
  f32x4 acc[9][2];
#pragma unroll
  for (int i = 0; i < 9; ++i) { acc[i][0] = vzero; acc[i][1] = vzero; }

  // ---- QK^T (swapped): fragment f = w + 4i; f<c0 -> tile0 kt=f, else tile1 kt=f-c0.
  // tl is wave-uniform; literal-inlined branches keep all array indices constant.
  auto qkt = [&](int i, int kt, bf16x8 (*qf)[2]) {
#pragma unroll
    for (int ks = 0; ks < 2; ++ks) {
      bf16x8 kf = *(const bf16x8*)(qk + qk_head + (size_t)(kt * 16 + lr) * D_ + ks * 32 + lk * 8);
      acc[i][0] = __builtin_amdgcn_mfma_f32_16x16x32_bf16(kf, qf[0][ks], acc[i][0], 0, 0, 0);
      acc[i][1] = __builtin_amdgcn_mfma_f32_16x16x32_bf16(kf, qf[1][ks], acc[i][1], 0, 0, 0);
    }
  };
#pragma unroll
  for (int i = 0; i < 9; ++i) {
    int f = w + 4 * i;
    if (f < 34) {
      if (f < c0) qkt(i, f, qf0); else qkt(i, f - c0, qf1);
    }
  }

  // ---- exp pass: e = (k < q) ? exp(score*frv) : 0 ; packed b64 P-writes; row sums
  float rs00 = 0.f, rs01 = 0.f, rs10 = 0.f, rs11 = 0.f;
  auto expw = [&](int i, int kt, int tl) {
    int kbase = kt * 16 + lk * 4;
    int colb = (tl ? colb1 : 0) + kbase;
#pragma unroll
    for (int qt = 0; qt < 2; ++qt) {
      int qrow = (tl ? qo1 : qo0) + qt * 16 + lr;
      float fv = tl ? frv1[qt] : frv0[qt];
      bf16x4 pk;
      float rs = 0.f;
#pragma unroll
      for (int j = 0; j < 4; ++j) {
        float e = (kbase + j < qrow) ? __expf(acc[i][qt][j] * fv) : 0.f;
        rs += e;
        pk[j] = f2bf(e);
      }
      *(bf16x4*)&P[qt * 16 + lr][colb] = pk;
      if (tl == 0) { if (qt == 0) rs00 += rs; else rs01 += rs; }
      else        { if (qt == 0) rs10 += rs; else rs11 += rs; }
    }
  };
#pragma unroll
  for (int i = 0; i < 9; ++i) {
    int f = w + 4 * i;
    if (f < 34) {
      if (f < c0) expw(i, f, 0); else expw(i, f - c0, 1);
    }
  }

  // reduce partial sums across lk (lanes with same lr): 2 shuffle steps
#pragma unroll
  for (int msk = 16; msk < 64; msk <<= 1) {
    rs00 += __shfl_xor(rs00, msk);
    rs01 += __shfl_xor(rs01, msk);
    rs10 += __shfl_xor(rs10, msk);
    rs11 += __shfl_xor(rs11, msk);
  }
  if (lk == 0) {
    redsum[0][lr][w] = rs00;
    redsum[0][16 + lr][w] = rs01;
    redsum[1][lr][w] = rs10;
    redsum[1][16 + lr][w] = rs11;
  }
  __syncthreads();   // P + redsum ready (single barrier)

  // ---- PV: wave w -> unit0 (tile0, qt=w&1, dh=w>>1), unit1 (tile1, qt=w>>1, dh=w&1)
  const int uqt[2] = {w & 1, w >> 1};
  const int udh[2] = {w >> 1, w & 1};
  const int unkb[2] = {p + 1, 16 - p};
  f32x4 oacc[2][2];
#pragma unroll
  for (int u = 0; u < 2; ++u) { oacc[u][0] = vzero; oacc[u][1] = vzero; }

#pragma unroll
  for (int kb = 0; kb < 16; ++kb) {
#pragma unroll
    for (int u = 0; u < 2; ++u) {
      if (kb < unkb[u]) {
        int qt = uqt[u], dh = udh[u];
        int colbase = (u ? colb1 : 0) + kb * 32 + lk * 8;
        bf16x8 pa = *(const bf16x8*)&P[qt * 16 + lr][colbase];
#pragma unroll
        for (int n = 0; n < 2; ++n) {
          bf16x8 vf = *(const bf16x8*)(vT + (size_t)(h * DK_ + dh * 32 + n * 16 + lr) * BS_
                                          + (size_t)b * S_ + kb * 32 + lk * 8);
          oacc[u][n] = __builtin_amdgcn_mfma_f32_16x16x32_bf16(pa, vf, oacc[u][n], 0, 0, 0);
        }
      }
    }
  }

#pragma unroll
  for (int u = 0; u < 2; ++u) {
    int qt = uqt[u], dh = udh[u];
    int qo = u ? qo1 : qo0;
    float invd[4];
#pragma unroll
    for (int j = 0; j < 4; ++j) {
      int row = qt * 16 + lk * 4 + j;
      float dsum = redsum[u][row][0] + redsum[u][row][1] + redsum[u][row][2] + redsum[u][row][3];
      invd[j] = dsum > 0.f ? 1.f / dsum : 0.f;   // row 0 -> 0 (zero_pad)
    }
#pragma unroll
    for (int n = 0; n < 2; ++n)
#pragma unroll
      for (int j = 0; j < 4; ++j) {
        int qrow = qo + qt * 16 + lk * 4 + j;
        out[qk_head + (size_t)qrow * D_ + dh * 32 + n * 16 + lr] = f2bf(oacc[u][n][j] * invd[j]);
      }
  }
}

// ---------------- fused residual + LayerNorm ----------------
__global__ __launch_bounds__(256) void ln_res(
    const float* __restrict__ xin, const short* __restrict__ add,
    const float* __restrict__ g, const float* __restrict__ bb,
    float* __restrict__ xout, short* __restrict__ xbout)
{
  const int row = blockIdx.x * 4 + (threadIdx.x >> 6);
  const int lane = threadIdx.x & 63;
  const size_t base = (size_t)row * D_ + lane * 8;

  f32x4 a0 = *(const f32x4*)(xin + base);
  f32x4 a1 = *(const f32x4*)(xin + base + 4);
  bf16x8 av = *(const bf16x8*)(add + base);
  float vals[8];
#pragma unroll
  for (int i = 0; i < 4; ++i) vals[i] = a0[i] + bf2f(av[i]);
#pragma unroll
  for (int i = 0; i < 4; ++i) vals[4 + i] = a1[i] + bf2f(av[4 + i]);

  float s = 0.f, sq = 0.f;
#pragma unroll
  for (int i = 0; i < 8; ++i) { s += vals[i]; sq += vals[i] * vals[i]; }
#pragma unroll
  for (int m = 1; m < 64; m <<= 1) { s += __shfl_xor(s, m); sq += __shfl_xor(sq, m); }

  float mean = s * (1.f / D_);
  float var = sq * (1.f / D_) - mean * mean;
  float rstd = rsqrtf(var + 1e-5f);

  int col = lane * 8;
  f32x4 o0, o1; bf16x8 ob;
#pragma unroll
  for (int i = 0; i < 8; ++i) {
    float vv = g[col + i] * (vals[i] - mean) * rstd + bb[col + i];
    if (i < 4) o0[i] = vv; else o1[i - 4] = vv;
    ob[i] = f2bf(vv);
  }
  *(f32x4*)(xout + base) = o0;
  *(f32x4*)(xout + base + 4) = o1;
  *(bf16x8*)(xbout + base) = ob;
}

// ---------------- host ----------------
extern "C" void kernel_launch(void* const* d_in, const int* in_sizes, int n_in,
                              void* d_out, int out_size, void* d_ws, size_t ws_size,
                              hipStream_t stream) {
  const float* q_emb = (const float*)d_in[0];
  const float* qa_emb = (const float*)d_in[1];
  const float* frate = (const float*)d_in[2];
  const float* Wk = (const float*)d_in[3];
  const float* bk = (const float*)d_in[4];
  const float* Wv = (const float*)d_in[5];
  const float* bv = (const float*)d_in[6];
  const float* Wo = (const float*)d_in[7];
  const float* bo = (const float*)d_in[8];
  const float* ln1g = (const float*)d_in[9];
  const float* ln1b = (const float*)d_in[10];
  const float* W1 = (const float*)d_in[11];
  const float* b1 = (const float*)d_in[12];
  const float* W2 = (const float*)d_in[13];
  const float* b2 = (const float*)d_in[14];
  const float* ln2g = (const float*)d_in[15];
  const float* ln2b = (const float*)d_in[16];
  float* x = (float*)d_out;

  char* ws = (char*)d_ws;
  size_t off = 0;
  auto alloc = [&](size_t bytes) -> void* {
    void* p = ws + off;
    off += (bytes + 255) & ~(size_t)255;
    return p;
  };
  const size_t MTOK = (size_t)BS_;   // 32768 rows
  float* pe    = (float*)alloc((size_t)S_ * D_ * 4);
  short* xb    = (short*)alloc(MTOK * D_ * 2);
  short* yb    = (short*)alloc(MTOK * D_ * 2);
  short* qkb   = (short*)alloc(MTOK * D_ * 2);
  short* vTb   = (short*)alloc(MTOK * D_ * 2);   // V transposed: [D][B*S]
  short* ff1b  = (short*)alloc(MTOK * DFF_ * 2);
  // lifetime-based aliases:
  //   attnb (attn->WoGEMM) aliases ff1b (ff1GEMM->ff2GEMM) -- disjoint within a layer
  //   goutb (WoGEMM/ff2GEMM -> ln_res) aliases qkb (dead after attn_kernel)
  short* attnb = ff1b;
  short* goutb = qkb;
  short* wT[L_][5];
  for (int i = 0; i < L_; ++i) {
    wT[i][0] = (short*)alloc((size_t)D_ * D_ * 2);     // WkT [D][D]
    wT[i][1] = (short*)alloc((size_t)D_ * D_ * 2);     // WvT
    wT[i][2] = (short*)alloc((size_t)D_ * D_ * 2);     // WoT
    wT[i][3] = (short*)alloc((size_t)D_ * DFF_ * 2);   // W1T [DFF][D]
    wT[i][4] = (short*)alloc((size_t)DFF_ * D_ * 2);   // W2T [D][DFF]
  }
  if (off > ws_size) {
    fprintf(stderr, "parKT: workspace overflow: need %zu have %zu\n", off, ws_size);
    return;
  }

  pe_kernel<<<(S_ * D_) / 256, 256, 0, stream>>>(pe);
  prep_kernel<<<(int)(MTOK * D_ / 256), 256, 0, stream>>>(q_emb, qa_emb, pe, x, xb, yb);

  for (int i = 0; i < L_; ++i) {
    tr_w<<<dim3(D_ / 64, D_ / 64), 256, 0, stream>>>(Wk + (size_t)i * D_ * D_, wT[i][0], D_, D_);
    tr_w<<<dim3(D_ / 64, D_ / 64), 256, 0, stream>>>(Wv + (size_t)i * D_ * D_, wT[i][1], D_, D_);
    tr_w<<<dim3(D_ / 64, D_ / 64), 256, 0, stream>>>(Wo + (size_t)i * D_ * D_, wT[i][2], D_, D_);
    tr_w<<<dim3(DFF_ / 64, D_ / 64), 256, 0, stream>>>(W1 + (size_t)i * D_ * DFF_, wT[i][3], D_, DFF_);
    tr_w<<<dim3(D_ / 64, DFF_ / 64), 256, 0, stream>>>(W2 + (size_t)i * DFF_ * D_, wT[i][4], DFF_, D_);
  }

  const int M = (int)MTOK;
  for (int i = 0; i < L_; ++i) {
    // qk = x @ Wk + bk  (M x D)
    gemm_bt<<<dim3(D_ / 128, M / 128), 256, 0, stream>>>(xb, wT[i][0], bk + (size_t)i * D_, qkb, M, D_, D_, 0, 0);
    // vT = WvT @ y^T + bv (bias per row): [D][B*S]
    gemm_bt<<<dim3(M / 128, D_ / 128), 256, 0, stream>>>(wT[i][1], yb, bv + (size_t)i * D_, vTb, D_, M, D_, 0, 1);
    attn_kernel<<<dim3(S_ / 64, H_, B_), 256, 0, stream>>>(qkb, vTb, frate, attnb);
    gemm_bt<<<dim3(D_ / 128, M / 128), 256, 0, stream>>>(attnb, wT[i][2], bo + (size_t)i * D_, goutb, M, D_, D_, 0, 0);
    ln_res<<<M / 4, 256, 0, stream>>>(x, goutb, ln1g + (size_t)i * D_, ln1b + (size_t)i * D_, x, xb);
    gemm_bt<<<dim3(DFF_ / 128, M / 128), 256, 0, stream>>>(xb, wT[i][3], b1 + (size_t)i * DFF_, ff1b, M, DFF_, D_, 1, 0);
    gemm_bt<<<dim3(D_ / 128, M / 128), 256, 0, stream>>>(ff1b, wT[i][4], b2 + (size_t)i * D_, goutb, M, D_, DFF_, 0, 0);
    ln_res<<<M / 4, 256, 0, stream>>>(x, goutb, ln2g + (size_t)i * D_, ln2b + (size_t)i * D_, x, xb);
  }
}

// Round 7
// 971.948 us; speedup vs baseline: 1.2941x; 1.0643x over previous
//
#include <hip/hip_runtime.h>
#include <cstdio>

#define B_   64
#define S_   512
#define D_   512
#define H_   8
#define DK_  64
#define DFF_ 1024
#define L_   2
#define BS_  (B_ * S_)   // 32768

typedef __attribute__((ext_vector_type(8))) short bf16x8;
typedef __attribute__((ext_vector_type(4))) short bf16x4;
typedef __attribute__((ext_vector_type(4))) float f32x4;

__device__ inline short f2bf(float f) {
  unsigned u = __float_as_uint(f);
  u = u + 0x7FFF + ((u >> 16) & 1);
  return (short)(u >> 16);
}
__device__ inline float bf2f(short s) {
  return __uint_as_float(((unsigned)(unsigned short)s) << 16);
}

// async global->LDS, 16B per lane; lds dest = wave-uniform base + lane*16
__device__ inline void gl_lds16(const short* g, void* lds_base) {
  __builtin_amdgcn_global_load_lds(
      (const __attribute__((address_space(1))) void*)g,
      (__attribute__((address_space(3))) void*)lds_base, 16, 0, 0);
}

// ---------------- positional encoding table ----------------
__global__ void pe_kernel(float* __restrict__ pe) {
  int idx = blockIdx.x * 256 + threadIdx.x;      // S_*D_ threads
  int s = idx >> 9, d = idx & 511;
  float dv = __expf((float)(d & ~1) * (-9.210340371976184f / (float)D_));
  float ang = (float)s * dv;
  pe[idx] = (d & 1) ? cosf(ang) : sinf(ang);
}

// x = q + pe (f32 master + bf16 mirror); yb = bf16(qa + pe). 8 elem/thread.
__global__ __launch_bounds__(256) void prep_kernel(
    const float* __restrict__ q, const float* __restrict__ qa,
    const float* __restrict__ pe, float* __restrict__ x,
    short* __restrict__ xb, short* __restrict__ yb) {
  size_t base = ((size_t)blockIdx.x * 256 + threadIdx.x) * 8;
  int sd = (int)(base & (size_t)(S_ * D_ - 1));
  f32x4 p0 = *(const f32x4*)(pe + sd);
  f32x4 p1 = *(const f32x4*)(pe + sd + 4);
  f32x4 q0 = *(const f32x4*)(q + base);
  f32x4 q1 = *(const f32x4*)(q + base + 4);
  f32x4 a0 = *(const f32x4*)(qa + base);
  f32x4 a1 = *(const f32x4*)(qa + base + 4);
  f32x4 x0, x1; bf16x8 xv, yv;
#pragma unroll
  for (int i = 0; i < 4; ++i) {
    float xe = q0[i] + p0[i]; x0[i] = xe; xv[i] = f2bf(xe);
    yv[i] = f2bf(a0[i] + p0[i]);
  }
#pragma unroll
  for (int i = 0; i < 4; ++i) {
    float xe = q1[i] + p1[i]; x1[i] = xe; xv[4 + i] = f2bf(xe);
    yv[4 + i] = f2bf(a1[i] + p1[i]);
  }
  *(f32x4*)(x + base) = x0;
  *(f32x4*)(x + base + 4) = x1;
  *(bf16x8*)(xb + base) = xv;
  *(bf16x8*)(yb + base) = yv;
}

// ---------------- all weight transposes in ONE launch ----------------
// slot = blockIdx.z; dst[c][r] = bf16(src[r][c]).
struct TrArgs {
  const float* src[10];
  short* dst[10];
  int R[10], C[10];
};
__global__ __launch_bounds__(256) void tr_w_all(TrArgs a) {
  const int slot = blockIdx.z;
  const int R = a.R[slot], C = a.C[slot];
  const int c0 = blockIdx.x * 64, r0 = blockIdx.y * 64;
  if (c0 >= C || r0 >= R) return;
  const float* __restrict__ src = a.src[slot];
  short* __restrict__ dst = a.dst[slot];
  __shared__ short Ts[64][72];
  const int t = threadIdx.x;
#pragma unroll
  for (int it = 0; it < 2; ++it) {
    int c2 = it * 256 + t;
    int srow = c2 >> 3, schunk = c2 & 7;
    const float* sp = src + (size_t)(r0 + srow) * C + c0 + schunk * 8;
    f32x4 a0 = *(const f32x4*)sp;
    f32x4 a1 = *(const f32x4*)(sp + 4);
#pragma unroll
    for (int k = 0; k < 4; ++k) Ts[srow][schunk * 8 + k] = f2bf(a0[k]);
#pragma unroll
    for (int k = 0; k < 4; ++k) Ts[srow][schunk * 8 + 4 + k] = f2bf(a1[k]);
  }
  __syncthreads();
#pragma unroll
  for (int it = 0; it < 2; ++it) {
    int c2 = it * 256 + t;
    int orow = c2 >> 3, ochunk = c2 & 7;
    bf16x8 vv;
#pragma unroll
    for (int k = 0; k < 8; ++k) vv[k] = Ts[ochunk * 8 + k][orow];
    *(bf16x8*)(dst + (size_t)(c0 + orow) * R + r0 + ochunk * 8) = vv;
  }
}

// ---------------- bf16 MFMA GEMM: C[M,N] = A[M,K] @ BT[N,K]^T + bias ----------------
// 128x128 tile, BK=32, double-buffered LDS, XCD-aware block remap (1D grid).
// xmaj=1: bcol = l%nx (A-panel-sharing blocks contiguous -> same XCD).
// xmaj=0: brow = l%ny (B-panel-sharing blocks contiguous -> same XCD).
__global__ __launch_bounds__(256) void gemm_bt(
    const short* __restrict__ A, const short* __restrict__ BT,
    const float* __restrict__ bias, short* __restrict__ Cb,
    int M, int N, int K, int relu, int bias_row, int nx, int xmaj)
{
  const int nwg = gridDim.x;                 // multiple of 8
  const int cpx = nwg >> 3;
  const int l = (blockIdx.x & 7) * cpx + (blockIdx.x >> 3);
  int bcol, brow;
  if (xmaj) { bcol = l % nx; brow = l / nx; }
  else      { int ny = nwg / nx; brow = l % ny; bcol = l / ny; }

  __shared__ __align__(16) short As[2][128][32];
  __shared__ __align__(16) short Bs[2][128][32];
  const int t = threadIdx.x;
  const int w = t >> 6, lane = t & 63, lr = lane & 15, lk = lane >> 4;
  const int wrow = w >> 1, wcol = w & 1;

  const f32x4 vzero = {0.f, 0.f, 0.f, 0.f};
  f32x4 acc[4][4];
#pragma unroll
  for (int m = 0; m < 4; ++m)
#pragma unroll
    for (int n = 0; n < 4; ++n) acc[m][n] = vzero;

  const short* Abase = A + (size_t)brow * 128 * K;
  const short* Bbase = BT + (size_t)bcol * 128 * K;

  auto stage = [&](int buf, int k0) {
#pragma unroll
    for (int it = 0; it < 2; ++it) {
      int cb = it * 256 + w * 64;          // wave-uniform chunk base (chunk = 16B)
      int c = cb + lane;
      int row = c >> 2, seg = c & 3;       // 4 chunks of 16B per 64B row
      gl_lds16(Abase + (size_t)row * K + k0 + seg * 8, (char*)&As[buf][0][0] + (size_t)cb * 16);
      gl_lds16(Bbase + (size_t)row * K + k0 + seg * 8, (char*)&Bs[buf][0][0] + (size_t)cb * 16);
    }
  };

  stage(0, 0);
  __syncthreads();          // drain vmcnt + barrier: buf0 ready
  int cur = 0;
  for (int k0 = 0; k0 < K; k0 += 32) {
    if (k0 + 32 < K) stage(cur ^ 1, k0 + 32);   // prefetch next tile

    bf16x8 af[4], bf[4];
#pragma unroll
    for (int m = 0; m < 4; ++m) af[m] = *(const bf16x8*)&As[cur][wrow * 64 + m * 16 + lr][lk * 8];
#pragma unroll
    for (int n = 0; n < 4; ++n) bf[n] = *(const bf16x8*)&Bs[cur][wcol * 64 + n * 16 + lr][lk * 8];
#pragma unroll
    for (int m = 0; m < 4; ++m)
#pragma unroll
      for (int n = 0; n < 4; ++n)
        acc[m][n] = __builtin_amdgcn_mfma_f32_16x16x32_bf16(af[m], bf[n], acc[m][n], 0, 0, 0);

    __syncthreads();        // next tile landed + everyone done reading cur
    cur ^= 1;
  }

#pragma unroll
  for (int m = 0; m < 4; ++m)
#pragma unroll
    for (int n = 0; n < 4; ++n) {
      int col = bcol * 128 + wcol * 64 + n * 16 + lr;
      float bcv = (bias && !bias_row) ? bias[col] : 0.f;
#pragma unroll
      for (int j = 0; j < 4; ++j) {
        int row = brow * 128 + wrow * 64 + m * 16 + lk * 4 + j;
        float vv = acc[m][n][j] + ((bias && bias_row) ? bias[row] : bcv);
        if (relu) vv = fmaxf(vv, 0.f);
        Cb[(size_t)row * N + col] = f2bf(vv);
      }
    }
}

// ---------------- fused attention: balanced-pair causal, swapped QK^T ----------------
// 1D grid 4096 with XCD remap: the 8 p-blocks of one (b,h) land on ONE XCD
// (K/V L2 locality). Block p handles q-tiles p and 15-p (constant work).
__global__ __launch_bounds__(256) void attn_kernel(
    const short* __restrict__ qk, const short* __restrict__ vT,
    const float* __restrict__ fr, short* __restrict__ out)
{
  const int hw = blockIdx.x;                 // 4096 blocks
  const int l = (hw & 7) * 512 + (hw >> 3);  // bijective XCD grouping
  const int p = l & 7, hb = l >> 3;
  const int h = hb & 7, b = hb >> 3;
  const int t = threadIdx.x;
  const int w = t >> 6, lane = t & 63, lr = lane & 15, lk = lane >> 4;

  const int qo0 = 32 * p, qo1 = 32 * (15 - p);
  const int c0 = 2 * p + 2;          // tile0 fragment count
  const int colb1 = c0 * 16;         // tile1 P column offset

  __shared__ short P[32][552];       // row stride 1104B (16B-aligned for b128)
  __shared__ float redsum[2][32][4];

  const size_t qk_head = (size_t)b * S_ * D_ + (size_t)h * DK_;
  const float scale = 0.125f;   // 1/sqrt(64)

  // Q fragments (used as B operand)
  bf16x8 qf0[2][2], qf1[2][2];   // [qt][ks]
#pragma unroll
  for (int qt = 0; qt < 2; ++qt)
#pragma unroll
    for (int ks = 0; ks < 2; ++ks) {
      qf0[qt][ks] = *(const bf16x8*)(qk + qk_head + (size_t)(qo0 + qt * 16 + lr) * D_ + ks * 32 + lk * 8);
      qf1[qt][ks] = *(const bf16x8*)(qk + qk_head + (size_t)(qo1 + qt * 16 + lr) * D_ + ks * 32 + lk * 8);
    }

  float frv0[2], frv1[2];
#pragma unroll
  for (int qt = 0; qt < 2; ++qt) {
    frv0[qt] = scale * fr[(size_t)b * S_ + qo0 + qt * 16 + lr];
    frv1[qt] = scale * fr[(size_t)b * S_ + qo1 + qt * 16 + lr];
  }

  const f32x4 vzero = {0.f, 0.f, 0.f, 0.f};
  f32x4 acc[9][2];
#pragma unroll
  for (int i = 0; i < 9; ++i) { acc[i][0] = vzero; acc[i][1] = vzero; }

  // ---- QK^T (swapped): fragment f = w + 4i; f<c0 -> tile0 kt=f, else tile1 kt=f-c0
  auto qkt = [&](int i, int kt, bf16x8 (*qf)[2]) {
#pragma unroll
    for (int ks = 0; ks < 2; ++ks) {
      bf16x8 kf = *(const bf16x8*)(qk + qk_head + (size_t)(kt * 16 + lr) * D_ + ks * 32 + lk * 8);
      acc[i][0] = __builtin_amdgcn_mfma_f32_16x16x32_bf16(kf, qf[0][ks], acc[i][0], 0, 0, 0);
      acc[i][1] = __builtin_amdgcn_mfma_f32_16x16x32_bf16(kf, qf[1][ks], acc[i][1], 0, 0, 0);
    }
  };
#pragma unroll
  for (int i = 0; i < 9; ++i) {
    int f = w + 4 * i;
    if (f < 34) {
      if (f < c0) qkt(i, f, qf0); else qkt(i, f - c0, qf1);
    }
  }

  // ---- exp pass: e = (k < q) ? exp(score*frv) : 0 ; packed b64 P-writes; row sums
  float rs00 = 0.f, rs01 = 0.f, rs10 = 0.f, rs11 = 0.f;
  auto expw = [&](int i, int kt, int tl) {
    int kbase = kt * 16 + lk * 4;
    int colb = (tl ? colb1 : 0) + kbase;
#pragma unroll
    for (int qt = 0; qt < 2; ++qt) {
      int qrow = (tl ? qo1 : qo0) + qt * 16 + lr;
      float fv = tl ? frv1[qt] : frv0[qt];
      bf16x4 pk;
      float rs = 0.f;
#pragma unroll
      for (int j = 0; j < 4; ++j) {
        float e = (kbase + j < qrow) ? __expf(acc[i][qt][j] * fv) : 0.f;
        rs += e;
        pk[j] = f2bf(e);
      }
      *(bf16x4*)&P[qt * 16 + lr][colb] = pk;
      if (tl == 0) { if (qt == 0) rs00 += rs; else rs01 += rs; }
      else        { if (qt == 0) rs10 += rs; else rs11 += rs; }
    }
  };
#pragma unroll
  for (int i = 0; i < 9; ++i) {
    int f = w + 4 * i;
    if (f < 34) {
      if (f < c0) expw(i, f, 0); else expw(i, f - c0, 1);
    }
  }

#pragma unroll
  for (int msk = 16; msk < 64; msk <<= 1) {
    rs00 += __shfl_xor(rs00, msk);
    rs01 += __shfl_xor(rs01, msk);
    rs10 += __shfl_xor(rs10, msk);
    rs11 += __shfl_xor(rs11, msk);
  }
  if (lk == 0) {
    redsum[0][lr][w] = rs00;
    redsum[0][16 + lr][w] = rs01;
    redsum[1][lr][w] = rs10;
    redsum[1][16 + lr][w] = rs11;
  }
  __syncthreads();   // P + redsum ready (single barrier)

  // ---- PV: wave w -> unit0 (tile0, qt=w&1, dh=w>>1), unit1 (tile1, qt=w>>1, dh=w&1)
  const int uqt[2] = {w & 1, w >> 1};
  const int udh[2] = {w >> 1, w & 1};
  const int unkb[2] = {p + 1, 16 - p};
  f32x4 oacc[2][2];
#pragma unroll
  for (int u = 0; u < 2; ++u) { oacc[u][0] = vzero; oacc[u][1] = vzero; }

#pragma unroll
  for (int kb = 0; kb < 16; ++kb) {
#pragma unroll
    for (int u = 0; u < 2; ++u) {
      if (kb < unkb[u]) {
        int qt = uqt[u], dh = udh[u];
        int colbase = (u ? colb1 : 0) + kb * 32 + lk * 8;
        bf16x8 pa = *(const bf16x8*)&P[qt * 16 + lr][colbase];
#pragma unroll
        for (int n = 0; n < 2; ++n) {
          bf16x8 vf = *(const bf16x8*)(vT + (size_t)(h * DK_ + dh * 32 + n * 16 + lr) * BS_
                                          + (size_t)b * S_ + kb * 32 + lk * 8);
          oacc[u][n] = __builtin_amdgcn_mfma_f32_16x16x32_bf16(pa, vf, oacc[u][n], 0, 0, 0);
        }
      }
    }
  }

#pragma unroll
  for (int u = 0; u < 2; ++u) {
    int qt = uqt[u], dh = udh[u];
    int qo = u ? qo1 : qo0;
    float invd[4];
#pragma unroll
    for (int j = 0; j < 4; ++j) {
      int row = qt * 16 + lk * 4 + j;
      float dsum = redsum[u][row][0] + redsum[u][row][1] + redsum[u][row][2] + redsum[u][row][3];
      invd[j] = dsum > 0.f ? 1.f / dsum : 0.f;   // row 0 -> 0 (zero_pad)
    }
#pragma unroll
    for (int n = 0; n < 2; ++n)
#pragma unroll
      for (int j = 0; j < 4; ++j) {
        int qrow = qo + qt * 16 + lk * 4 + j;
        out[qk_head + (size_t)qrow * D_ + dh * 32 + n * 16 + lr] = f2bf(oacc[u][n][j] * invd[j]);
      }
  }
}

// ---------------- fused residual + LayerNorm ----------------
__global__ __launch_bounds__(256) void ln_res(
    const float* __restrict__ xin, const short* __restrict__ add,
    const float* __restrict__ g, const float* __restrict__ bb,
    float* __restrict__ xout, short* __restrict__ xbout)
{
  const int row = blockIdx.x * 4 + (threadIdx.x >> 6);
  const int lane = threadIdx.x & 63;
  const size_t base = (size_t)row * D_ + lane * 8;

  f32x4 a0 = *(const f32x4*)(xin + base);
  f32x4 a1 = *(const f32x4*)(xin + base + 4);
  bf16x8 av = *(const bf16x8*)(add + base);
  float vals[8];
#pragma unroll
  for (int i = 0; i < 4; ++i) vals[i] = a0[i] + bf2f(av[i]);
#pragma unroll
  for (int i = 0; i < 4; ++i) vals[4 + i] = a1[i] + bf2f(av[4 + i]);

  float s = 0.f, sq = 0.f;
#pragma unroll
  for (int i = 0; i < 8; ++i) { s += vals[i]; sq += vals[i] * vals[i]; }
#pragma unroll
  for (int m = 1; m < 64; m <<= 1) { s += __shfl_xor(s, m); sq += __shfl_xor(sq, m); }

  float mean = s * (1.f / D_);
  float var = sq * (1.f / D_) - mean * mean;
  float rstd = rsqrtf(var + 1e-5f);

  int col = lane * 8;
  f32x4 o0, o1; bf16x8 ob;
#pragma unroll
  for (int i = 0; i < 8; ++i) {
    float vv = g[col + i] * (vals[i] - mean) * rstd + bb[col + i];
    if (i < 4) o0[i] = vv; else o1[i - 4] = vv;
    ob[i] = f2bf(vv);
  }
  *(f32x4*)(xout + base) = o0;
  *(f32x4*)(xout + base + 4) = o1;
  *(bf16x8*)(xbout + base) = ob;
}

// ---------------- host ----------------
extern "C" void kernel_launch(void* const* d_in, const int* in_sizes, int n_in,
                              void* d_out, int out_size, void* d_ws, size_t ws_size,
                              hipStream_t stream) {
  const float* q_emb = (const float*)d_in[0];
  const float* qa_emb = (const float*)d_in[1];
  const float* frate = (const float*)d_in[2];
  const float* Wk = (const float*)d_in[3];
  const float* bk = (const float*)d_in[4];
  const float* Wv = (const float*)d_in[5];
  const float* bv = (const float*)d_in[6];
  const float* Wo = (const float*)d_in[7];
  const float* bo = (const float*)d_in[8];
  const float* ln1g = (const float*)d_in[9];
  const float* ln1b = (const float*)d_in[10];
  const float* W1 = (const float*)d_in[11];
  const float* b1 = (const float*)d_in[12];
  const float* W2 = (const float*)d_in[13];
  const float* b2 = (const float*)d_in[14];
  const float* ln2g = (const float*)d_in[15];
  const float* ln2b = (const float*)d_in[16];
  float* x = (float*)d_out;

  char* ws = (char*)d_ws;
  size_t off = 0;
  auto alloc = [&](size_t bytes) -> void* {
    void* p = ws + off;
    off += (bytes + 255) & ~(size_t)255;
    return p;
  };
  const size_t MTOK = (size_t)BS_;   // 32768 rows
  float* pe    = (float*)alloc((size_t)S_ * D_ * 4);
  short* xb    = (short*)alloc(MTOK * D_ * 2);
  short* yb    = (short*)alloc(MTOK * D_ * 2);
  short* qkb   = (short*)alloc(MTOK * D_ * 2);
  short* vTb   = (short*)alloc(MTOK * D_ * 2);   // V transposed: [D][B*S]
  short* ff1b  = (short*)alloc(MTOK * DFF_ * 2);
  // lifetime-based aliases:
  //   attnb (attn->WoGEMM) aliases ff1b (ff1GEMM->ff2GEMM) -- disjoint within a layer
  //   goutb (WoGEMM/ff2GEMM -> ln_res) aliases qkb (dead after attn_kernel)
  short* attnb = ff1b;
  short* goutb = qkb;
  short* wT[L_][5];
  for (int i = 0; i < L_; ++i) {
    wT[i][0] = (short*)alloc((size_t)D_ * D_ * 2);     // WkT [D][D]
    wT[i][1] = (short*)alloc((size_t)D_ * D_ * 2);     // WvT
    wT[i][2] = (short*)alloc((size_t)D_ * D_ * 2);     // WoT
    wT[i][3] = (short*)alloc((size_t)D_ * DFF_ * 2);   // W1T [DFF][D]
    wT[i][4] = (short*)alloc((size_t)DFF_ * D_ * 2);   // W2T [D][DFF]
  }
  if (off > ws_size) {
    fprintf(stderr, "parKT: workspace overflow: need %zu have %zu\n", off, ws_size);
    return;
  }

  pe_kernel<<<(S_ * D_) / 256, 256, 0, stream>>>(pe);
  prep_kernel<<<(int)(MTOK * D_ / (256 * 8)), 256, 0, stream>>>(q_emb, qa_emb, pe, x, xb, yb);

  // all 10 weight transposes in one launch
  TrArgs ta;
  for (int i = 0; i < L_; ++i) {
    ta.src[i * 5 + 0] = Wk + (size_t)i * D_ * D_;  ta.dst[i * 5 + 0] = wT[i][0]; ta.R[i * 5 + 0] = D_;   ta.C[i * 5 + 0] = D_;
    ta.src[i * 5 + 1] = Wv + (size_t)i * D_ * D_;  ta.dst[i * 5 + 1] = wT[i][1]; ta.R[i * 5 + 1] = D_;   ta.C[i * 5 + 1] = D_;
    ta.src[i * 5 + 2] = Wo + (size_t)i * D_ * D_;  ta.dst[i * 5 + 2] = wT[i][2]; ta.R[i * 5 + 2] = D_;   ta.C[i * 5 + 2] = D_;
    ta.src[i * 5 + 3] = W1 + (size_t)i * D_ * DFF_; ta.dst[i * 5 + 3] = wT[i][3]; ta.R[i * 5 + 3] = D_;   ta.C[i * 5 + 3] = DFF_;
    ta.src[i * 5 + 4] = W2 + (size_t)i * DFF_ * D_; ta.dst[i * 5 + 4] = wT[i][4]; ta.R[i * 5 + 4] = DFF_; ta.C[i * 5 + 4] = D_;
  }
  tr_w_all<<<dim3(DFF_ / 64, DFF_ / 64, 10), 256, 0, stream>>>(ta);

  const int M = (int)MTOK;
  for (int i = 0; i < L_; ++i) {
    // qk = x @ Wk + bk  (M x D): A-panel sharing -> xmaj=1, nx = D/128
    gemm_bt<<<(D_ / 128) * (M / 128), 256, 0, stream>>>(xb, wT[i][0], bk + (size_t)i * D_, qkb, M, D_, D_, 0, 0, D_ / 128, 1);
    // vT = WvT @ y^T + bv (bias per row): [D][B*S]: B-panel (yb) sharing -> xmaj=0, nx = M/128
    gemm_bt<<<(M / 128) * (D_ / 128), 256, 0, stream>>>(wT[i][1], yb, bv + (size_t)i * D_, vTb, D_, M, D_, 0, 1, M / 128, 0);
    attn_kernel<<<(S_ / 64) * H_ * B_, 256, 0, stream>>>(qkb, vTb, frate, attnb);
    gemm_bt<<<(D_ / 128) * (M / 128), 256, 0, stream>>>(attnb, wT[i][2], bo + (size_t)i * D_, goutb, M, D_, D_, 0, 0, D_ / 128, 1);
    ln_res<<<M / 4, 256, 0, stream>>>(x, goutb, ln1g + (size_t)i * D_, ln1b + (size_t)i * D_, x, xb);
    gemm_bt<<<(DFF_ / 128) * (M / 128), 256, 0, stream>>>(xb, wT[i][3], b1 + (size_t)i * DFF_, ff1b, M, DFF_, D_, 1, 0, DFF_ / 128, 1);
    gemm_bt<<<(D_ / 128) * (M / 128), 256, 0, stream>>>(ff1b, wT[i][4], b2 + (size_t)i * D_, goutb, M, D_, DFF_, 0, 0, D_ / 128, 1);
    ln_res<<<M / 4, 256, 0, stream>>>(x, goutb, ln2g + (size_t)i * D_, ln2b + (size_t)i * D_, x, xb);
  }
}

// Round 8
// 882.516 us; speedup vs baseline: 1.4253x; 1.1013x over previous
//
#include <hip/hip_runtime.h>
#include <cstdio>

#define B_   64
#define S_   512
#define D_   512
#define H_   8
#define DK_  64
#define DFF_ 1024
#define L_   2
#define BS_  (B_ * S_)   // 32768

typedef __attribute__((ext_vector_type(8))) short bf16x8;
typedef __attribute__((ext_vector_type(4))) short bf16x4;
typedef __attribute__((ext_vector_type(4))) float f32x4;

__device__ inline short f2bf(float f) {
  unsigned u = __float_as_uint(f);
  u = u + 0x7FFF + ((u >> 16) & 1);
  return (short)(u >> 16);
}
__device__ inline float bf2f(short s) {
  return __uint_as_float(((unsigned)(unsigned short)s) << 16);
}

// async global->LDS, 16B per lane; lds dest = wave-uniform base + lane*16
__device__ inline void gl_lds16(const short* g, void* lds_base) {
  __builtin_amdgcn_global_load_lds(
      (const __attribute__((address_space(1))) void*)g,
      (__attribute__((address_space(3))) void*)lds_base, 16, 0, 0);
}

// ---------------- positional encoding table ----------------
__global__ void pe_kernel(float* __restrict__ pe) {
  int idx = blockIdx.x * 256 + threadIdx.x;      // S_*D_ threads
  int s = idx >> 9, d = idx & 511;
  float dv = __expf((float)(d & ~1) * (-9.210340371976184f / (float)D_));
  float ang = (float)s * dv;
  pe[idx] = (d & 1) ? cosf(ang) : sinf(ang);
}

// x = q + pe (f32 master + bf16 mirror); yb = bf16(qa + pe). 8 elem/thread.
__global__ __launch_bounds__(256) void prep_kernel(
    const float* __restrict__ q, const float* __restrict__ qa,
    const float* __restrict__ pe, float* __restrict__ x,
    short* __restrict__ xb, short* __restrict__ yb) {
  size_t base = ((size_t)blockIdx.x * 256 + threadIdx.x) * 8;
  int sd = (int)(base & (size_t)(S_ * D_ - 1));
  f32x4 p0 = *(const f32x4*)(pe + sd);
  f32x4 p1 = *(const f32x4*)(pe + sd + 4);
  f32x4 q0 = *(const f32x4*)(q + base);
  f32x4 q1 = *(const f32x4*)(q + base + 4);
  f32x4 a0 = *(const f32x4*)(qa + base);
  f32x4 a1 = *(const f32x4*)(qa + base + 4);
  f32x4 x0, x1; bf16x8 xv, yv;
#pragma unroll
  for (int i = 0; i < 4; ++i) {
    float xe = q0[i] + p0[i]; x0[i] = xe; xv[i] = f2bf(xe);
    yv[i] = f2bf(a0[i] + p0[i]);
  }
#pragma unroll
  for (int i = 0; i < 4; ++i) {
    float xe = q1[i] + p1[i]; x1[i] = xe; xv[4 + i] = f2bf(xe);
    yv[4 + i] = f2bf(a1[i] + p1[i]);
  }
  *(f32x4*)(x + base) = x0;
  *(f32x4*)(x + base + 4) = x1;
  *(bf16x8*)(xb + base) = xv;
  *(bf16x8*)(yb + base) = yv;
}

// ---------------- all weight transposes in ONE launch ----------------
struct TrArgs {
  const float* src[10];
  short* dst[10];
  int R[10], C[10];
};
__global__ __launch_bounds__(256) void tr_w_all(TrArgs a) {
  const int slot = blockIdx.z;
  const int R = a.R[slot], C = a.C[slot];
  const int c0 = blockIdx.x * 64, r0 = blockIdx.y * 64;
  if (c0 >= C || r0 >= R) return;
  const float* __restrict__ src = a.src[slot];
  short* __restrict__ dst = a.dst[slot];
  __shared__ short Ts[64][72];
  const int t = threadIdx.x;
#pragma unroll
  for (int it = 0; it < 2; ++it) {
    int c2 = it * 256 + t;
    int srow = c2 >> 3, schunk = c2 & 7;
    const float* sp = src + (size_t)(r0 + srow) * C + c0 + schunk * 8;
    f32x4 a0 = *(const f32x4*)sp;
    f32x4 a1 = *(const f32x4*)(sp + 4);
#pragma unroll
    for (int k = 0; k < 4; ++k) Ts[srow][schunk * 8 + k] = f2bf(a0[k]);
#pragma unroll
    for (int k = 0; k < 4; ++k) Ts[srow][schunk * 8 + 4 + k] = f2bf(a1[k]);
  }
  __syncthreads();
#pragma unroll
  for (int it = 0; it < 2; ++it) {
    int c2 = it * 256 + t;
    int orow = c2 >> 3, ochunk = c2 & 7;
    bf16x8 vv;
#pragma unroll
    for (int k = 0; k < 8; ++k) vv[k] = Ts[ochunk * 8 + k][orow];
    *(bf16x8*)(dst + (size_t)(c0 + orow) * R + r0 + ochunk * 8) = vv;
  }
}

// ---------------- bf16 MFMA GEMM: C[M,N] = A[M,K] @ BT[N,K]^T + bias ----------------
// 128x128 tile, BK=32, dbuf LDS, counted-vmcnt pipeline (prefetch stays in flight
// across the barrier), swapped-operand MFMA so each lane holds 4 consecutive
// OUTPUT COLUMNS -> b64 C-stores. XCD-aware 1D block remap.
__global__ __launch_bounds__(256) void gemm_bt(
    const short* __restrict__ A, const short* __restrict__ BT,
    const float* __restrict__ bias, short* __restrict__ Cb,
    int M, int N, int K, int relu, int bias_row, int nx, int xmaj)
{
  const int nwg = gridDim.x;                 // multiple of 8
  const int cpx = nwg >> 3;
  const int l = (blockIdx.x & 7) * cpx + (blockIdx.x >> 3);
  int bcol, brow;
  if (xmaj) { bcol = l % nx; brow = l / nx; }
  else      { int ny = nwg / nx; brow = l % ny; bcol = l / ny; }

  __shared__ __align__(16) short As[2][128][32];
  __shared__ __align__(16) short Bs[2][128][32];
  const int t = threadIdx.x;
  const int w = t >> 6, lane = t & 63, lr = lane & 15, lk = lane >> 4;
  const int wrow = w >> 1, wcol = w & 1;

  const f32x4 vzero = {0.f, 0.f, 0.f, 0.f};
  f32x4 acc[4][4];
#pragma unroll
  for (int m = 0; m < 4; ++m)
#pragma unroll
    for (int n = 0; n < 4; ++n) acc[m][n] = vzero;

  const short* Abase = A + (size_t)brow * 128 * K;
  const short* Bbase = BT + (size_t)bcol * 128 * K;

  auto stage = [&](int buf, int k0) {   // 4 gl_lds per thread
#pragma unroll
    for (int it = 0; it < 2; ++it) {
      int cb = it * 256 + w * 64;          // wave-uniform chunk base (chunk = 16B)
      int c = cb + lane;
      int row = c >> 2, seg = c & 3;       // 4 chunks of 16B per 64B row
      gl_lds16(Abase + (size_t)row * K + k0 + seg * 8, (char*)&As[buf][0][0] + (size_t)cb * 16);
      gl_lds16(Bbase + (size_t)row * K + k0 + seg * 8, (char*)&Bs[buf][0][0] + (size_t)cb * 16);
    }
  };

  stage(0, 0);
  int cur = 0;
  for (int k0 = 0; k0 < K; k0 += 32) {
    if (k0 + 32 < K) {
      stage(cur ^ 1, k0 + 32);                         // tile t+1 in flight
      asm volatile("s_waitcnt vmcnt(4)" ::: "memory"); // tile t's 4 loads landed
    } else {
      asm volatile("s_waitcnt vmcnt(0)" ::: "memory");
    }
    asm volatile("s_barrier" ::: "memory");            // buf cur ready for all waves

    bf16x8 af[4], bf[4];
#pragma unroll
    for (int m = 0; m < 4; ++m) af[m] = *(const bf16x8*)&As[cur][wrow * 64 + m * 16 + lr][lk * 8];
#pragma unroll
    for (int n = 0; n < 4; ++n) bf[n] = *(const bf16x8*)&Bs[cur][wcol * 64 + n * 16 + lr][lk * 8];
    // swapped operands: D rows = B rows (N-cols), D cols = A rows (M-rows)
    // -> lane holds M-row (lr) x 4 consecutive N-cols (lk*4+j)
#pragma unroll
    for (int m = 0; m < 4; ++m)
#pragma unroll
      for (int n = 0; n < 4; ++n)
        acc[m][n] = __builtin_amdgcn_mfma_f32_16x16x32_bf16(bf[n], af[m], acc[m][n], 0, 0, 0);

    asm volatile("s_barrier" ::: "memory");            // all waves done reading cur
    cur ^= 1;
  }

#pragma unroll
  for (int m = 0; m < 4; ++m) {
    int row = brow * 128 + wrow * 64 + m * 16 + lr;
    float brv = (bias && bias_row) ? bias[row] : 0.f;
    size_t rb = (size_t)row * N;
#pragma unroll
    for (int n = 0; n < 4; ++n) {
      int colb = bcol * 128 + wcol * 64 + n * 16 + lk * 4;
      f32x4 bv4;
      if (bias && !bias_row) bv4 = *(const f32x4*)(bias + colb);
      else { bv4[0] = brv; bv4[1] = brv; bv4[2] = brv; bv4[3] = brv; }
      bf16x4 ov;
#pragma unroll
      for (int j = 0; j < 4; ++j) {
        float vv = acc[m][n][j] + bv4[j];
        if (relu) vv = fmaxf(vv, 0.f);
        ov[j] = f2bf(vv);
      }
      *(bf16x4*)(Cb + rb + colb) = ov;   // 8B store, 4 lanes/row contiguous 32B
    }
  }
}

// ---------------- fused attention: balanced-pair causal, swapped QK^T, static-p ----
template<int P>
__device__ __forceinline__ void attn_body(
    const short* __restrict__ qk, const short* __restrict__ vT,
    const float* __restrict__ fr, short* __restrict__ out,
    short (*Pl)[552], float (*redsum)[32][4],
    int h, int b, int w, int lr, int lk)
{
  constexpr int qo0 = 32 * P, qo1 = 32 * (15 - P);
  constexpr int c0 = 2 * P + 2;          // tile0 fragment count
  constexpr int colb1 = c0 * 16;         // tile1 P-column offset

  const size_t qk_head = (size_t)b * S_ * D_ + (size_t)h * DK_;
  const float scale = 0.125f;   // 1/sqrt(64)

  bf16x8 qf0[2][2], qf1[2][2];   // [qt][ks]
#pragma unroll
  for (int qt = 0; qt < 2; ++qt)
#pragma unroll
    for (int ks = 0; ks < 2; ++ks) {
      qf0[qt][ks] = *(const bf16x8*)(qk + qk_head + (size_t)(qo0 + qt * 16 + lr) * D_ + ks * 32 + lk * 8);
      qf1[qt][ks] = *(const bf16x8*)(qk + qk_head + (size_t)(qo1 + qt * 16 + lr) * D_ + ks * 32 + lk * 8);
    }

  float frv0[2], frv1[2];
#pragma unroll
  for (int qt = 0; qt < 2; ++qt) {
    frv0[qt] = scale * fr[(size_t)b * S_ + qo0 + qt * 16 + lr];
    frv1[qt] = scale * fr[(size_t)b * S_ + qo1 + qt * 16 + lr];
  }

  const f32x4 vzero = {0.f, 0.f, 0.f, 0.f};
  f32x4 acc[9][2];
#pragma unroll
  for (int i = 0; i < 9; ++i) { acc[i][0] = vzero; acc[i][1] = vzero; }

  // ---- QK^T (swapped): fragment frag handled by wave (frag&3); tile split static
#pragma unroll
  for (int frag = 0; frag < 34; ++frag) {
    if ((frag & 3) == w) {               // wave-uniform
      const int i = frag >> 2;
      if (frag < c0) {                   // compile-time
        const int kt = frag;
#pragma unroll
        for (int ks = 0; ks < 2; ++ks) {
          bf16x8 kf = *(const bf16x8*)(qk + qk_head + (size_t)(kt * 16 + lr) * D_ + ks * 32 + lk * 8);
          acc[i][0] = __builtin_amdgcn_mfma_f32_16x16x32_bf16(kf, qf0[0][ks], acc[i][0], 0, 0, 0);
          acc[i][1] = __builtin_amdgcn_mfma_f32_16x16x32_bf16(kf, qf0[1][ks], acc[i][1], 0, 0, 0);
        }
      } else {
        const int kt = frag - c0;
#pragma unroll
        for (int ks = 0; ks < 2; ++ks) {
          bf16x8 kf = *(const bf16x8*)(qk + qk_head + (size_t)(kt * 16 + lr) * D_ + ks * 32 + lk * 8);
          acc[i][0] = __builtin_amdgcn_mfma_f32_16x16x32_bf16(kf, qf1[0][ks], acc[i][0], 0, 0, 0);
          acc[i][1] = __builtin_amdgcn_mfma_f32_16x16x32_bf16(kf, qf1[1][ks], acc[i][1], 0, 0, 0);
        }
      }
    }
  }

  // ---- exp pass: e = (k < q) ? exp(score*frv) : 0 ; b64 P-writes; row sums
  float rs00 = 0.f, rs01 = 0.f, rs10 = 0.f, rs11 = 0.f;
#pragma unroll
  for (int frag = 0; frag < 34; ++frag) {
    if ((frag & 3) == w) {
      const int i = frag >> 2;
      const int tl = (frag < c0) ? 0 : 1;              // compile-time
      const int kt = tl ? frag - c0 : frag;
      const int kbase = kt * 16 + lk * 4;
      const int colb = (tl ? colb1 : 0) + kbase;
#pragma unroll
      for (int qt = 0; qt < 2; ++qt) {
        int qrow = (tl ? qo1 : qo0) + qt * 16 + lr;
        float fv = tl ? frv1[qt] : frv0[qt];
        bf16x4 pk;
        float rs = 0.f;
#pragma unroll
        for (int j = 0; j < 4; ++j) {
          float e = (kbase + j < qrow) ? __expf(acc[i][qt][j] * fv) : 0.f;
          rs += e;
          pk[j] = f2bf(e);
        }
        *(bf16x4*)&Pl[qt * 16 + lr][colb] = pk;
        if (tl == 0) { if (qt == 0) rs00 += rs; else rs01 += rs; }
        else         { if (qt == 0) rs10 += rs; else rs11 += rs; }
      }
    }
  }

#pragma unroll
  for (int msk = 16; msk < 64; msk <<= 1) {
    rs00 += __shfl_xor(rs00, msk);
    rs01 += __shfl_xor(rs01, msk);
    rs10 += __shfl_xor(rs10, msk);
    rs11 += __shfl_xor(rs11, msk);
  }
  if (lk == 0) {
    redsum[0][lr][w] = rs00;
    redsum[0][16 + lr][w] = rs01;
    redsum[1][lr][w] = rs10;
    redsum[1][16 + lr][w] = rs11;
  }
  __syncthreads();   // P + redsum ready (single barrier)

  // ---- PV (fully static trip counts): unit0 (tile0, qt=w&1, dh=w>>1),
  //                                     unit1 (tile1, qt=w>>1, dh=w&1)
  const int uqt0 = w & 1, udh0 = w >> 1;
  const int uqt1 = w >> 1, udh1 = w & 1;
  f32x4 oacc0[2] = {vzero, vzero}, oacc1[2] = {vzero, vzero};

#pragma unroll
  for (int kb = 0; kb < 16; ++kb) {
    if (kb < P + 1) {                    // compile-time
      bf16x8 pa = *(const bf16x8*)&Pl[uqt0 * 16 + lr][kb * 32 + lk * 8];
#pragma unroll
      for (int n = 0; n < 2; ++n) {
        bf16x8 vf = *(const bf16x8*)(vT + (size_t)(h * DK_ + udh0 * 32 + n * 16 + lr) * BS_
                                        + (size_t)b * S_ + kb * 32 + lk * 8);
        oacc0[n] = __builtin_amdgcn_mfma_f32_16x16x32_bf16(pa, vf, oacc0[n], 0, 0, 0);
      }
    }
    if (kb < 16 - P) {                   // compile-time
      bf16x8 pa = *(const bf16x8*)&Pl[uqt1 * 16 + lr][colb1 + kb * 32 + lk * 8];
#pragma unroll
      for (int n = 0; n < 2; ++n) {
        bf16x8 vf = *(const bf16x8*)(vT + (size_t)(h * DK_ + udh1 * 32 + n * 16 + lr) * BS_
                                        + (size_t)b * S_ + kb * 32 + lk * 8);
        oacc1[n] = __builtin_amdgcn_mfma_f32_16x16x32_bf16(pa, vf, oacc1[n], 0, 0, 0);
      }
    }
  }

  // ---- normalize + write
  {
    float invd[4];
#pragma unroll
    for (int j = 0; j < 4; ++j) {
      int row = uqt0 * 16 + lk * 4 + j;
      float ds = redsum[0][row][0] + redsum[0][row][1] + redsum[0][row][2] + redsum[0][row][3];
      invd[j] = ds > 0.f ? 1.f / ds : 0.f;
    }
#pragma unroll
    for (int n = 0; n < 2; ++n)
#pragma unroll
      for (int j = 0; j < 4; ++j) {
        int qrow = qo0 + uqt0 * 16 + lk * 4 + j;
        out[qk_head + (size_t)qrow * D_ + udh0 * 32 + n * 16 + lr] = f2bf(oacc0[n][j] * invd[j]);
      }
  }
  {
    float invd[4];
#pragma unroll
    for (int j = 0; j < 4; ++j) {
      int row = uqt1 * 16 + lk * 4 + j;
      float ds = redsum[1][row][0] + redsum[1][row][1] + redsum[1][row][2] + redsum[1][row][3];
      invd[j] = ds > 0.f ? 1.f / ds : 0.f;
    }
#pragma unroll
    for (int n = 0; n < 2; ++n)
#pragma unroll
      for (int j = 0; j < 4; ++j) {
        int qrow = qo1 + uqt1 * 16 + lk * 4 + j;
        out[qk_head + (size_t)qrow * D_ + udh1 * 32 + n * 16 + lr] = f2bf(oacc1[n][j] * invd[j]);
      }
  }
}

__global__ __launch_bounds__(256, 4) void attn_kernel(
    const short* __restrict__ qk, const short* __restrict__ vT,
    const float* __restrict__ fr, short* __restrict__ out)
{
  const int hw = blockIdx.x;                 // 4096 blocks
  const int l = (hw & 7) * 512 + (hw >> 3);  // bijective XCD grouping
  const int p = l & 7, hb = l >> 3;
  const int h = hb & 7, b = hb >> 3;
  const int t = threadIdx.x;
  const int w = t >> 6, lr = t & 15, lk = (t & 63) >> 4;

  __shared__ short Pl[32][552];
  __shared__ float redsum[2][32][4];

  switch (p) {
    case 0: attn_body<0>(qk, vT, fr, out, Pl, redsum, h, b, w, lr, lk); break;
    case 1: attn_body<1>(qk, vT, fr, out, Pl, redsum, h, b, w, lr, lk); break;
    case 2: attn_body<2>(qk, vT, fr, out, Pl, redsum, h, b, w, lr, lk); break;
    case 3: attn_body<3>(qk, vT, fr, out, Pl, redsum, h, b, w, lr, lk); break;
    case 4: attn_body<4>(qk, vT, fr, out, Pl, redsum, h, b, w, lr, lk); break;
    case 5: attn_body<5>(qk, vT, fr, out, Pl, redsum, h, b, w, lr, lk); break;
    case 6: attn_body<6>(qk, vT, fr, out, Pl, redsum, h, b, w, lr, lk); break;
    case 7: attn_body<7>(qk, vT, fr, out, Pl, redsum, h, b, w, lr, lk); break;
  }
}

// ---------------- fused residual + LayerNorm ----------------
__global__ __launch_bounds__(256) void ln_res(
    const float* __restrict__ xin, const short* __restrict__ add,
    const float* __restrict__ g, const float* __restrict__ bb,
    float* __restrict__ xout, short* __restrict__ xbout)
{
  const int row = blockIdx.x * 4 + (threadIdx.x >> 6);
  const int lane = threadIdx.x & 63;
  const size_t base = (size_t)row * D_ + lane * 8;

  f32x4 a0 = *(const f32x4*)(xin + base);
  f32x4 a1 = *(const f32x4*)(xin + base + 4);
  bf16x8 av = *(const bf16x8*)(add + base);
  float vals[8];
#pragma unroll
  for (int i = 0; i < 4; ++i) vals[i] = a0[i] + bf2f(av[i]);
#pragma unroll
  for (int i = 0; i < 4; ++i) vals[4 + i] = a1[i] + bf2f(av[4 + i]);

  float s = 0.f, sq = 0.f;
#pragma unroll
  for (int i = 0; i < 8; ++i) { s += vals[i]; sq += vals[i] * vals[i]; }
#pragma unroll
  for (int m = 1; m < 64; m <<= 1) { s += __shfl_xor(s, m); sq += __shfl_xor(sq, m); }

  float mean = s * (1.f / D_);
  float var = sq * (1.f / D_) - mean * mean;
  float rstd = rsqrtf(var + 1e-5f);

  int col = lane * 8;
  f32x4 o0, o1; bf16x8 ob;
#pragma unroll
  for (int i = 0; i < 8; ++i) {
    float vv = g[col + i] * (vals[i] - mean) * rstd + bb[col + i];
    if (i < 4) o0[i] = vv; else o1[i - 4] = vv;
    ob[i] = f2bf(vv);
  }
  *(f32x4*)(xout + base) = o0;
  *(f32x4*)(xout + base + 4) = o1;
  *(bf16x8*)(xbout + base) = ob;
}

// ---------------- host ----------------
extern "C" void kernel_launch(void* const* d_in, const int* in_sizes, int n_in,
                              void* d_out, int out_size, void* d_ws, size_t ws_size,
                              hipStream_t stream) {
  const float* q_emb = (const float*)d_in[0];
  const float* qa_emb = (const float*)d_in[1];
  const float* frate = (const float*)d_in[2];
  const float* Wk = (const float*)d_in[3];
  const float* bk = (const float*)d_in[4];
  const float* Wv = (const float*)d_in[5];
  const float* bv = (const float*)d_in[6];
  const float* Wo = (const float*)d_in[7];
  const float* bo = (const float*)d_in[8];
  const float* ln1g = (const float*)d_in[9];
  const float* ln1b = (const float*)d_in[10];
  const float* W1 = (const float*)d_in[11];
  const float* b1 = (const float*)d_in[12];
  const float* W2 = (const float*)d_in[13];
  const float* b2 = (const float*)d_in[14];
  const float* ln2g = (const float*)d_in[15];
  const float* ln2b = (const float*)d_in[16];
  float* x = (float*)d_out;

  char* ws = (char*)d_ws;
  size_t off = 0;
  auto alloc = [&](size_t bytes) -> void* {
    void* p = ws + off;
    off += (bytes + 255) & ~(size_t)255;
    return p;
  };
  const size_t MTOK = (size_t)BS_;   // 32768 rows
  float* pe    = (float*)alloc((size_t)S_ * D_ * 4);
  short* xb    = (short*)alloc(MTOK * D_ * 2);
  short* yb    = (short*)alloc(MTOK * D_ * 2);
  short* qkb   = (short*)alloc(MTOK * D_ * 2);
  short* vTb   = (short*)alloc(MTOK * D_ * 2);   // V transposed: [D][B*S]
  short* ff1b  = (short*)alloc(MTOK * DFF_ * 2);
  // lifetime-based aliases:
  //   attnb (attn->WoGEMM) aliases ff1b (ff1GEMM->ff2GEMM) -- disjoint within a layer
  //   goutb (WoGEMM/ff2GEMM -> ln_res) aliases qkb (dead after attn_kernel)
  short* attnb = ff1b;
  short* goutb = qkb;
  short* wT[L_][5];
  for (int i = 0; i < L_; ++i) {
    wT[i][0] = (short*)alloc((size_t)D_ * D_ * 2);     // WkT [D][D]
    wT[i][1] = (short*)alloc((size_t)D_ * D_ * 2);     // WvT
    wT[i][2] = (short*)alloc((size_t)D_ * D_ * 2);     // WoT
    wT[i][3] = (short*)alloc((size_t)D_ * DFF_ * 2);   // W1T [DFF][D]
    wT[i][4] = (short*)alloc((size_t)DFF_ * D_ * 2);   // W2T [D][DFF]
  }
  if (off > ws_size) {
    fprintf(stderr, "parKT: workspace overflow: need %zu have %zu\n", off, ws_size);
    return;
  }

  pe_kernel<<<(S_ * D_) / 256, 256, 0, stream>>>(pe);
  prep_kernel<<<(int)(MTOK * D_ / (256 * 8)), 256, 0, stream>>>(q_emb, qa_emb, pe, x, xb, yb);

  TrArgs ta;
  for (int i = 0; i < L_; ++i) {
    ta.src[i * 5 + 0] = Wk + (size_t)i * D_ * D_;  ta.dst[i * 5 + 0] = wT[i][0]; ta.R[i * 5 + 0] = D_;   ta.C[i * 5 + 0] = D_;
    ta.src[i * 5 + 1] = Wv + (size_t)i * D_ * D_;  ta.dst[i * 5 + 1] = wT[i][1]; ta.R[i * 5 + 1] = D_;   ta.C[i * 5 + 1] = D_;
    ta.src[i * 5 + 2] = Wo + (size_t)i * D_ * D_;  ta.dst[i * 5 + 2] = wT[i][2]; ta.R[i * 5 + 2] = D_;   ta.C[i * 5 + 2] = D_;
    ta.src[i * 5 + 3] = W1 + (size_t)i * D_ * DFF_; ta.dst[i * 5 + 3] = wT[i][3]; ta.R[i * 5 + 3] = D_;   ta.C[i * 5 + 3] = DFF_;
    ta.src[i * 5 + 4] = W2 + (size_t)i * DFF_ * D_; ta.dst[i * 5 + 4] = wT[i][4]; ta.R[i * 5 + 4] = DFF_; ta.C[i * 5 + 4] = D_;
  }
  tr_w_all<<<dim3(DFF_ / 64, DFF_ / 64, 10), 256, 0, stream>>>(ta);

  const int M = (int)MTOK;
  for (int i = 0; i < L_; ++i) {
    // qk = x @ Wk + bk  (M x D): A-panel sharing -> xmaj=1
    gemm_bt<<<(D_ / 128) * (M / 128), 256, 0, stream>>>(xb, wT[i][0], bk + (size_t)i * D_, qkb, M, D_, D_, 0, 0, D_ / 128, 1);
    // vT = WvT @ y^T + bv (bias per row): [D][B*S]: B-panel (yb) sharing -> xmaj=0
    gemm_bt<<<(M / 128) * (D_ / 128), 256, 0, stream>>>(wT[i][1], yb, bv + (size_t)i * D_, vTb, D_, M, D_, 0, 1, M / 128, 0);
    attn_kernel<<<(S_ / 64) * H_ * B_, 256, 0, stream>>>(qkb, vTb, frate, attnb);
    gemm_bt<<<(D_ / 128) * (M / 128), 256, 0, stream>>>(attnb, wT[i][2], bo + (size_t)i * D_, goutb, M, D_, D_, 0, 0, D_ / 128, 1);
    ln_res<<<M / 4, 256, 0, stream>>>(x, goutb, ln1g + (size_t)i * D_, ln1b + (size_t)i * D_, x, xb);
    gemm_bt<<<(DFF_ / 128) * (M / 128), 256, 0, stream>>>(xb, wT[i][3], b1 + (size_t)i * DFF_, ff1b, M, DFF_, D_, 1, 0, DFF_ / 128, 1);
    gemm_bt<<<(D_ / 128) * (M / 128), 256, 0, stream>>>(ff1b, wT[i][4], b2 + (size_t)i * D_, goutb, M, D_, DFF_, 0, 0, D_ / 128, 1);
    ln_res<<<M / 4, 256, 0, stream>>>(x, goutb, ln2g + (size_t)i * D_, ln2b + (size_t)i * D_, x, xb);
  }
}

// Round 9
// 815.194 us; speedup vs baseline: 1.5430x; 1.0826x over previous
//
#include <hip/hip_runtime.h>
#include <cstdio>

#define B_   64
#define S_   512
#define D_   512
#define H_   8
#define DK_  64
#define DFF_ 1024
#define L_   2
#define BS_  (B_ * S_)   // 32768

typedef __attribute__((ext_vector_type(8))) short bf16x8;
typedef __attribute__((ext_vector_type(4))) short bf16x4;
typedef __attribute__((ext_vector_type(4))) float f32x4;

__device__ inline short f2bf(float f) {
  unsigned u = __float_as_uint(f);
  u = u + 0x7FFF + ((u >> 16) & 1);
  return (short)(u >> 16);
}
__device__ inline float bf2f(short s) {
  return __uint_as_float(((unsigned)(unsigned short)s) << 16);
}

// async global->LDS, 16B per lane; lds dest = wave-uniform base + lane*16
__device__ inline void gl_lds16(const short* g, void* lds_base) {
  __builtin_amdgcn_global_load_lds(
      (const __attribute__((address_space(1))) void*)g,
      (__attribute__((address_space(3))) void*)lds_base, 16, 0, 0);
}

// ---------------- positional encoding table ----------------
__global__ void pe_kernel(float* __restrict__ pe) {
  int idx = blockIdx.x * 256 + threadIdx.x;      // S_*D_ threads
  int s = idx >> 9, d = idx & 511;
  float dv = __expf((float)(d & ~1) * (-9.210340371976184f / (float)D_));
  float ang = (float)s * dv;
  pe[idx] = (d & 1) ? cosf(ang) : sinf(ang);
}

// x = q + pe (f32 master + bf16 mirror); yb = bf16(qa + pe). 8 elem/thread.
__global__ __launch_bounds__(256) void prep_kernel(
    const float* __restrict__ q, const float* __restrict__ qa,
    const float* __restrict__ pe, float* __restrict__ x,
    short* __restrict__ xb, short* __restrict__ yb) {
  size_t base = ((size_t)blockIdx.x * 256 + threadIdx.x) * 8;
  int sd = (int)(base & (size_t)(S_ * D_ - 1));
  f32x4 p0 = *(const f32x4*)(pe + sd);
  f32x4 p1 = *(const f32x4*)(pe + sd + 4);
  f32x4 q0 = *(const f32x4*)(q + base);
  f32x4 q1 = *(const f32x4*)(q + base + 4);
  f32x4 a0 = *(const f32x4*)(qa + base);
  f32x4 a1 = *(const f32x4*)(qa + base + 4);
  f32x4 x0, x1; bf16x8 xv, yv;
#pragma unroll
  for (int i = 0; i < 4; ++i) {
    float xe = q0[i] + p0[i]; x0[i] = xe; xv[i] = f2bf(xe);
    yv[i] = f2bf(a0[i] + p0[i]);
  }
#pragma unroll
  for (int i = 0; i < 4; ++i) {
    float xe = q1[i] + p1[i]; x1[i] = xe; xv[4 + i] = f2bf(xe);
    yv[4 + i] = f2bf(a1[i] + p1[i]);
  }
  *(f32x4*)(x + base) = x0;
  *(f32x4*)(x + base + 4) = x1;
  *(bf16x8*)(xb + base) = xv;
  *(bf16x8*)(yb + base) = yv;
}

// ---------------- all weight transposes in ONE launch ----------------
struct TrArgs {
  const float* src[10];
  short* dst[10];
  int R[10], C[10];
};
__global__ __launch_bounds__(256) void tr_w_all(TrArgs a) {
  const int slot = blockIdx.z;
  const int R = a.R[slot], C = a.C[slot];
  const int c0 = blockIdx.x * 64, r0 = blockIdx.y * 64;
  if (c0 >= C || r0 >= R) return;
  const float* __restrict__ src = a.src[slot];
  short* __restrict__ dst = a.dst[slot];
  __shared__ short Ts[64][72];
  const int t = threadIdx.x;
#pragma unroll
  for (int it = 0; it < 2; ++it) {
    int c2 = it * 256 + t;
    int srow = c2 >> 3, schunk = c2 & 7;
    const float* sp = src + (size_t)(r0 + srow) * C + c0 + schunk * 8;
    f32x4 a0 = *(const f32x4*)sp;
    f32x4 a1 = *(const f32x4*)(sp + 4);
#pragma unroll
    for (int k = 0; k < 4; ++k) Ts[srow][schunk * 8 + k] = f2bf(a0[k]);
#pragma unroll
    for (int k = 0; k < 4; ++k) Ts[srow][schunk * 8 + 4 + k] = f2bf(a1[k]);
  }
  __syncthreads();
#pragma unroll
  for (int it = 0; it < 2; ++it) {
    int c2 = it * 256 + t;
    int orow = c2 >> 3, ochunk = c2 & 7;
    bf16x8 vv;
#pragma unroll
    for (int k = 0; k < 8; ++k) vv[k] = Ts[ochunk * 8 + k][orow];
    *(bf16x8*)(dst + (size_t)(c0 + orow) * R + r0 + ochunk * 8) = vv;
  }
}

// ---------------- bf16 MFMA GEMM: C[M,N] = A[M,K] @ BT[N,K]^T + bias ----------------
// 128x256 tile, BK=32, dbuf LDS, counted-vmcnt pipeline, swapped-operand MFMA
// (lane holds 4 consecutive output cols -> b64 stores). XCD-aware 1D remap.
__global__ __launch_bounds__(256, 2) void gemm_bt(
    const short* __restrict__ A, const short* __restrict__ BT,
    const float* __restrict__ bias, short* __restrict__ Cb,
    int M, int N, int K, int relu, int bias_row, int nx, int xmaj)
{
  const int nwg = gridDim.x;                 // multiple of 8
  const int cpx = nwg >> 3;
  const int l = (blockIdx.x & 7) * cpx + (blockIdx.x >> 3);
  int bcol, brow;
  if (xmaj) { bcol = l % nx; brow = l / nx; }
  else      { int ny = nwg / nx; brow = l % ny; bcol = l / ny; }

  __shared__ __align__(16) short As[2][128][32];
  __shared__ __align__(16) short Bs[2][256][32];
  const int t = threadIdx.x;
  const int w = t >> 6, lane = t & 63, lr = lane & 15, lk = lane >> 4;
  const int wr = w >> 1, wc = w & 1;   // wave: rows wr*64+, cols wc*128+

  const f32x4 vzero = {0.f, 0.f, 0.f, 0.f};
  f32x4 acc[4][8];
#pragma unroll
  for (int m = 0; m < 4; ++m)
#pragma unroll
    for (int n = 0; n < 8; ++n) acc[m][n] = vzero;

  const short* Abase = A + (size_t)brow * 128 * K;
  const short* Bbase = BT + (size_t)bcol * 256 * K;

  auto stage = [&](int buf, int k0) {   // 6 gl_lds per thread (A:2, B:4)
#pragma unroll
    for (int it = 0; it < 2; ++it) {
      int cb = it * 256 + w * 64;
      int c = cb + lane;
      gl_lds16(Abase + (size_t)(c >> 2) * K + k0 + (c & 3) * 8, (char*)&As[buf][0][0] + (size_t)cb * 16);
    }
#pragma unroll
    for (int it = 0; it < 4; ++it) {
      int cb = it * 256 + w * 64;
      int c = cb + lane;
      gl_lds16(Bbase + (size_t)(c >> 2) * K + k0 + (c & 3) * 8, (char*)&Bs[buf][0][0] + (size_t)cb * 16);
    }
  };

  stage(0, 0);
  int cur = 0;
  for (int k0 = 0; k0 < K; k0 += 32) {
    if (k0 + 32 < K) {
      stage(cur ^ 1, k0 + 32);                         // tile t+1 in flight (6 loads)
      asm volatile("s_waitcnt vmcnt(6)" ::: "memory"); // tile t's 6 loads landed
    } else {
      asm volatile("s_waitcnt vmcnt(0)" ::: "memory");
    }
    asm volatile("s_barrier" ::: "memory");            // buf cur ready for all waves

    bf16x8 af[4], bf[8];
#pragma unroll
    for (int m = 0; m < 4; ++m) af[m] = *(const bf16x8*)&As[cur][wr * 64 + m * 16 + lr][lk * 8];
#pragma unroll
    for (int n = 0; n < 8; ++n) bf[n] = *(const bf16x8*)&Bs[cur][wc * 128 + n * 16 + lr][lk * 8];
#pragma unroll
    for (int m = 0; m < 4; ++m)
#pragma unroll
      for (int n = 0; n < 8; ++n)
        acc[m][n] = __builtin_amdgcn_mfma_f32_16x16x32_bf16(bf[n], af[m], acc[m][n], 0, 0, 0);

    asm volatile("s_barrier" ::: "memory");            // all waves done reading cur
    cur ^= 1;
  }

#pragma unroll
  for (int m = 0; m < 4; ++m) {
    int row = brow * 128 + wr * 64 + m * 16 + lr;
    float brv = (bias && bias_row) ? bias[row] : 0.f;
    size_t rb = (size_t)row * N;
#pragma unroll
    for (int n = 0; n < 8; ++n) {
      int colb = bcol * 256 + wc * 128 + n * 16 + lk * 4;
      f32x4 bv4;
      if (bias && !bias_row) bv4 = *(const f32x4*)(bias + colb);
      else { bv4[0] = brv; bv4[1] = brv; bv4[2] = brv; bv4[3] = brv; }
      bf16x4 ov;
#pragma unroll
      for (int j = 0; j < 4; ++j) {
        float vv = acc[m][n][j] + bv4[j];
        if (relu) vv = fmaxf(vv, 0.f);
        ov[j] = f2bf(vv);
      }
      *(bf16x4*)(Cb + rb + colb) = ov;   // 8B store, 4 lanes/row contiguous 32B
    }
  }
}

// ---------------- fused attention: balanced-pair causal, swapped QK^T, static-p,
// ---------------- explicit 1-deep load pipelining in QK^T and PV ----------------
template<int P>
__device__ __forceinline__ void attn_body(
    const short* __restrict__ qk, const short* __restrict__ vT,
    const float* __restrict__ fr, short* __restrict__ out,
    short (*Pl)[552], float (*redsum)[32][4],
    int h, int b, int w, int lr, int lk)
{
  constexpr int qo0 = 32 * P, qo1 = 32 * (15 - P);
  constexpr int c0 = 2 * P + 2;          // tile0 fragment count
  constexpr int colb1 = c0 * 16;         // tile1 P-column offset

  const size_t qk_head = (size_t)b * S_ * D_ + (size_t)h * DK_;
  const float scale = 0.125f;   // 1/sqrt(64)

  bf16x8 qf0[2][2], qf1[2][2];   // [qt][ks]
#pragma unroll
  for (int qt = 0; qt < 2; ++qt)
#pragma unroll
    for (int ks = 0; ks < 2; ++ks) {
      qf0[qt][ks] = *(const bf16x8*)(qk + qk_head + (size_t)(qo0 + qt * 16 + lr) * D_ + ks * 32 + lk * 8);
      qf1[qt][ks] = *(const bf16x8*)(qk + qk_head + (size_t)(qo1 + qt * 16 + lr) * D_ + ks * 32 + lk * 8);
    }

  float frv0[2], frv1[2];
#pragma unroll
  for (int qt = 0; qt < 2; ++qt) {
    frv0[qt] = scale * fr[(size_t)b * S_ + qo0 + qt * 16 + lr];
    frv1[qt] = scale * fr[(size_t)b * S_ + qo1 + qt * 16 + lr];
  }

  const f32x4 vzero = {0.f, 0.f, 0.f, 0.f};
  f32x4 acc[9][2];
#pragma unroll
  for (int i = 0; i < 9; ++i) { acc[i][0] = vzero; acc[i][1] = vzero; }

  // ---- QK^T (swapped) with 1-deep kf prefetch.
  // wave w owns fragments f = w + 4i; nfr = 9 for w<2 else 8 (34 total).
  const int nfr = (w < 2) ? 9 : 8;
  const short* kqbase = qk + qk_head + (size_t)lr * D_ + lk * 8;
  auto kfoff = [&](int i) -> size_t {
    int f = w + 4 * i;
    int kt = (f < c0) ? f : f - c0;
    return (size_t)kt * 16 * D_;
  };
  bf16x8 kbuf[2][2];
  {
    const short* p = kqbase + kfoff(0);
    kbuf[0][0] = *(const bf16x8*)p;
    kbuf[0][1] = *(const bf16x8*)(p + 32);
  }
#pragma unroll
  for (int i = 0; i < 9; ++i) {
    if (i < nfr) {                       // wave-uniform
      if (i + 1 < nfr) {                 // prefetch next fragment's K
        const short* p = kqbase + kfoff(i + 1);
        kbuf[(i + 1) & 1][0] = *(const bf16x8*)p;
        kbuf[(i + 1) & 1][1] = *(const bf16x8*)(p + 32);
      }
      const int f = w + 4 * i;
      if (f < c0) {
#pragma unroll
        for (int ks = 0; ks < 2; ++ks) {
          acc[i][0] = __builtin_amdgcn_mfma_f32_16x16x32_bf16(kbuf[i & 1][ks], qf0[0][ks], acc[i][0], 0, 0, 0);
          acc[i][1] = __builtin_amdgcn_mfma_f32_16x16x32_bf16(kbuf[i & 1][ks], qf0[1][ks], acc[i][1], 0, 0, 0);
        }
      } else {
#pragma unroll
        for (int ks = 0; ks < 2; ++ks) {
          acc[i][0] = __builtin_amdgcn_mfma_f32_16x16x32_bf16(kbuf[i & 1][ks], qf1[0][ks], acc[i][0], 0, 0, 0);
          acc[i][1] = __builtin_amdgcn_mfma_f32_16x16x32_bf16(kbuf[i & 1][ks], qf1[1][ks], acc[i][1], 0, 0, 0);
        }
      }
    }
  }

  // ---- exp pass: e = (k < q) ? exp(score*frv) : 0 ; b64 P-writes; row sums
  float rs00 = 0.f, rs01 = 0.f, rs10 = 0.f, rs11 = 0.f;
#pragma unroll
  for (int frag = 0; frag < 34; ++frag) {
    if ((frag & 3) == w) {
      const int i = frag >> 2;
      const int tl = (frag < c0) ? 0 : 1;              // compile-time
      const int kt = tl ? frag - c0 : frag;
      const int kbase = kt * 16 + lk * 4;
      const int colb = (tl ? colb1 : 0) + kbase;
#pragma unroll
      for (int qt = 0; qt < 2; ++qt) {
        int qrow = (tl ? qo1 : qo0) + qt * 16 + lr;
        float fv = tl ? frv1[qt] : frv0[qt];
        bf16x4 pk;
        float rs = 0.f;
#pragma unroll
        for (int j = 0; j < 4; ++j) {
          float e = (kbase + j < qrow) ? __expf(acc[i][qt][j] * fv) : 0.f;
          rs += e;
          pk[j] = f2bf(e);
        }
        *(bf16x4*)&Pl[qt * 16 + lr][colb] = pk;
        if (tl == 0) { if (qt == 0) rs00 += rs; else rs01 += rs; }
        else         { if (qt == 0) rs10 += rs; else rs11 += rs; }
      }
    }
  }

#pragma unroll
  for (int msk = 16; msk < 64; msk <<= 1) {
    rs00 += __shfl_xor(rs00, msk);
    rs01 += __shfl_xor(rs01, msk);
    rs10 += __shfl_xor(rs10, msk);
    rs11 += __shfl_xor(rs11, msk);
  }
  if (lk == 0) {
    redsum[0][lr][w] = rs00;
    redsum[0][16 + lr][w] = rs01;
    redsum[1][lr][w] = rs10;
    redsum[1][16 + lr][w] = rs11;
  }
  __syncthreads();   // P + redsum ready (single barrier)

  // ---- PV with 1-deep prefetch: unit0 (tile0, qt=w&1, dh=w>>1),
  //                               unit1 (tile1, qt=w>>1, dh=w&1)
  const int uqt0 = w & 1, udh0 = w >> 1;
  const int uqt1 = w >> 1, udh1 = w & 1;
  const short* vu0 = vT + (size_t)(h * DK_ + udh0 * 32 + lr) * BS_ + (size_t)b * S_ + lk * 8;
  const short* vu1 = vT + (size_t)(h * DK_ + udh1 * 32 + lr) * BS_ + (size_t)b * S_ + lk * 8;
  const short* prow0 = &Pl[uqt0 * 16 + lr][lk * 8];
  const short* prow1 = &Pl[uqt1 * 16 + lr][colb1 + lk * 8];

  f32x4 oacc0[2] = {vzero, vzero}, oacc1[2] = {vzero, vzero};
  bf16x8 paB[2][2];       // [parity][unit]
  bf16x8 vfB[2][2][2];    // [parity][unit][n]
  paB[0][0] = *(const bf16x8*)prow0;
  paB[0][1] = *(const bf16x8*)prow1;
#pragma unroll
  for (int n = 0; n < 2; ++n) {
    vfB[0][0][n] = *(const bf16x8*)(vu0 + (size_t)n * 16 * BS_);
    vfB[0][1][n] = *(const bf16x8*)(vu1 + (size_t)n * 16 * BS_);
  }
#pragma unroll
  for (int kb = 0; kb < 16; ++kb) {
    const int pc = kb & 1, pn = (kb + 1) & 1;
    if (kb + 1 < P + 1) {                              // compile-time
      paB[pn][0] = *(const bf16x8*)(prow0 + (kb + 1) * 32);
#pragma unroll
      for (int n = 0; n < 2; ++n)
        vfB[pn][0][n] = *(const bf16x8*)(vu0 + (size_t)n * 16 * BS_ + (kb + 1) * 32);
    }
    if (kb + 1 < 16 - P) {                             // compile-time
      paB[pn][1] = *(const bf16x8*)(prow1 + (kb + 1) * 32);
#pragma unroll
      for (int n = 0; n < 2; ++n)
        vfB[pn][1][n] = *(const bf16x8*)(vu1 + (size_t)n * 16 * BS_ + (kb + 1) * 32);
    }
    if (kb < P + 1) {
#pragma unroll
      for (int n = 0; n < 2; ++n)
        oacc0[n] = __builtin_amdgcn_mfma_f32_16x16x32_bf16(paB[pc][0], vfB[pc][0][n], oacc0[n], 0, 0, 0);
    }
    if (kb < 16 - P) {
#pragma unroll
      for (int n = 0; n < 2; ++n)
        oacc1[n] = __builtin_amdgcn_mfma_f32_16x16x32_bf16(paB[pc][1], vfB[pc][1][n], oacc1[n], 0, 0, 0);
    }
  }

  // ---- normalize + write
  {
    float invd[4];
#pragma unroll
    for (int j = 0; j < 4; ++j) {
      int row = uqt0 * 16 + lk * 4 + j;
      float ds = redsum[0][row][0] + redsum[0][row][1] + redsum[0][row][2] + redsum[0][row][3];
      invd[j] = ds > 0.f ? 1.f / ds : 0.f;
    }
#pragma unroll
    for (int n = 0; n < 2; ++n)
#pragma unroll
      for (int j = 0; j < 4; ++j) {
        int qrow = qo0 + uqt0 * 16 + lk * 4 + j;
        out[qk_head + (size_t)qrow * D_ + udh0 * 32 + n * 16 + lr] = f2bf(oacc0[n][j] * invd[j]);
      }
  }
  {
    float invd[4];
#pragma unroll
    for (int j = 0; j < 4; ++j) {
      int row = uqt1 * 16 + lk * 4 + j;
      float ds = redsum[1][row][0] + redsum[1][row][1] + redsum[1][row][2] + redsum[1][row][3];
      invd[j] = ds > 0.f ? 1.f / ds : 0.f;
    }
#pragma unroll
    for (int n = 0; n < 2; ++n)
#pragma unroll
      for (int j = 0; j < 4; ++j) {
        int qrow = qo1 + uqt1 * 16 + lk * 4 + j;
        out[qk_head + (size_t)qrow * D_ + udh1 * 32 + n * 16 + lr] = f2bf(oacc1[n][j] * invd[j]);
      }
  }
}

__global__ __launch_bounds__(256, 3) void attn_kernel(
    const short* __restrict__ qk, const short* __restrict__ vT,
    const float* __restrict__ fr, short* __restrict__ out)
{
  const int hw = blockIdx.x;                 // 4096 blocks
  const int l = (hw & 7) * 512 + (hw >> 3);  // bijective XCD grouping
  const int p = l & 7, hb = l >> 3;
  const int h = hb & 7, b = hb >> 3;
  const int t = threadIdx.x;
  const int w = t >> 6, lr = t & 15, lk = (t & 63) >> 4;

  __shared__ short Pl[32][552];
  __shared__ float redsum[2][32][4];

  switch (p) {
    case 0: attn_body<0>(qk, vT, fr, out, Pl, redsum, h, b, w, lr, lk); break;
    case 1: attn_body<1>(qk, vT, fr, out, Pl, redsum, h, b, w, lr, lk); break;
    case 2: attn_body<2>(qk, vT, fr, out, Pl, redsum, h, b, w, lr, lk); break;
    case 3: attn_body<3>(qk, vT, fr, out, Pl, redsum, h, b, w, lr, lk); break;
    case 4: attn_body<4>(qk, vT, fr, out, Pl, redsum, h, b, w, lr, lk); break;
    case 5: attn_body<5>(qk, vT, fr, out, Pl, redsum, h, b, w, lr, lk); break;
    case 6: attn_body<6>(qk, vT, fr, out, Pl, redsum, h, b, w, lr, lk); break;
    case 7: attn_body<7>(qk, vT, fr, out, Pl, redsum, h, b, w, lr, lk); break;
  }
}

// ---------------- fused residual + LayerNorm ----------------
__global__ __launch_bounds__(256) void ln_res(
    const float* __restrict__ xin, const short* __restrict__ add,
    const float* __restrict__ g, const float* __restrict__ bb,
    float* __restrict__ xout, short* __restrict__ xbout)
{
  const int row = blockIdx.x * 4 + (threadIdx.x >> 6);
  const int lane = threadIdx.x & 63;
  const size_t base = (size_t)row * D_ + lane * 8;

  f32x4 a0 = *(const f32x4*)(xin + base);
  f32x4 a1 = *(const f32x4*)(xin + base + 4);
  bf16x8 av = *(const bf16x8*)(add + base);
  float vals[8];
#pragma unroll
  for (int i = 0; i < 4; ++i) vals[i] = a0[i] + bf2f(av[i]);
#pragma unroll
  for (int i = 0; i < 4; ++i) vals[4 + i] = a1[i] + bf2f(av[4 + i]);

  float s = 0.f, sq = 0.f;
#pragma unroll
  for (int i = 0; i < 8; ++i) { s += vals[i]; sq += vals[i] * vals[i]; }
#pragma unroll
  for (int m = 1; m < 64; m <<= 1) { s += __shfl_xor(s, m); sq += __shfl_xor(sq, m); }

  float mean = s * (1.f / D_);
  float var = sq * (1.f / D_) - mean * mean;
  float rstd = rsqrtf(var + 1e-5f);

  int col = lane * 8;
  f32x4 o0, o1; bf16x8 ob;
#pragma unroll
  for (int i = 0; i < 8; ++i) {
    float vv = g[col + i] * (vals[i] - mean) * rstd + bb[col + i];
    if (i < 4) o0[i] = vv; else o1[i - 4] = vv;
    ob[i] = f2bf(vv);
  }
  *(f32x4*)(xout + base) = o0;
  *(f32x4*)(xout + base + 4) = o1;
  *(bf16x8*)(xbout + base) = ob;
}

// ---------------- host ----------------
extern "C" void kernel_launch(void* const* d_in, const int* in_sizes, int n_in,
                              void* d_out, int out_size, void* d_ws, size_t ws_size,
                              hipStream_t stream) {
  const float* q_emb = (const float*)d_in[0];
  const float* qa_emb = (const float*)d_in[1];
  const float* frate = (const float*)d_in[2];
  const float* Wk = (const float*)d_in[3];
  const float* bk = (const float*)d_in[4];
  const float* Wv = (const float*)d_in[5];
  const float* bv = (const float*)d_in[6];
  const float* Wo = (const float*)d_in[7];
  const float* bo = (const float*)d_in[8];
  const float* ln1g = (const float*)d_in[9];
  const float* ln1b = (const float*)d_in[10];
  const float* W1 = (const float*)d_in[11];
  const float* b1 = (const float*)d_in[12];
  const float* W2 = (const float*)d_in[13];
  const float* b2 = (const float*)d_in[14];
  const float* ln2g = (const float*)d_in[15];
  const float* ln2b = (const float*)d_in[16];
  float* x = (float*)d_out;

  char* ws = (char*)d_ws;
  size_t off = 0;
  auto alloc = [&](size_t bytes) -> void* {
    void* p = ws + off;
    off += (bytes + 255) & ~(size_t)255;
    return p;
  };
  const size_t MTOK = (size_t)BS_;   // 32768 rows
  float* pe    = (float*)alloc((size_t)S_ * D_ * 4);
  short* xb    = (short*)alloc(MTOK * D_ * 2);
  short* yb    = (short*)alloc(MTOK * D_ * 2);
  short* qkb   = (short*)alloc(MTOK * D_ * 2);
  short* vTb   = (short*)alloc(MTOK * D_ * 2);   // V transposed: [D][B*S]
  short* ff1b  = (short*)alloc(MTOK * DFF_ * 2);
  // lifetime-based aliases:
  //   attnb (attn->WoGEMM) aliases ff1b (ff1GEMM->ff2GEMM) -- disjoint within a layer
  //   goutb (WoGEMM/ff2GEMM -> ln_res) aliases qkb (dead after attn_kernel)
  short* attnb = ff1b;
  short* goutb = qkb;
  short* wT[L_][5];
  for (int i = 0; i < L_; ++i) {
    wT[i][0] = (short*)alloc((size_t)D_ * D_ * 2);     // WkT [D][D]
    wT[i][1] = (short*)alloc((size_t)D_ * D_ * 2);     // WvT
    wT[i][2] = (short*)alloc((size_t)D_ * D_ * 2);     // WoT
    wT[i][3] = (short*)alloc((size_t)D_ * DFF_ * 2);   // W1T [DFF][D]
    wT[i][4] = (short*)alloc((size_t)DFF_ * D_ * 2);   // W2T [D][DFF]
  }
  if (off > ws_size) {
    fprintf(stderr, "parKT: workspace overflow: need %zu have %zu\n", off, ws_size);
    return;
  }

  pe_kernel<<<(S_ * D_) / 256, 256, 0, stream>>>(pe);
  prep_kernel<<<(int)(MTOK * D_ / (256 * 8)), 256, 0, stream>>>(q_emb, qa_emb, pe, x, xb, yb);

  TrArgs ta;
  for (int i = 0; i < L_; ++i) {
    ta.src[i * 5 + 0] = Wk + (size_t)i * D_ * D_;  ta.dst[i * 5 + 0] = wT[i][0]; ta.R[i * 5 + 0] = D_;   ta.C[i * 5 + 0] = D_;
    ta.src[i * 5 + 1] = Wv + (size_t)i * D_ * D_;  ta.dst[i * 5 + 1] = wT[i][1]; ta.R[i * 5 + 1] = D_;   ta.C[i * 5 + 1] = D_;
    ta.src[i * 5 + 2] = Wo + (size_t)i * D_ * D_;  ta.dst[i * 5 + 2] = wT[i][2]; ta.R[i * 5 + 2] = D_;   ta.C[i * 5 + 2] = D_;
    ta.src[i * 5 + 3] = W1 + (size_t)i * D_ * DFF_; ta.dst[i * 5 + 3] = wT[i][3]; ta.R[i * 5 + 3] = D_;   ta.C[i * 5 + 3] = DFF_;
    ta.src[i * 5 + 4] = W2 + (size_t)i * DFF_ * D_; ta.dst[i * 5 + 4] = wT[i][4]; ta.R[i * 5 + 4] = DFF_; ta.C[i * 5 + 4] = D_;
  }
  tr_w_all<<<dim3(DFF_ / 64, DFF_ / 64, 10), 256, 0, stream>>>(ta);

  const int M = (int)MTOK;
  for (int i = 0; i < L_; ++i) {
    // qk = x @ Wk + bk: grid (M/128)*(D/256), A-panel sharing -> xmaj=1, nx=D/256
    gemm_bt<<<(M / 128) * (D_ / 256), 256, 0, stream>>>(xb, wT[i][0], bk + (size_t)i * D_, qkb, M, D_, D_, 0, 0, D_ / 256, 1);
    // vT = WvT @ y^T + bv (bias per row): [D][B*S]; B-panel (yb) sharing -> xmaj=0, nx=#bcol=M/256
    gemm_bt<<<(D_ / 128) * (M / 256), 256, 0, stream>>>(wT[i][1], yb, bv + (size_t)i * D_, vTb, D_, M, D_, 0, 1, M / 256, 0);
    attn_kernel<<<(S_ / 64) * H_ * B_, 256, 0, stream>>>(qkb, vTb, frate, attnb);
    gemm_bt<<<(M / 128) * (D_ / 256), 256, 0, stream>>>(attnb, wT[i][2], bo + (size_t)i * D_, goutb, M, D_, D_, 0, 0, D_ / 256, 1);
    ln_res<<<M / 4, 256, 0, stream>>>(x, goutb, ln1g + (size_t)i * D_, ln1b + (size_t)i * D_, x, xb);
    gemm_bt<<<(M / 128) * (DFF_ / 256), 256, 0, stream>>>(xb, wT[i][3], b1 + (size_t)i * DFF_, ff1b, M, DFF_, D_, 1, 0, DFF_ / 256, 1);
    gemm_bt<<<(M / 128) * (D_ / 256), 256, 0, stream>>>(ff1b, wT[i][4], b2 + (size_t)i * D_, goutb, M, D_, DFF_, 0, 0, D_ / 256, 1);
    ln_res<<<M / 4, 256, 0, stream>>>(x, goutb, ln2g + (size_t)i * D_, ln2b + (size_t)i * D_, x, xb);
  }
}

// Round 10
// 729.966 us; speedup vs baseline: 1.7231x; 1.1168x over previous
//
#include <hip/hip_runtime.h>
#include <cstdio>

#define B_   64
#define S_   512
#define D_   512
#define H_   8
#define DK_  64
#define DFF_ 1024
#define L_   2
#define BS_  (B_ * S_)   // 32768

typedef __attribute__((ext_vector_type(8))) short bf16x8;
typedef __attribute__((ext_vector_type(4))) short bf16x4;
typedef __attribute__((ext_vector_type(4))) float f32x4;

__device__ inline short f2bf(float f) {
  unsigned u = __float_as_uint(f);
  u = u + 0x7FFF + ((u >> 16) & 1);
  return (short)(u >> 16);
}
__device__ inline float bf2f(short s) {
  return __uint_as_float(((unsigned)(unsigned short)s) << 16);
}

// async global->LDS, 16B per lane; lds dest = wave-uniform base + lane*16
__device__ inline void gl_lds16(const short* g, void* lds_base) {
  __builtin_amdgcn_global_load_lds(
      (const __attribute__((address_space(1))) void*)g,
      (__attribute__((address_space(3))) void*)lds_base, 16, 0, 0);
}

// ---------------- positional encoding table ----------------
__global__ void pe_kernel(float* __restrict__ pe) {
  int idx = blockIdx.x * 256 + threadIdx.x;      // S_*D_ threads
  int s = idx >> 9, d = idx & 511;
  float dv = __expf((float)(d & ~1) * (-9.210340371976184f / (float)D_));
  float ang = (float)s * dv;
  pe[idx] = (d & 1) ? cosf(ang) : sinf(ang);
}

// xb = bf16(q + pe); yb = bf16(qa + pe). 8 elem/thread. (bf16 residual master)
__global__ __launch_bounds__(256) void prep_kernel(
    const float* __restrict__ q, const float* __restrict__ qa,
    const float* __restrict__ pe,
    short* __restrict__ xb, short* __restrict__ yb) {
  size_t base = ((size_t)blockIdx.x * 256 + threadIdx.x) * 8;
  int sd = (int)(base & (size_t)(S_ * D_ - 1));
  f32x4 p0 = *(const f32x4*)(pe + sd);
  f32x4 p1 = *(const f32x4*)(pe + sd + 4);
  f32x4 q0 = *(const f32x4*)(q + base);
  f32x4 q1 = *(const f32x4*)(q + base + 4);
  f32x4 a0 = *(const f32x4*)(qa + base);
  f32x4 a1 = *(const f32x4*)(qa + base + 4);
  bf16x8 xv, yv;
#pragma unroll
  for (int i = 0; i < 4; ++i) {
    xv[i] = f2bf(q0[i] + p0[i]);
    yv[i] = f2bf(a0[i] + p0[i]);
  }
#pragma unroll
  for (int i = 0; i < 4; ++i) {
    xv[4 + i] = f2bf(q1[i] + p1[i]);
    yv[4 + i] = f2bf(a1[i] + p1[i]);
  }
  *(bf16x8*)(xb + base) = xv;
  *(bf16x8*)(yb + base) = yv;
}

// ---------------- all weight transposes in ONE launch ----------------
struct TrArgs {
  const float* src[10];
  short* dst[10];
  int R[10], C[10];
};
__global__ __launch_bounds__(256) void tr_w_all(TrArgs a) {
  const int slot = blockIdx.z;
  const int R = a.R[slot], C = a.C[slot];
  const int c0 = blockIdx.x * 64, r0 = blockIdx.y * 64;
  if (c0 >= C || r0 >= R) return;
  const float* __restrict__ src = a.src[slot];
  short* __restrict__ dst = a.dst[slot];
  __shared__ short Ts[64][72];
  const int t = threadIdx.x;
#pragma unroll
  for (int it = 0; it < 2; ++it) {
    int c2 = it * 256 + t;
    int srow = c2 >> 3, schunk = c2 & 7;
    const float* sp = src + (size_t)(r0 + srow) * C + c0 + schunk * 8;
    f32x4 a0 = *(const f32x4*)sp;
    f32x4 a1 = *(const f32x4*)(sp + 4);
#pragma unroll
    for (int k = 0; k < 4; ++k) Ts[srow][schunk * 8 + k] = f2bf(a0[k]);
#pragma unroll
    for (int k = 0; k < 4; ++k) Ts[srow][schunk * 8 + 4 + k] = f2bf(a1[k]);
  }
  __syncthreads();
#pragma unroll
  for (int it = 0; it < 2; ++it) {
    int c2 = it * 256 + t;
    int orow = c2 >> 3, ochunk = c2 & 7;
    bf16x8 vv;
#pragma unroll
    for (int k = 0; k < 8; ++k) vv[k] = Ts[ochunk * 8 + k][orow];
    *(bf16x8*)(dst + (size_t)(c0 + orow) * R + r0 + ochunk * 8) = vv;
  }
}

// ---------------- bf16 MFMA GEMM: C[M,N] = A[M,K] @ BT[N,K]^T + bias ----------------
// 128x256 tile, BK=32, dbuf LDS, counted-vmcnt pipeline, swapped-operand MFMA
// (lane holds 4 consecutive output cols -> b64 stores). XCD-aware 1D remap.
__global__ __launch_bounds__(256, 2) void gemm_bt(
    const short* __restrict__ A, const short* __restrict__ BT,
    const float* __restrict__ bias, short* __restrict__ Cb,
    int M, int N, int K, int relu, int bias_row, int nx, int xmaj)
{
  const int nwg = gridDim.x;                 // multiple of 8
  const int cpx = nwg >> 3;
  const int l = (blockIdx.x & 7) * cpx + (blockIdx.x >> 3);
  int bcol, brow;
  if (xmaj) { bcol = l % nx; brow = l / nx; }
  else      { int ny = nwg / nx; brow = l % ny; bcol = l / ny; }

  __shared__ __align__(16) short As[2][128][32];
  __shared__ __align__(16) short Bs[2][256][32];
  const int t = threadIdx.x;
  const int w = t >> 6, lane = t & 63, lr = lane & 15, lk = lane >> 4;
  const int wr = w >> 1, wc = w & 1;   // wave: rows wr*64+, cols wc*128+

  const f32x4 vzero = {0.f, 0.f, 0.f, 0.f};
  f32x4 acc[4][8];
#pragma unroll
  for (int m = 0; m < 4; ++m)
#pragma unroll
    for (int n = 0; n < 8; ++n) acc[m][n] = vzero;

  const short* Abase = A + (size_t)brow * 128 * K;
  const short* Bbase = BT + (size_t)bcol * 256 * K;

  auto stage = [&](int buf, int k0) {   // 6 gl_lds per thread (A:2, B:4)
#pragma unroll
    for (int it = 0; it < 2; ++it) {
      int cb = it * 256 + w * 64;
      int c = cb + lane;
      gl_lds16(Abase + (size_t)(c >> 2) * K + k0 + (c & 3) * 8, (char*)&As[buf][0][0] + (size_t)cb * 16);
    }
#pragma unroll
    for (int it = 0; it < 4; ++it) {
      int cb = it * 256 + w * 64;
      int c = cb + lane;
      gl_lds16(Bbase + (size_t)(c >> 2) * K + k0 + (c & 3) * 8, (char*)&Bs[buf][0][0] + (size_t)cb * 16);
    }
  };

  stage(0, 0);
  int cur = 0;
  for (int k0 = 0; k0 < K; k0 += 32) {
    if (k0 + 32 < K) {
      stage(cur ^ 1, k0 + 32);                         // tile t+1 in flight (6 loads)
      asm volatile("s_waitcnt vmcnt(6)" ::: "memory"); // tile t's 6 loads landed
    } else {
      asm volatile("s_waitcnt vmcnt(0)" ::: "memory");
    }
    asm volatile("s_barrier" ::: "memory");            // buf cur ready for all waves

    bf16x8 af[4], bf[8];
#pragma unroll
    for (int m = 0; m < 4; ++m) af[m] = *(const bf16x8*)&As[cur][wr * 64 + m * 16 + lr][lk * 8];
#pragma unroll
    for (int n = 0; n < 8; ++n) bf[n] = *(const bf16x8*)&Bs[cur][wc * 128 + n * 16 + lr][lk * 8];
#pragma unroll
    for (int m = 0; m < 4; ++m)
#pragma unroll
      for (int n = 0; n < 8; ++n)
        acc[m][n] = __builtin_amdgcn_mfma_f32_16x16x32_bf16(bf[n], af[m], acc[m][n], 0, 0, 0);

    asm volatile("s_barrier" ::: "memory");            // all waves done reading cur
    cur ^= 1;
  }

#pragma unroll
  for (int m = 0; m < 4; ++m) {
    int row = brow * 128 + wr * 64 + m * 16 + lr;
    float brv = (bias && bias_row) ? bias[row] : 0.f;
    size_t rb = (size_t)row * N;
#pragma unroll
    for (int n = 0; n < 8; ++n) {
      int colb = bcol * 256 + wc * 128 + n * 16 + lk * 4;
      f32x4 bv4;
      if (bias && !bias_row) bv4 = *(const f32x4*)(bias + colb);
      else { bv4[0] = brv; bv4[1] = brv; bv4[2] = brv; bv4[3] = brv; }
      bf16x4 ov;
#pragma unroll
      for (int j = 0; j < 4; ++j) {
        float vv = acc[m][n][j] + bv4[j];
        if (relu) vv = fmaxf(vv, 0.f);
        ov[j] = f2bf(vv);
      }
      *(bf16x4*)(Cb + rb + colb) = ov;   // 8B store, 4 lanes/row contiguous 32B
    }
  }
}

// ---------------- fused attention: balanced-pair causal, swapped QK^T, static-p,
// ---------------- sched_barrier-pinned load pipelining ----------------
template<int P>
__device__ __forceinline__ void attn_body(
    const short* __restrict__ qk, const short* __restrict__ vT,
    const float* __restrict__ fr, short* __restrict__ out,
    short (*Pl)[552], float (*redsum)[32][4],
    int h, int b, int w, int lr, int lk)
{
  constexpr int qo0 = 32 * P, qo1 = 32 * (15 - P);
  constexpr int c0 = 2 * P + 2;          // tile0 fragment count
  constexpr int colb1 = c0 * 16;         // tile1 P-column offset
  constexpr int n0 = P + 1;              // unit0 PV kb count
  constexpr int n1 = 16 - P;             // unit1 PV kb count

  const size_t qk_head = (size_t)b * S_ * D_ + (size_t)h * DK_;
  const float scale = 0.125f;   // 1/sqrt(64)

  bf16x8 qf0[2][2], qf1[2][2];   // [qt][ks]
#pragma unroll
  for (int qt = 0; qt < 2; ++qt)
#pragma unroll
    for (int ks = 0; ks < 2; ++ks) {
      qf0[qt][ks] = *(const bf16x8*)(qk + qk_head + (size_t)(qo0 + qt * 16 + lr) * D_ + ks * 32 + lk * 8);
      qf1[qt][ks] = *(const bf16x8*)(qk + qk_head + (size_t)(qo1 + qt * 16 + lr) * D_ + ks * 32 + lk * 8);
    }

  float frv0[2], frv1[2];
#pragma unroll
  for (int qt = 0; qt < 2; ++qt) {
    frv0[qt] = scale * fr[(size_t)b * S_ + qo0 + qt * 16 + lr];
    frv1[qt] = scale * fr[(size_t)b * S_ + qo1 + qt * 16 + lr];
  }

  const f32x4 vzero = {0.f, 0.f, 0.f, 0.f};
  f32x4 acc[9][2];
#pragma unroll
  for (int i = 0; i < 9; ++i) { acc[i][0] = vzero; acc[i][1] = vzero; }

  // ---- QK^T (swapped) with sched_barrier-pinned 1-deep K prefetch.
  const int nfr = (w < 2) ? 9 : 8;     // 34 fragments over 4 waves
  const short* kqbase = qk + qk_head + (size_t)lr * D_ + lk * 8;
  auto kfoff = [&](int i) -> size_t {
    int f = w + 4 * i;
    int kt = (f < c0) ? f : f - c0;
    return (size_t)kt * 16 * D_;
  };
  bf16x8 kbuf[2][2];
  {
    const short* p = kqbase + kfoff(0);
    kbuf[0][0] = *(const bf16x8*)p;
    kbuf[0][1] = *(const bf16x8*)(p + 32);
  }
#pragma unroll
  for (int i = 0; i < 9; ++i) {
    if (i < nfr) {                       // wave-uniform
      if (i + 1 < nfr) {                 // prefetch next fragment's K
        const short* p = kqbase + kfoff(i + 1);
        kbuf[(i + 1) & 1][0] = *(const bf16x8*)p;
        kbuf[(i + 1) & 1][1] = *(const bf16x8*)(p + 32);
      }
      __builtin_amdgcn_sched_barrier(0);   // pin: prefetch issued before MFMAs
      const int f = w + 4 * i;
      if (f < c0) {
#pragma unroll
        for (int ks = 0; ks < 2; ++ks) {
          acc[i][0] = __builtin_amdgcn_mfma_f32_16x16x32_bf16(kbuf[i & 1][ks], qf0[0][ks], acc[i][0], 0, 0, 0);
          acc[i][1] = __builtin_amdgcn_mfma_f32_16x16x32_bf16(kbuf[i & 1][ks], qf0[1][ks], acc[i][1], 0, 0, 0);
        }
      } else {
#pragma unroll
        for (int ks = 0; ks < 2; ++ks) {
          acc[i][0] = __builtin_amdgcn_mfma_f32_16x16x32_bf16(kbuf[i & 1][ks], qf1[0][ks], acc[i][0], 0, 0, 0);
          acc[i][1] = __builtin_amdgcn_mfma_f32_16x16x32_bf16(kbuf[i & 1][ks], qf1[1][ks], acc[i][1], 0, 0, 0);
        }
      }
      __builtin_amdgcn_sched_barrier(0);
    }
  }

  // ---- PV V-prefetch for kb=0,1 issued NOW (hidden under the exp pass) ----
  const int uqt0 = w & 1, udh0 = w >> 1;
  const int uqt1 = w >> 1, udh1 = w & 1;
  const short* vu0 = vT + (size_t)(h * DK_ + udh0 * 32 + lr) * BS_ + (size_t)b * S_ + lk * 8;
  const short* vu1 = vT + (size_t)(h * DK_ + udh1 * 32 + lr) * BS_ + (size_t)b * S_ + lk * 8;
  bf16x8 vfB[2][2][2];    // [parity][unit][n]
#pragma unroll
  for (int n = 0; n < 2; ++n) {
    vfB[0][0][n] = *(const bf16x8*)(vu0 + (size_t)n * 16 * BS_);
    vfB[0][1][n] = *(const bf16x8*)(vu1 + (size_t)n * 16 * BS_);
  }
  if (1 < n0) {
#pragma unroll
    for (int n = 0; n < 2; ++n)
      vfB[1][0][n] = *(const bf16x8*)(vu0 + (size_t)n * 16 * BS_ + 32);
  }
#pragma unroll
  for (int n = 0; n < 2; ++n)
    vfB[1][1][n] = *(const bf16x8*)(vu1 + (size_t)n * 16 * BS_ + 32);   // n1 >= 9
  __builtin_amdgcn_sched_barrier(0);     // pin: V loads in flight before exp pass

  // ---- exp pass: e = (k < q) ? exp(score*frv) : 0 ; b64 P-writes; row sums
  float rs00 = 0.f, rs01 = 0.f, rs10 = 0.f, rs11 = 0.f;
#pragma unroll
  for (int frag = 0; frag < 34; ++frag) {
    if ((frag & 3) == w) {
      const int i = frag >> 2;
      const int tl = (frag < c0) ? 0 : 1;              // compile-time
      const int kt = tl ? frag - c0 : frag;
      const int kbase = kt * 16 + lk * 4;
      const int colb = (tl ? colb1 : 0) + kbase;
#pragma unroll
      for (int qt = 0; qt < 2; ++qt) {
        int qrow = (tl ? qo1 : qo0) + qt * 16 + lr;
        float fv = tl ? frv1[qt] : frv0[qt];
        bf16x4 pk;
        float rs = 0.f;
#pragma unroll
        for (int j = 0; j < 4; ++j) {
          float e = (kbase + j < qrow) ? __expf(acc[i][qt][j] * fv) : 0.f;
          rs += e;
          pk[j] = f2bf(e);
        }
        *(bf16x4*)&Pl[qt * 16 + lr][colb] = pk;
        if (tl == 0) { if (qt == 0) rs00 += rs; else rs01 += rs; }
        else         { if (qt == 0) rs10 += rs; else rs11 += rs; }
      }
    }
  }

#pragma unroll
  for (int msk = 16; msk < 64; msk <<= 1) {
    rs00 += __shfl_xor(rs00, msk);
    rs01 += __shfl_xor(rs01, msk);
    rs10 += __shfl_xor(rs10, msk);
    rs11 += __shfl_xor(rs11, msk);
  }
  if (lk == 0) {
    redsum[0][lr][w] = rs00;
    redsum[0][16 + lr][w] = rs01;
    redsum[1][lr][w] = rs10;
    redsum[1][16 + lr][w] = rs11;
  }
  __syncthreads();   // P + redsum ready (single barrier)

  // ---- PV: depth-2 V pipeline + 1-deep pa(LDS) prefetch, sched_barrier-pinned
  const short* prow0 = &Pl[uqt0 * 16 + lr][lk * 8];
  const short* prow1 = &Pl[uqt1 * 16 + lr][colb1 + lk * 8];
  f32x4 oacc0[2] = {vzero, vzero}, oacc1[2] = {vzero, vzero};
  bf16x8 paB[2][2];       // [parity][unit]
  paB[0][0] = *(const bf16x8*)prow0;
  paB[0][1] = *(const bf16x8*)prow1;

#pragma unroll
  for (int kb = 0; kb < 16; ++kb) {
    const int pc = kb & 1, pn = pc ^ 1;
    if (kb + 1 < n0) paB[pn][0] = *(const bf16x8*)(prow0 + (kb + 1) * 32);
    if (kb + 1 < n1) paB[pn][1] = *(const bf16x8*)(prow1 + (kb + 1) * 32);
    __builtin_amdgcn_sched_barrier(0);   // pa(kb+1) issued; MFMAs below use kb
    if (kb < n0) {
#pragma unroll
      for (int n = 0; n < 2; ++n)
        oacc0[n] = __builtin_amdgcn_mfma_f32_16x16x32_bf16(paB[pc][0], vfB[pc][0][n], oacc0[n], 0, 0, 0);
    }
    if (kb < n1) {
#pragma unroll
      for (int n = 0; n < 2; ++n)
        oacc1[n] = __builtin_amdgcn_mfma_f32_16x16x32_bf16(paB[pc][1], vfB[pc][1][n], oacc1[n], 0, 0, 0);
    }
    __builtin_amdgcn_sched_barrier(0);   // MFMAs(kb) before V(kb+2) refill of pc
    if (kb + 2 < n0) {
#pragma unroll
      for (int n = 0; n < 2; ++n)
        vfB[pc][0][n] = *(const bf16x8*)(vu0 + (size_t)n * 16 * BS_ + (kb + 2) * 32);
    }
    if (kb + 2 < n1) {
#pragma unroll
      for (int n = 0; n < 2; ++n)
        vfB[pc][1][n] = *(const bf16x8*)(vu1 + (size_t)n * 16 * BS_ + (kb + 2) * 32);
    }
    __builtin_amdgcn_sched_barrier(0);
  }

  // ---- normalize + write
  {
    float invd[4];
#pragma unroll
    for (int j = 0; j < 4; ++j) {
      int row = uqt0 * 16 + lk * 4 + j;
      float ds = redsum[0][row][0] + redsum[0][row][1] + redsum[0][row][2] + redsum[0][row][3];
      invd[j] = ds > 0.f ? 1.f / ds : 0.f;
    }
#pragma unroll
    for (int n = 0; n < 2; ++n)
#pragma unroll
      for (int j = 0; j < 4; ++j) {
        int qrow = qo0 + uqt0 * 16 + lk * 4 + j;
        out[qk_head + (size_t)qrow * D_ + udh0 * 32 + n * 16 + lr] = f2bf(oacc0[n][j] * invd[j]);
      }
  }
  {
    float invd[4];
#pragma unroll
    for (int j = 0; j < 4; ++j) {
      int row = uqt1 * 16 + lk * 4 + j;
      float ds = redsum[1][row][0] + redsum[1][row][1] + redsum[1][row][2] + redsum[1][row][3];
      invd[j] = ds > 0.f ? 1.f / ds : 0.f;
    }
#pragma unroll
    for (int n = 0; n < 2; ++n)
#pragma unroll
      for (int j = 0; j < 4; ++j) {
        int qrow = qo1 + uqt1 * 16 + lk * 4 + j;
        out[qk_head + (size_t)qrow * D_ + udh1 * 32 + n * 16 + lr] = f2bf(oacc1[n][j] * invd[j]);
      }
  }
}

__global__ __launch_bounds__(256, 3) void attn_kernel(
    const short* __restrict__ qk, const short* __restrict__ vT,
    const float* __restrict__ fr, short* __restrict__ out)
{
  const int hw = blockIdx.x;                 // 4096 blocks
  const int l = (hw & 7) * 512 + (hw >> 3);  // bijective XCD grouping
  const int p = l & 7, hb = l >> 3;
  const int h = hb & 7, b = hb >> 3;
  const int t = threadIdx.x;
  const int w = t >> 6, lr = t & 15, lk = (t & 63) >> 4;

  __shared__ short Pl[32][552];
  __shared__ float redsum[2][32][4];

  switch (p) {
    case 0: attn_body<0>(qk, vT, fr, out, Pl, redsum, h, b, w, lr, lk); break;
    case 1: attn_body<1>(qk, vT, fr, out, Pl, redsum, h, b, w, lr, lk); break;
    case 2: attn_body<2>(qk, vT, fr, out, Pl, redsum, h, b, w, lr, lk); break;
    case 3: attn_body<3>(qk, vT, fr, out, Pl, redsum, h, b, w, lr, lk); break;
    case 4: attn_body<4>(qk, vT, fr, out, Pl, redsum, h, b, w, lr, lk); break;
    case 5: attn_body<5>(qk, vT, fr, out, Pl, redsum, h, b, w, lr, lk); break;
    case 6: attn_body<6>(qk, vT, fr, out, Pl, redsum, h, b, w, lr, lk); break;
    case 7: attn_body<7>(qk, vT, fr, out, Pl, redsum, h, b, w, lr, lk); break;
  }
}

// ---------------- fused residual + LayerNorm (bf16 master) ----------------
// FINAL=0: write bf16 master only. FINAL=1: write f32 to d_out only.
template<int FINAL>
__global__ __launch_bounds__(256) void ln_res_t(
    const short* __restrict__ xin, const short* __restrict__ add,
    const float* __restrict__ g, const float* __restrict__ bb,
    short* __restrict__ xbout, float* __restrict__ fout)
{
  const int row = blockIdx.x * 4 + (threadIdx.x >> 6);
  const int lane = threadIdx.x & 63;
  const size_t base = (size_t)row * D_ + lane * 8;

  bf16x8 xv = *(const bf16x8*)(xin + base);
  bf16x8 av = *(const bf16x8*)(add + base);
  float vals[8];
#pragma unroll
  for (int i = 0; i < 8; ++i) vals[i] = bf2f(xv[i]) + bf2f(av[i]);

  float s = 0.f, sq = 0.f;
#pragma unroll
  for (int i = 0; i < 8; ++i) { s += vals[i]; sq += vals[i] * vals[i]; }
#pragma unroll
  for (int m = 1; m < 64; m <<= 1) { s += __shfl_xor(s, m); sq += __shfl_xor(sq, m); }

  float mean = s * (1.f / D_);
  float var = sq * (1.f / D_) - mean * mean;
  float rstd = rsqrtf(var + 1e-5f);

  int col = lane * 8;
  if (FINAL) {
    f32x4 o0, o1;
#pragma unroll
    for (int i = 0; i < 8; ++i) {
      float vv = g[col + i] * (vals[i] - mean) * rstd + bb[col + i];
      if (i < 4) o0[i] = vv; else o1[i - 4] = vv;
    }
    *(f32x4*)(fout + base) = o0;
    *(f32x4*)(fout + base + 4) = o1;
  } else {
    bf16x8 ob;
#pragma unroll
    for (int i = 0; i < 8; ++i)
      ob[i] = f2bf(g[col + i] * (vals[i] - mean) * rstd + bb[col + i]);
    *(bf16x8*)(xbout + base) = ob;
  }
}

// ---------------- host ----------------
extern "C" void kernel_launch(void* const* d_in, const int* in_sizes, int n_in,
                              void* d_out, int out_size, void* d_ws, size_t ws_size,
                              hipStream_t stream) {
  const float* q_emb = (const float*)d_in[0];
  const float* qa_emb = (const float*)d_in[1];
  const float* frate = (const float*)d_in[2];
  const float* Wk = (const float*)d_in[3];
  const float* bk = (const float*)d_in[4];
  const float* Wv = (const float*)d_in[5];
  const float* bv = (const float*)d_in[6];
  const float* Wo = (const float*)d_in[7];
  const float* bo = (const float*)d_in[8];
  const float* ln1g = (const float*)d_in[9];
  const float* ln1b = (const float*)d_in[10];
  const float* W1 = (const float*)d_in[11];
  const float* b1 = (const float*)d_in[12];
  const float* W2 = (const float*)d_in[13];
  const float* b2 = (const float*)d_in[14];
  const float* ln2g = (const float*)d_in[15];
  const float* ln2b = (const float*)d_in[16];
  float* x = (float*)d_out;

  char* ws = (char*)d_ws;
  size_t off = 0;
  auto alloc = [&](size_t bytes) -> void* {
    void* p = ws + off;
    off += (bytes + 255) & ~(size_t)255;
    return p;
  };
  const size_t MTOK = (size_t)BS_;   // 32768 rows
  float* pe    = (float*)alloc((size_t)S_ * D_ * 4);
  short* xb    = (short*)alloc(MTOK * D_ * 2);
  short* yb    = (short*)alloc(MTOK * D_ * 2);
  short* qkb   = (short*)alloc(MTOK * D_ * 2);
  short* vTb   = (short*)alloc(MTOK * D_ * 2);   // V transposed: [D][B*S]
  short* ff1b  = (short*)alloc(MTOK * DFF_ * 2);
  // lifetime-based aliases:
  //   attnb (attn->WoGEMM) aliases ff1b (ff1GEMM->ff2GEMM) -- disjoint within a layer
  //   goutb (WoGEMM/ff2GEMM -> ln_res) aliases qkb (dead after attn_kernel)
  short* attnb = ff1b;
  short* goutb = qkb;
  short* wT[L_][5];
  for (int i = 0; i < L_; ++i) {
    wT[i][0] = (short*)alloc((size_t)D_ * D_ * 2);     // WkT [D][D]
    wT[i][1] = (short*)alloc((size_t)D_ * D_ * 2);     // WvT
    wT[i][2] = (short*)alloc((size_t)D_ * D_ * 2);     // WoT
    wT[i][3] = (short*)alloc((size_t)D_ * DFF_ * 2);   // W1T [DFF][D]
    wT[i][4] = (short*)alloc((size_t)DFF_ * D_ * 2);   // W2T [D][DFF]
  }
  if (off > ws_size) {
    fprintf(stderr, "parKT: workspace overflow: need %zu have %zu\n", off, ws_size);
    return;
  }

  pe_kernel<<<(S_ * D_) / 256, 256, 0, stream>>>(pe);
  prep_kernel<<<(int)(MTOK * D_ / (256 * 8)), 256, 0, stream>>>(q_emb, qa_emb, pe, xb, yb);

  TrArgs ta;
  for (int i = 0; i < L_; ++i) {
    ta.src[i * 5 + 0] = Wk + (size_t)i * D_ * D_;  ta.dst[i * 5 + 0] = wT[i][0]; ta.R[i * 5 + 0] = D_;   ta.C[i * 5 + 0] = D_;
    ta.src[i * 5 + 1] = Wv + (size_t)i * D_ * D_;  ta.dst[i * 5 + 1] = wT[i][1]; ta.R[i * 5 + 1] = D_;   ta.C[i * 5 + 1] = D_;
    ta.src[i * 5 + 2] = Wo + (size_t)i * D_ * D_;  ta.dst[i * 5 + 2] = wT[i][2]; ta.R[i * 5 + 2] = D_;   ta.C[i * 5 + 2] = D_;
    ta.src[i * 5 + 3] = W1 + (size_t)i * D_ * DFF_; ta.dst[i * 5 + 3] = wT[i][3]; ta.R[i * 5 + 3] = D_;   ta.C[i * 5 + 3] = DFF_;
    ta.src[i * 5 + 4] = W2 + (size_t)i * DFF_ * D_; ta.dst[i * 5 + 4] = wT[i][4]; ta.R[i * 5 + 4] = DFF_; ta.C[i * 5 + 4] = D_;
  }
  tr_w_all<<<dim3(DFF_ / 64, DFF_ / 64, 10), 256, 0, stream>>>(ta);

  const int M = (int)MTOK;
  for (int i = 0; i < L_; ++i) {
    // qk = x @ Wk + bk: grid (M/128)*(D/256), A-panel sharing -> xmaj=1, nx=D/256
    gemm_bt<<<(M / 128) * (D_ / 256), 256, 0, stream>>>(xb, wT[i][0], bk + (size_t)i * D_, qkb, M, D_, D_, 0, 0, D_ / 256, 1);
    // vT = WvT @ y^T + bv (bias per row): [D][B*S]; B-panel (yb) sharing -> xmaj=0, nx=#bcol=M/256
    gemm_bt<<<(D_ / 128) * (M / 256), 256, 0, stream>>>(wT[i][1], yb, bv + (size_t)i * D_, vTb, D_, M, D_, 0, 1, M / 256, 0);
    attn_kernel<<<(S_ / 64) * H_ * B_, 256, 0, stream>>>(qkb, vTb, frate, attnb);
    gemm_bt<<<(M / 128) * (D_ / 256), 256, 0, stream>>>(attnb, wT[i][2], bo + (size_t)i * D_, goutb, M, D_, D_, 0, 0, D_ / 256, 1);
    ln_res_t<0><<<M / 4, 256, 0, stream>>>(xb, goutb, ln1g + (size_t)i * D_, ln1b + (size_t)i * D_, xb, nullptr);
    gemm_bt<<<(M / 128) * (DFF_ / 256), 256, 0, stream>>>(xb, wT[i][3], b1 + (size_t)i * DFF_, ff1b, M, DFF_, D_, 1, 0, DFF_ / 256, 1);
    gemm_bt<<<(M / 128) * (D_ / 256), 256, 0, stream>>>(ff1b, wT[i][4], b2 + (size_t)i * D_, goutb, M, D_, DFF_, 0, 0, D_ / 256, 1);
    if (i == L_ - 1)
      ln_res_t<1><<<M / 4, 256, 0, stream>>>(xb, goutb, ln2g + (size_t)i * D_, ln2b + (size_t)i * D_, nullptr, x);
    else
      ln_res_t<0><<<M / 4, 256, 0, stream>>>(xb, goutb, ln2g + (size_t)i * D_, ln2b + (size_t)i * D_, xb, nullptr);
  }
}

// Round 11
// 723.936 us; speedup vs baseline: 1.7375x; 1.0083x over previous
//
#include <hip/hip_runtime.h>
#include <cstdio>

#define B_   64
#define S_   512
#define D_   512
#define H_   8
#define DK_  64
#define DFF_ 1024
#define L_   2
#define BS_  (B_ * S_)   // 32768

typedef __attribute__((ext_vector_type(8))) short bf16x8;
typedef __attribute__((ext_vector_type(4))) short bf16x4;
typedef __attribute__((ext_vector_type(4))) float f32x4;

__device__ inline short f2bf(float f) {
  unsigned u = __float_as_uint(f);
  u = u + 0x7FFF + ((u >> 16) & 1);
  return (short)(u >> 16);
}
__device__ inline float bf2f(short s) {
  return __uint_as_float(((unsigned)(unsigned short)s) << 16);
}

// async global->LDS, 16B per lane; lds dest = wave-uniform base + lane*16
__device__ inline void gl_lds16(const short* g, void* lds_base) {
  __builtin_amdgcn_global_load_lds(
      (const __attribute__((address_space(1))) void*)g,
      (__attribute__((address_space(3))) void*)lds_base, 16, 0, 0);
}

// ---------------- positional encoding table ----------------
__global__ void pe_kernel(float* __restrict__ pe) {
  int idx = blockIdx.x * 256 + threadIdx.x;      // S_*D_ threads
  int s = idx >> 9, d = idx & 511;
  float dv = __expf((float)(d & ~1) * (-9.210340371976184f / (float)D_));
  float ang = (float)s * dv;
  pe[idx] = (d & 1) ? cosf(ang) : sinf(ang);
}

// xb = bf16(q + pe); yb = bf16(qa + pe). 8 elem/thread. (bf16 residual master)
__global__ __launch_bounds__(256) void prep_kernel(
    const float* __restrict__ q, const float* __restrict__ qa,
    const float* __restrict__ pe,
    short* __restrict__ xb, short* __restrict__ yb) {
  size_t base = ((size_t)blockIdx.x * 256 + threadIdx.x) * 8;
  int sd = (int)(base & (size_t)(S_ * D_ - 1));
  f32x4 p0 = *(const f32x4*)(pe + sd);
  f32x4 p1 = *(const f32x4*)(pe + sd + 4);
  f32x4 q0 = *(const f32x4*)(q + base);
  f32x4 q1 = *(const f32x4*)(q + base + 4);
  f32x4 a0 = *(const f32x4*)(qa + base);
  f32x4 a1 = *(const f32x4*)(qa + base + 4);
  bf16x8 xv, yv;
#pragma unroll
  for (int i = 0; i < 4; ++i) {
    xv[i] = f2bf(q0[i] + p0[i]);
    yv[i] = f2bf(a0[i] + p0[i]);
  }
#pragma unroll
  for (int i = 0; i < 4; ++i) {
    xv[4 + i] = f2bf(q1[i] + p1[i]);
    yv[4 + i] = f2bf(a1[i] + p1[i]);
  }
  *(bf16x8*)(xb + base) = xv;
  *(bf16x8*)(yb + base) = yv;
}

// ---------------- all weight transposes in ONE launch ----------------
struct TrArgs {
  const float* src[10];
  short* dst[10];
  int R[10], C[10];
};
__global__ __launch_bounds__(256) void tr_w_all(TrArgs a) {
  const int slot = blockIdx.z;
  const int R = a.R[slot], C = a.C[slot];
  const int c0 = blockIdx.x * 64, r0 = blockIdx.y * 64;
  if (c0 >= C || r0 >= R) return;
  const float* __restrict__ src = a.src[slot];
  short* __restrict__ dst = a.dst[slot];
  __shared__ short Ts[64][72];
  const int t = threadIdx.x;
#pragma unroll
  for (int it = 0; it < 2; ++it) {
    int c2 = it * 256 + t;
    int srow = c2 >> 3, schunk = c2 & 7;
    const float* sp = src + (size_t)(r0 + srow) * C + c0 + schunk * 8;
    f32x4 a0 = *(const f32x4*)sp;
    f32x4 a1 = *(const f32x4*)(sp + 4);
#pragma unroll
    for (int k = 0; k < 4; ++k) Ts[srow][schunk * 8 + k] = f2bf(a0[k]);
#pragma unroll
    for (int k = 0; k < 4; ++k) Ts[srow][schunk * 8 + 4 + k] = f2bf(a1[k]);
  }
  __syncthreads();
#pragma unroll
  for (int it = 0; it < 2; ++it) {
    int c2 = it * 256 + t;
    int orow = c2 >> 3, ochunk = c2 & 7;
    bf16x8 vv;
#pragma unroll
    for (int k = 0; k < 8; ++k) vv[k] = Ts[ochunk * 8 + k][orow];
    *(bf16x8*)(dst + (size_t)(c0 + orow) * R + r0 + ochunk * 8) = vv;
  }
}

// ---------------- bf16 MFMA GEMM: C[M,N] = A[M,K] @ BT[N,K]^T + bias ----------------
// 128x256 tile, BK=32, dbuf LDS, counted-vmcnt pipeline, swapped-operand MFMA
// (lane holds 4 consecutive output cols -> b64 stores). XCD-aware 1D remap.
__global__ __launch_bounds__(256, 2) void gemm_bt(
    const short* __restrict__ A, const short* __restrict__ BT,
    const float* __restrict__ bias, short* __restrict__ Cb,
    int M, int N, int K, int relu, int bias_row, int nx, int xmaj)
{
  const int nwg = gridDim.x;                 // multiple of 8
  const int cpx = nwg >> 3;
  const int l = (blockIdx.x & 7) * cpx + (blockIdx.x >> 3);
  int bcol, brow;
  if (xmaj) { bcol = l % nx; brow = l / nx; }
  else      { int ny = nwg / nx; brow = l % ny; bcol = l / ny; }

  __shared__ __align__(16) short As[2][128][32];
  __shared__ __align__(16) short Bs[2][256][32];
  const int t = threadIdx.x;
  const int w = t >> 6, lane = t & 63, lr = lane & 15, lk = lane >> 4;
  const int wr = w >> 1, wc = w & 1;   // wave: rows wr*64+, cols wc*128+

  const f32x4 vzero = {0.f, 0.f, 0.f, 0.f};
  f32x4 acc[4][8];
#pragma unroll
  for (int m = 0; m < 4; ++m)
#pragma unroll
    for (int n = 0; n < 8; ++n) acc[m][n] = vzero;

  const short* Abase = A + (size_t)brow * 128 * K;
  const short* Bbase = BT + (size_t)bcol * 256 * K;

  auto stage = [&](int buf, int k0) {   // 6 gl_lds per thread (A:2, B:4)
#pragma unroll
    for (int it = 0; it < 2; ++it) {
      int cb = it * 256 + w * 64;
      int c = cb + lane;
      gl_lds16(Abase + (size_t)(c >> 2) * K + k0 + (c & 3) * 8, (char*)&As[buf][0][0] + (size_t)cb * 16);
    }
#pragma unroll
    for (int it = 0; it < 4; ++it) {
      int cb = it * 256 + w * 64;
      int c = cb + lane;
      gl_lds16(Bbase + (size_t)(c >> 2) * K + k0 + (c & 3) * 8, (char*)&Bs[buf][0][0] + (size_t)cb * 16);
    }
  };

  stage(0, 0);
  int cur = 0;
  for (int k0 = 0; k0 < K; k0 += 32) {
    if (k0 + 32 < K) {
      stage(cur ^ 1, k0 + 32);                         // tile t+1 in flight (6 loads)
      asm volatile("s_waitcnt vmcnt(6)" ::: "memory"); // tile t's 6 loads landed
    } else {
      asm volatile("s_waitcnt vmcnt(0)" ::: "memory");
    }
    asm volatile("s_barrier" ::: "memory");            // buf cur ready for all waves

    bf16x8 af[4], bf[8];
#pragma unroll
    for (int m = 0; m < 4; ++m) af[m] = *(const bf16x8*)&As[cur][wr * 64 + m * 16 + lr][lk * 8];
#pragma unroll
    for (int n = 0; n < 8; ++n) bf[n] = *(const bf16x8*)&Bs[cur][wc * 128 + n * 16 + lr][lk * 8];
#pragma unroll
    for (int m = 0; m < 4; ++m)
#pragma unroll
      for (int n = 0; n < 8; ++n)
        acc[m][n] = __builtin_amdgcn_mfma_f32_16x16x32_bf16(bf[n], af[m], acc[m][n], 0, 0, 0);

    asm volatile("s_barrier" ::: "memory");            // all waves done reading cur
    cur ^= 1;
  }

#pragma unroll
  for (int m = 0; m < 4; ++m) {
    int row = brow * 128 + wr * 64 + m * 16 + lr;
    float brv = (bias && bias_row) ? bias[row] : 0.f;
    size_t rb = (size_t)row * N;
#pragma unroll
    for (int n = 0; n < 8; ++n) {
      int colb = bcol * 256 + wc * 128 + n * 16 + lk * 4;
      f32x4 bv4;
      if (bias && !bias_row) bv4 = *(const f32x4*)(bias + colb);
      else { bv4[0] = brv; bv4[1] = brv; bv4[2] = brv; bv4[3] = brv; }
      bf16x4 ov;
#pragma unroll
      for (int j = 0; j < 4; ++j) {
        float vv = acc[m][n][j] + bv4[j];
        if (relu) vv = fmaxf(vv, 0.f);
        ov[j] = f2bf(vv);
      }
      *(bf16x4*)(Cb + rb + colb) = ov;   // 8B store, 4 lanes/row contiguous 32B
    }
  }
}

// ---------------- fused attention: balanced-pair causal, swapped QK^T, static-p,
// ---------------- ring-4 K pipeline, ring-3 V pipeline, setprio on MFMA ----------
template<int P>
__device__ __forceinline__ void attn_body(
    const short* __restrict__ qk, const short* __restrict__ vT,
    const float* __restrict__ fr, short* __restrict__ out,
    short (*Pl)[552], float (*redsum)[32][4],
    int h, int b, int w, int lr, int lk)
{
  constexpr int qo0 = 32 * P, qo1 = 32 * (15 - P);
  constexpr int c0 = 2 * P + 2;          // tile0 fragment count
  constexpr int colb1 = c0 * 16;         // tile1 P-column offset
  constexpr int n0 = P + 1;              // unit0 PV kb count
  constexpr int n1 = 16 - P;             // unit1 PV kb count

  const size_t qk_head = (size_t)b * S_ * D_ + (size_t)h * DK_;
  const float scale = 0.125f;   // 1/sqrt(64)

  bf16x8 qf0[2][2], qf1[2][2];   // [qt][ks]
#pragma unroll
  for (int qt = 0; qt < 2; ++qt)
#pragma unroll
    for (int ks = 0; ks < 2; ++ks) {
      qf0[qt][ks] = *(const bf16x8*)(qk + qk_head + (size_t)(qo0 + qt * 16 + lr) * D_ + ks * 32 + lk * 8);
      qf1[qt][ks] = *(const bf16x8*)(qk + qk_head + (size_t)(qo1 + qt * 16 + lr) * D_ + ks * 32 + lk * 8);
    }

  float frv0[2], frv1[2];
#pragma unroll
  for (int qt = 0; qt < 2; ++qt) {
    frv0[qt] = scale * fr[(size_t)b * S_ + qo0 + qt * 16 + lr];
    frv1[qt] = scale * fr[(size_t)b * S_ + qo1 + qt * 16 + lr];
  }

  const f32x4 vzero = {0.f, 0.f, 0.f, 0.f};
  f32x4 acc[9][2];
#pragma unroll
  for (int i = 0; i < 9; ++i) { acc[i][0] = vzero; acc[i][1] = vzero; }

  // ---- QK^T (swapped), ring-4 K prefetch: issue-to-use distance = 4 iters ----
  const int nfr = (w < 2) ? 9 : 8;     // 34 fragments over 4 waves
  const short* kqbase = qk + qk_head + (size_t)lr * D_ + lk * 8;
  auto kfoff = [&](int i) -> size_t {
    int f = w + 4 * i;
    int kt = (f < c0) ? f : f - c0;
    return (size_t)kt * 16 * D_;
  };
  bf16x8 kreg[4][2];
#pragma unroll
  for (int i = 0; i < 4; ++i) {
    if (i < nfr) {                       // wave-uniform; 8 loads back-to-back
      const short* p = kqbase + kfoff(i);
      kreg[i][0] = *(const bf16x8*)p;
      kreg[i][1] = *(const bf16x8*)(p + 32);
    }
  }
  __builtin_amdgcn_sched_barrier(0);
#pragma unroll
  for (int i = 0; i < 9; ++i) {
    if (i < nfr) {                       // wave-uniform
      const int f = w + 4 * i;
      __builtin_amdgcn_s_setprio(1);
      if (f < c0) {
#pragma unroll
        for (int ks = 0; ks < 2; ++ks) {
          acc[i][0] = __builtin_amdgcn_mfma_f32_16x16x32_bf16(kreg[i & 3][ks], qf0[0][ks], acc[i][0], 0, 0, 0);
          acc[i][1] = __builtin_amdgcn_mfma_f32_16x16x32_bf16(kreg[i & 3][ks], qf0[1][ks], acc[i][1], 0, 0, 0);
        }
      } else {
#pragma unroll
        for (int ks = 0; ks < 2; ++ks) {
          acc[i][0] = __builtin_amdgcn_mfma_f32_16x16x32_bf16(kreg[i & 3][ks], qf1[0][ks], acc[i][0], 0, 0, 0);
          acc[i][1] = __builtin_amdgcn_mfma_f32_16x16x32_bf16(kreg[i & 3][ks], qf1[1][ks], acc[i][1], 0, 0, 0);
        }
      }
      __builtin_amdgcn_s_setprio(0);
      __builtin_amdgcn_sched_barrier(0); // MFMAs(i) before refill of slot i&3
      if (i + 4 < nfr) {                 // refill slot with fragment i+4
        const short* p = kqbase + kfoff(i + 4);
        kreg[i & 3][0] = *(const bf16x8*)p;
        kreg[i & 3][1] = *(const bf16x8*)(p + 32);
      }
      __builtin_amdgcn_sched_barrier(0);
    }
  }

  // ---- PV V-prologue: V(0..2) for both units issued NOW (hidden under exp) ----
  const int uqt0 = w & 1, udh0 = w >> 1;
  const int uqt1 = w >> 1, udh1 = w & 1;
  const short* vu0 = vT + (size_t)(h * DK_ + udh0 * 32 + lr) * BS_ + (size_t)b * S_ + lk * 8;
  const short* vu1 = vT + (size_t)(h * DK_ + udh1 * 32 + lr) * BS_ + (size_t)b * S_ + lk * 8;
  bf16x8 vfB[3][2][2];    // [slot][unit][n], slot = kb % 3
#pragma unroll
  for (int kb = 0; kb < 3; ++kb) {
    if (kb < n0) {
#pragma unroll
      for (int n = 0; n < 2; ++n)
        vfB[kb][0][n] = *(const bf16x8*)(vu0 + (size_t)n * 16 * BS_ + kb * 32);
    }
    if (kb < n1) {
#pragma unroll
      for (int n = 0; n < 2; ++n)
        vfB[kb][1][n] = *(const bf16x8*)(vu1 + (size_t)n * 16 * BS_ + kb * 32);
    }
  }
  __builtin_amdgcn_sched_barrier(0);     // V loads in flight before exp pass

  // ---- exp pass: e = (k < q) ? exp(score*frv) : 0 ; b64 P-writes; row sums
  float rs00 = 0.f, rs01 = 0.f, rs10 = 0.f, rs11 = 0.f;
#pragma unroll
  for (int frag = 0; frag < 34; ++frag) {
    if ((frag & 3) == w) {
      const int i = frag >> 2;
      const int tl = (frag < c0) ? 0 : 1;              // compile-time
      const int kt = tl ? frag - c0 : frag;
      const int kbase = kt * 16 + lk * 4;
      const int colb = (tl ? colb1 : 0) + kbase;
#pragma unroll
      for (int qt = 0; qt < 2; ++qt) {
        int qrow = (tl ? qo1 : qo0) + qt * 16 + lr;
        float fv = tl ? frv1[qt] : frv0[qt];
        bf16x4 pk;
        float rs = 0.f;
#pragma unroll
        for (int j = 0; j < 4; ++j) {
          float e = (kbase + j < qrow) ? __expf(acc[i][qt][j] * fv) : 0.f;
          rs += e;
          pk[j] = f2bf(e);
        }
        *(bf16x4*)&Pl[qt * 16 + lr][colb] = pk;
        if (tl == 0) { if (qt == 0) rs00 += rs; else rs01 += rs; }
        else         { if (qt == 0) rs10 += rs; else rs11 += rs; }
      }
    }
  }

#pragma unroll
  for (int msk = 16; msk < 64; msk <<= 1) {
    rs00 += __shfl_xor(rs00, msk);
    rs01 += __shfl_xor(rs01, msk);
    rs10 += __shfl_xor(rs10, msk);
    rs11 += __shfl_xor(rs11, msk);
  }
  if (lk == 0) {
    redsum[0][lr][w] = rs00;
    redsum[0][16 + lr][w] = rs01;
    redsum[1][lr][w] = rs10;
    redsum[1][16 + lr][w] = rs11;
  }
  __syncthreads();   // P + redsum ready (single barrier)

  // ---- PV: ring-3 V pipeline + 1-deep pa(LDS) prefetch ----
  const short* prow0 = &Pl[uqt0 * 16 + lr][lk * 8];
  const short* prow1 = &Pl[uqt1 * 16 + lr][colb1 + lk * 8];
  f32x4 oacc0[2] = {vzero, vzero}, oacc1[2] = {vzero, vzero};
  bf16x8 paB[2][2];       // [parity][unit]
  paB[0][0] = *(const bf16x8*)prow0;
  paB[0][1] = *(const bf16x8*)prow1;

#pragma unroll
  for (int kb = 0; kb < 16; ++kb) {
    const int sc = kb % 3;               // compile-time in unrolled loop
    const int pc = kb & 1, pn = pc ^ 1;
    if (kb + 1 < n0) paB[pn][0] = *(const bf16x8*)(prow0 + (kb + 1) * 32);
    if (kb + 1 < n1) paB[pn][1] = *(const bf16x8*)(prow1 + (kb + 1) * 32);
    __builtin_amdgcn_sched_barrier(0);   // pa(kb+1) issued; MFMAs below use kb
    __builtin_amdgcn_s_setprio(1);
    if (kb < n0) {
#pragma unroll
      for (int n = 0; n < 2; ++n)
        oacc0[n] = __builtin_amdgcn_mfma_f32_16x16x32_bf16(paB[pc][0], vfB[sc][0][n], oacc0[n], 0, 0, 0);
    }
    if (kb < n1) {
#pragma unroll
      for (int n = 0; n < 2; ++n)
        oacc1[n] = __builtin_amdgcn_mfma_f32_16x16x32_bf16(paB[pc][1], vfB[sc][1][n], oacc1[n], 0, 0, 0);
    }
    __builtin_amdgcn_s_setprio(0);
    __builtin_amdgcn_sched_barrier(0);   // MFMAs(kb) before refill of slot sc
    if (kb + 3 < n0) {
#pragma unroll
      for (int n = 0; n < 2; ++n)
        vfB[sc][0][n] = *(const bf16x8*)(vu0 + (size_t)n * 16 * BS_ + (kb + 3) * 32);
    }
    if (kb + 3 < n1) {
#pragma unroll
      for (int n = 0; n < 2; ++n)
        vfB[sc][1][n] = *(const bf16x8*)(vu1 + (size_t)n * 16 * BS_ + (kb + 3) * 32);
    }
    __builtin_amdgcn_sched_barrier(0);
  }

  // ---- normalize + write
  {
    float invd[4];
#pragma unroll
    for (int j = 0; j < 4; ++j) {
      int row = uqt0 * 16 + lk * 4 + j;
      float ds = redsum[0][row][0] + redsum[0][row][1] + redsum[0][row][2] + redsum[0][row][3];
      invd[j] = ds > 0.f ? 1.f / ds : 0.f;
    }
#pragma unroll
    for (int n = 0; n < 2; ++n)
#pragma unroll
      for (int j = 0; j < 4; ++j) {
        int qrow = qo0 + uqt0 * 16 + lk * 4 + j;
        out[qk_head + (size_t)qrow * D_ + udh0 * 32 + n * 16 + lr] = f2bf(oacc0[n][j] * invd[j]);
      }
  }
  {
    float invd[4];
#pragma unroll
    for (int j = 0; j < 4; ++j) {
      int row = uqt1 * 16 + lk * 4 + j;
      float ds = redsum[1][row][0] + redsum[1][row][1] + redsum[1][row][2] + redsum[1][row][3];
      invd[j] = ds > 0.f ? 1.f / ds : 0.f;
    }
#pragma unroll
    for (int n = 0; n < 2; ++n)
#pragma unroll
      for (int j = 0; j < 4; ++j) {
        int qrow = qo1 + uqt1 * 16 + lk * 4 + j;
        out[qk_head + (size_t)qrow * D_ + udh1 * 32 + n * 16 + lr] = f2bf(oacc1[n][j] * invd[j]);
      }
  }
}

__global__ __launch_bounds__(256, 3) void attn_kernel(
    const short* __restrict__ qk, const short* __restrict__ vT,
    const float* __restrict__ fr, short* __restrict__ out)
{
  const int hw = blockIdx.x;                 // 4096 blocks
  const int l = (hw & 7) * 512 + (hw >> 3);  // bijective XCD grouping
  const int p = l & 7, hb = l >> 3;
  const int h = hb & 7, b = hb >> 3;
  const int t = threadIdx.x;
  const int w = t >> 6, lr = t & 15, lk = (t & 63) >> 4;

  __shared__ short Pl[32][552];
  __shared__ float redsum[2][32][4];

  switch (p) {
    case 0: attn_body<0>(qk, vT, fr, out, Pl, redsum, h, b, w, lr, lk); break;
    case 1: attn_body<1>(qk, vT, fr, out, Pl, redsum, h, b, w, lr, lk); break;
    case 2: attn_body<2>(qk, vT, fr, out, Pl, redsum, h, b, w, lr, lk); break;
    case 3: attn_body<3>(qk, vT, fr, out, Pl, redsum, h, b, w, lr, lk); break;
    case 4: attn_body<4>(qk, vT, fr, out, Pl, redsum, h, b, w, lr, lk); break;
    case 5: attn_body<5>(qk, vT, fr, out, Pl, redsum, h, b, w, lr, lk); break;
    case 6: attn_body<6>(qk, vT, fr, out, Pl, redsum, h, b, w, lr, lk); break;
    case 7: attn_body<7>(qk, vT, fr, out, Pl, redsum, h, b, w, lr, lk); break;
  }
}

// ---------------- fused residual + LayerNorm (bf16 master) ----------------
// FINAL=0: write bf16 master only. FINAL=1: write f32 to d_out only.
template<int FINAL>
__global__ __launch_bounds__(256) void ln_res_t(
    const short* __restrict__ xin, const short* __restrict__ add,
    const float* __restrict__ g, const float* __restrict__ bb,
    short* __restrict__ xbout, float* __restrict__ fout)
{
  const int row = blockIdx.x * 4 + (threadIdx.x >> 6);
  const int lane = threadIdx.x & 63;
  const size_t base = (size_t)row * D_ + lane * 8;

  bf16x8 xv = *(const bf16x8*)(xin + base);
  bf16x8 av = *(const bf16x8*)(add + base);
  float vals[8];
#pragma unroll
  for (int i = 0; i < 8; ++i) vals[i] = bf2f(xv[i]) + bf2f(av[i]);

  float s = 0.f, sq = 0.f;
#pragma unroll
  for (int i = 0; i < 8; ++i) { s += vals[i]; sq += vals[i] * vals[i]; }
#pragma unroll
  for (int m = 1; m < 64; m <<= 1) { s += __shfl_xor(s, m); sq += __shfl_xor(sq, m); }

  float mean = s * (1.f / D_);
  float var = sq * (1.f / D_) - mean * mean;
  float rstd = rsqrtf(var + 1e-5f);

  int col = lane * 8;
  if (FINAL) {
    f32x4 o0, o1;
#pragma unroll
    for (int i = 0; i < 8; ++i) {
      float vv = g[col + i] * (vals[i] - mean) * rstd + bb[col + i];
      if (i < 4) o0[i] = vv; else o1[i - 4] = vv;
    }
    *(f32x4*)(fout + base) = o0;
    *(f32x4*)(fout + base + 4) = o1;
  } else {
    bf16x8 ob;
#pragma unroll
    for (int i = 0; i < 8; ++i)
      ob[i] = f2bf(g[col + i] * (vals[i] - mean) * rstd + bb[col + i]);
    *(bf16x8*)(xbout + base) = ob;
  }
}

// ---------------- host ----------------
extern "C" void kernel_launch(void* const* d_in, const int* in_sizes, int n_in,
                              void* d_out, int out_size, void* d_ws, size_t ws_size,
                              hipStream_t stream) {
  const float* q_emb = (const float*)d_in[0];
  const float* qa_emb = (const float*)d_in[1];
  const float* frate = (const float*)d_in[2];
  const float* Wk = (const float*)d_in[3];
  const float* bk = (const float*)d_in[4];
  const float* Wv = (const float*)d_in[5];
  const float* bv = (const float*)d_in[6];
  const float* Wo = (const float*)d_in[7];
  const float* bo = (const float*)d_in[8];
  const float* ln1g = (const float*)d_in[9];
  const float* ln1b = (const float*)d_in[10];
  const float* W1 = (const float*)d_in[11];
  const float* b1 = (const float*)d_in[12];
  const float* W2 = (const float*)d_in[13];
  const float* b2 = (const float*)d_in[14];
  const float* ln2g = (const float*)d_in[15];
  const float* ln2b = (const float*)d_in[16];
  float* x = (float*)d_out;

  char* ws = (char*)d_ws;
  size_t off = 0;
  auto alloc = [&](size_t bytes) -> void* {
    void* p = ws + off;
    off += (bytes + 255) & ~(size_t)255;
    return p;
  };
  const size_t MTOK = (size_t)BS_;   // 32768 rows
  float* pe    = (float*)alloc((size_t)S_ * D_ * 4);
  short* xb    = (short*)alloc(MTOK * D_ * 2);
  short* yb    = (short*)alloc(MTOK * D_ * 2);
  short* qkb   = (short*)alloc(MTOK * D_ * 2);
  short* vTb   = (short*)alloc(MTOK * D_ * 2);   // V transposed: [D][B*S]
  short* ff1b  = (short*)alloc(MTOK * DFF_ * 2);
  // lifetime-based aliases:
  //   attnb (attn->WoGEMM) aliases ff1b (ff1GEMM->ff2GEMM) -- disjoint within a layer
  //   goutb (WoGEMM/ff2GEMM -> ln_res) aliases qkb (dead after attn_kernel)
  short* attnb = ff1b;
  short* goutb = qkb;
  short* wT[L_][5];
  for (int i = 0; i < L_; ++i) {
    wT[i][0] = (short*)alloc((size_t)D_ * D_ * 2);     // WkT [D][D]
    wT[i][1] = (short*)alloc((size_t)D_ * D_ * 2);     // WvT
    wT[i][2] = (short*)alloc((size_t)D_ * D_ * 2);     // WoT
    wT[i][3] = (short*)alloc((size_t)D_ * DFF_ * 2);   // W1T [DFF][D]
    wT[i][4] = (short*)alloc((size_t)DFF_ * D_ * 2);   // W2T [D][DFF]
  }
  if (off > ws_size) {
    fprintf(stderr, "parKT: workspace overflow: need %zu have %zu\n", off, ws_size);
    return;
  }

  pe_kernel<<<(S_ * D_) / 256, 256, 0, stream>>>(pe);
  prep_kernel<<<(int)(MTOK * D_ / (256 * 8)), 256, 0, stream>>>(q_emb, qa_emb, pe, xb, yb);

  TrArgs ta;
  for (int i = 0; i < L_; ++i) {
    ta.src[i * 5 + 0] = Wk + (size_t)i * D_ * D_;  ta.dst[i * 5 + 0] = wT[i][0]; ta.R[i * 5 + 0] = D_;   ta.C[i * 5 + 0] = D_;
    ta.src[i * 5 + 1] = Wv + (size_t)i * D_ * D_;  ta.dst[i * 5 + 1] = wT[i][1]; ta.R[i * 5 + 1] = D_;   ta.C[i * 5 + 1] = D_;
    ta.src[i * 5 + 2] = Wo + (size_t)i * D_ * D_;  ta.dst[i * 5 + 2] = wT[i][2]; ta.R[i * 5 + 2] = D_;   ta.C[i * 5 + 2] = D_;
    ta.src[i * 5 + 3] = W1 + (size_t)i * D_ * DFF_; ta.dst[i * 5 + 3] = wT[i][3]; ta.R[i * 5 + 3] = D_;   ta.C[i * 5 + 3] = DFF_;
    ta.src[i * 5 + 4] = W2 + (size_t)i * DFF_ * D_; ta.dst[i * 5 + 4] = wT[i][4]; ta.R[i * 5 + 4] = DFF_; ta.C[i * 5 + 4] = D_;
  }
  tr_w_all<<<dim3(DFF_ / 64, DFF_ / 64, 10), 256, 0, stream>>>(ta);

  const int M = (int)MTOK;
  for (int i = 0; i < L_; ++i) {
    // qk = x @ Wk + bk: grid (M/128)*(D/256), A-panel sharing -> xmaj=1, nx=D/256
    gemm_bt<<<(M / 128) * (D_ / 256), 256, 0, stream>>>(xb, wT[i][0], bk + (size_t)i * D_, qkb, M, D_, D_, 0, 0, D_ / 256, 1);
    // vT = WvT @ y^T + bv (bias per row): [D][B*S]; B-panel (yb) sharing -> xmaj=0, nx=#bcol=M/256
    gemm_bt<<<(D_ / 128) * (M / 256), 256, 0, stream>>>(wT[i][1], yb, bv + (size_t)i * D_, vTb, D_, M, D_, 0, 1, M / 256, 0);
    attn_kernel<<<(S_ / 64) * H_ * B_, 256, 0, stream>>>(qkb, vTb, frate, attnb);
    gemm_bt<<<(M / 128) * (D_ / 256), 256, 0, stream>>>(attnb, wT[i][2], bo + (size_t)i * D_, goutb, M, D_, D_, 0, 0, D_ / 256, 1);
    ln_res_t<0><<<M / 4, 256, 0, stream>>>(xb, goutb, ln1g + (size_t)i * D_, ln1b + (size_t)i * D_, xb, nullptr);
    gemm_bt<<<(M / 128) * (DFF_ / 256), 256, 0, stream>>>(xb, wT[i][3], b1 + (size_t)i * DFF_, ff1b, M, DFF_, D_, 1, 0, DFF_ / 256, 1);
    gemm_bt<<<(M / 128) * (D_ / 256), 256, 0, stream>>>(ff1b, wT[i][4], b2 + (size_t)i * D_, goutb, M, D_, DFF_, 0, 0, D_ / 256, 1);
    if (i == L_ - 1)
      ln_res_t<1><<<M / 4, 256, 0, stream>>>(xb, goutb, ln2g + (size_t)i * D_, ln2b + (size_t)i * D_, nullptr, x);
    else
      ln_res_t<0><<<M / 4, 256, 0, stream>>>(xb, goutb, ln2g + (size_t)i * D_, ln2b + (size_t)i * D_, xb, nullptr);
  }
}